// Round 1
// baseline (1562.319 us; speedup 1.0000x reference)
//
#include <hip/hip_runtime.h>
#include <math.h>

#define B_ 32
#define D_ 512
#define T_ 256
#define NH_ 8
#define DK_ 64
#define ML_ 25

// ---------------- prep: enc[b,t,c] = x[b,c,t]*sqrt(512) + pos[epos[t],c] ----------------
__global__ __launch_bounds__(256) void prep_kernel(const float* __restrict__ x,
                                                   const int* __restrict__ epos,
                                                   const float* __restrict__ pos,
                                                   float* __restrict__ enc) {
    int i = blockIdx.x * 256 + threadIdx.x;            // 0 .. 32*256*512-1
    int c = i & 511;
    int t = (i >> 9) & 255;
    int b = i >> 17;
    float xv = x[((size_t)b * D_ + c) * T_ + t];
    enc[i] = xv * 22.627417f + pos[(size_t)epos[t] * D_ + c];
}

// ---------------- LayerNorm: wave per row, 8 elems/lane ----------------
__global__ __launch_bounds__(256) void ln_kernel(const float* __restrict__ x,
                                                 const float* __restrict__ s,
                                                 const float* __restrict__ b,
                                                 float* __restrict__ y) {
    int wid = threadIdx.x >> 6, lane = threadIdx.x & 63;
    size_t row = (size_t)blockIdx.x * 4 + wid;
    const float4* xr = (const float4*)(x + row * D_);
    float4 v0 = xr[lane * 2], v1 = xr[lane * 2 + 1];
    float sum = v0.x + v0.y + v0.z + v0.w + v1.x + v1.y + v1.z + v1.w;
    for (int o = 32; o; o >>= 1) sum += __shfl_xor(sum, o);
    float mean = sum * (1.f / 512.f);
    float d0 = v0.x - mean, d1 = v0.y - mean, d2 = v0.z - mean, d3 = v0.w - mean;
    float d4 = v1.x - mean, d5 = v1.y - mean, d6 = v1.z - mean, d7 = v1.w - mean;
    float vs = d0*d0 + d1*d1 + d2*d2 + d3*d3 + d4*d4 + d5*d5 + d6*d6 + d7*d7;
    for (int o = 32; o; o >>= 1) vs += __shfl_xor(vs, o);
    float var = vs * (1.f / 512.f);
    float r = 1.f / sqrtf(var + 1e-5f);
    const float4* s4 = (const float4*)s;
    const float4* b4 = (const float4*)b;
    float4 sa = s4[lane * 2], sb = s4[lane * 2 + 1];
    float4 ba = b4[lane * 2], bb = b4[lane * 2 + 1];
    float4 o0, o1;
    o0.x = d0 * r * sa.x + ba.x; o0.y = d1 * r * sa.y + ba.y;
    o0.z = d2 * r * sa.z + ba.z; o0.w = d3 * r * sa.w + ba.w;
    o1.x = d4 * r * sb.x + bb.x; o1.y = d5 * r * sb.y + bb.y;
    o1.z = d6 * r * sb.z + bb.z; o1.w = d7 * r * sb.w + bb.w;
    float4* yr = (float4*)(y + row * D_);
    yr[lane * 2] = o0; yr[lane * 2 + 1] = o1;
}

// ---------------- GEMM: C[M=8192,512] = A[8192,512] @ W[512,512] + bias (+res) (relu) ----------------
template<bool RES, bool RELU>
__global__ __launch_bounds__(256) void gemm_kernel(const float* __restrict__ A,
                                                   const float* __restrict__ W,
                                                   const float* __restrict__ bias,
                                                   const float* __restrict__ res,
                                                   float* __restrict__ C) {
    __shared__ float As[16][68];   // [k][m], padded: 16B-aligned rows, spread banks
    __shared__ float Bs[16][68];   // [k][n]
    int tid = threadIdx.x;
    int bm = blockIdx.x, bn = blockIdx.y;
    const float* Ab = A + (size_t)bm * 64 * D_;
    int am = tid >> 2, ak = (tid & 3) << 2;       // A load: row am, k-chunk ak
    int wk = tid >> 4, wn = (tid & 15) << 2;      // B load: k row wk, n-chunk wn
    int trow = (tid >> 4) << 2, tcol = (tid & 15) << 2;
    float acc[4][4] = {};
    for (int k0 = 0; k0 < 512; k0 += 16) {
        float4 a4 = *(const float4*)(Ab + (size_t)am * D_ + k0 + ak);
        float4 b4 = *(const float4*)(W + (size_t)(k0 + wk) * D_ + bn * 64 + wn);
        __syncthreads();
        As[ak + 0][am] = a4.x; As[ak + 1][am] = a4.y;
        As[ak + 2][am] = a4.z; As[ak + 3][am] = a4.w;
        *(float4*)&Bs[wk][wn] = b4;
        __syncthreads();
#pragma unroll
        for (int kk = 0; kk < 16; kk++) {
            float4 av = *(const float4*)&As[kk][trow];
            float4 bv = *(const float4*)&Bs[kk][tcol];
            acc[0][0] += av.x * bv.x; acc[0][1] += av.x * bv.y; acc[0][2] += av.x * bv.z; acc[0][3] += av.x * bv.w;
            acc[1][0] += av.y * bv.x; acc[1][1] += av.y * bv.y; acc[1][2] += av.y * bv.z; acc[1][3] += av.y * bv.w;
            acc[2][0] += av.z * bv.x; acc[2][1] += av.z * bv.y; acc[2][2] += av.z * bv.z; acc[2][3] += av.z * bv.w;
            acc[3][0] += av.w * bv.x; acc[3][1] += av.w * bv.y; acc[3][2] += av.w * bv.z; acc[3][3] += av.w * bv.w;
        }
    }
    int row0 = bm * 64 + trow, col0 = bn * 64 + tcol;
    float4 bb = *(const float4*)(bias + col0);
#pragma unroll
    for (int i = 0; i < 4; i++) {
        float4 o;
        o.x = acc[i][0] + bb.x; o.y = acc[i][1] + bb.y;
        o.z = acc[i][2] + bb.z; o.w = acc[i][3] + bb.w;
        if (RES) {
            float4 r = *(const float4*)(res + (size_t)(row0 + i) * D_ + col0);
            o.x += r.x; o.y += r.y; o.z += r.z; o.w += r.w;
        }
        if (RELU) {
            o.x = fmaxf(o.x, 0.f); o.y = fmaxf(o.y, 0.f);
            o.z = fmaxf(o.z, 0.f); o.w = fmaxf(o.w, 0.f);
        }
        *(float4*)(C + (size_t)(row0 + i) * D_ + col0) = o;
    }
}

// ---------------- fused attention: one block per (b,h); thread owns one q row ----------------
__global__ __launch_bounds__(256) void attn_kernel(const float* __restrict__ q,
                                                   const float* __restrict__ k,
                                                   const float* __restrict__ v,
                                                   float* __restrict__ o) {
    __shared__ float Ks[256][64];
    __shared__ float Vs[256][64];
    int bh = blockIdx.x;
    int b = bh >> 3, h = bh & 7;
    const size_t base = ((size_t)b * T_) * D_ + (size_t)h * DK_;
    int tid = threadIdx.x;
    // stage K,V tiles (row-major 256x64) into LDS
#pragma unroll
    for (int it = 0; it < 16; it++) {
        int idx = it * 256 + tid;
        int row = idx >> 4, ch = (idx & 15) << 2;
        *(float4*)&Ks[row][ch] = *(const float4*)(k + base + (size_t)row * D_ + ch);
        *(float4*)&Vs[row][ch] = *(const float4*)(v + base + (size_t)row * D_ + ch);
    }
    float4 qr[16];
    const float* qp = q + base + (size_t)tid * D_;
#pragma unroll
    for (int i = 0; i < 16; i++) qr[i] = ((const float4*)qp)[i];
    __syncthreads();
    // pass 1: row max of scores
    float mx = -1e30f;
    for (int j = 0; j < 256; j++) {
        float s = 0.f;
#pragma unroll
        for (int i = 0; i < 16; i++) {
            float4 kk = *(const float4*)&Ks[j][i * 4];
            s += qr[i].x * kk.x + qr[i].y * kk.y + qr[i].z * kk.z + qr[i].w * kk.w;
        }
        mx = fmaxf(mx, s * 0.125f);
    }
    // pass 2: exp-weighted sum of V
    float lsum = 0.f;
    float4 ov[16];
#pragma unroll
    for (int i = 0; i < 16; i++) { ov[i].x = 0.f; ov[i].y = 0.f; ov[i].z = 0.f; ov[i].w = 0.f; }
    for (int j = 0; j < 256; j++) {
        float s = 0.f;
#pragma unroll
        for (int i = 0; i < 16; i++) {
            float4 kk = *(const float4*)&Ks[j][i * 4];
            s += qr[i].x * kk.x + qr[i].y * kk.y + qr[i].z * kk.z + qr[i].w * kk.w;
        }
        float e = __expf(s * 0.125f - mx);
        lsum += e;
#pragma unroll
        for (int i = 0; i < 16; i++) {
            float4 vv = *(const float4*)&Vs[j][i * 4];
            ov[i].x += e * vv.x; ov[i].y += e * vv.y;
            ov[i].z += e * vv.z; ov[i].w += e * vv.w;
        }
    }
    float inv = 1.f / lsum;
    float* op = o + base + (size_t)tid * D_;
#pragma unroll
    for (int i = 0; i < 16; i++) {
        float4 w;
        w.x = ov[i].x * inv; w.y = ov[i].y * inv;
        w.z = ov[i].z * inv; w.w = ov[i].w * inv;
        ((float4*)op)[i] = w;
    }
}

// ---------------- PVAM head: block per (b,m) ----------------
__global__ __launch_bounds__(256) void pvam_kernel(const float* __restrict__ wf,
                                                   const int* __restrict__ gpos,
                                                   const float* __restrict__ emb,
                                                   const float* __restrict__ w1,
                                                   float* __restrict__ out) {
    __shared__ float wp[512];
    __shared__ float w1s[512];
    __shared__ float sc[256];
    __shared__ float red[4];
    int bm = blockIdx.x;
    int b = bm / ML_, m = bm - b * ML_;
    int tid = threadIdx.x;
    if (tid < 128) {
        int mrow = gpos[m];
        ((float4*)wp)[tid] = ((const float4*)(emb + (size_t)mrow * D_))[tid];
    } else {
        ((float4*)w1s)[tid - 128] = ((const float4*)w1)[tid - 128];
    }
    __syncthreads();
    const float* wfb = wf + (size_t)b * T_ * D_;
    const float* wr = wfb + (size_t)tid * D_;
    float s = 0.f;
#pragma unroll 4
    for (int c = 0; c < 512; c += 4) {
        float4 v = *(const float4*)(wr + c);
        s += tanhf(v.x + wp[c + 0]) * w1s[c + 0];
        s += tanhf(v.y + wp[c + 1]) * w1s[c + 1];
        s += tanhf(v.z + wp[c + 2]) * w1s[c + 2];
        s += tanhf(v.w + wp[c + 3]) * w1s[c + 3];
    }
    // softmax over the 256 threads' scores
    float mx = s;
    for (int o = 32; o; o >>= 1) mx = fmaxf(mx, __shfl_xor(mx, o));
    if ((tid & 63) == 0) red[tid >> 6] = mx;
    __syncthreads();
    mx = fmaxf(fmaxf(red[0], red[1]), fmaxf(red[2], red[3]));
    float e = __expf(s - mx);
    float sum = e;
    for (int o = 32; o; o >>= 1) sum += __shfl_xor(sum, o);
    __syncthreads();
    if ((tid & 63) == 0) red[tid >> 6] = sum;
    __syncthreads();
    sum = red[0] + red[1] + red[2] + red[3];
    sc[tid] = e / sum;
    __syncthreads();
    // out[b,m,c] = sum_t attn[t] * wf[b,t,c]; thread owns c=tid and c=tid+256
    float a0 = 0.f, a1 = 0.f;
    for (int t = 0; t < 256; t++) {
        float a = sc[t];
        a0 += a * wfb[(size_t)t * D_ + tid];
        a1 += a * wfb[(size_t)t * D_ + tid + 256];
    }
    float* op = out + (size_t)bm * D_;
    op[tid] = a0;
    op[tid + 256] = a1;
}

extern "C" void kernel_launch(void* const* d_in, const int* in_sizes, int n_in,
                              void* d_out, int out_size, void* d_ws, size_t ws_size,
                              hipStream_t stream) {
    (void)in_sizes; (void)n_in; (void)out_size; (void)ws_size;
    const float* x        = (const float*)d_in[0];
    const int*   epos     = (const int*)d_in[1];
    const int*   gpos     = (const int*)d_in[2];
    const float* pos_tab  = (const float*)d_in[3];
    const float* ln1_s    = (const float*)d_in[4];
    const float* ln1_b    = (const float*)d_in[5];
    const float* Wq       = (const float*)d_in[6];
    const float* bq       = (const float*)d_in[7];
    const float* Wk       = (const float*)d_in[8];
    const float* bk       = (const float*)d_in[9];
    const float* Wv       = (const float*)d_in[10];
    const float* bv       = (const float*)d_in[11];
    const float* Wo       = (const float*)d_in[12];
    const float* bo       = (const float*)d_in[13];
    const float* ln2_s    = (const float*)d_in[14];
    const float* ln2_b    = (const float*)d_in[15];
    const float* W1       = (const float*)d_in[16];
    const float* b1       = (const float*)d_in[17];
    const float* W2       = (const float*)d_in[18];
    const float* b2       = (const float*)d_in[19];
    const float* lnf_s    = (const float*)d_in[20];
    const float* lnf_b    = (const float*)d_in[21];
    const float* fc0_w    = (const float*)d_in[22];
    const float* fc0_b    = (const float*)d_in[23];
    const float* emb      = (const float*)d_in[24];
    const float* fc1_w    = (const float*)d_in[25];

    const size_t NBUF = (size_t)B_ * T_ * D_;   // 4,194,304 floats = 16.78 MB
    float* ws  = (float*)d_ws;
    float* enc = ws;
    float* t0  = ws + NBUF;
    float* q   = ws + 2 * NBUF;
    float* kk  = ws + 3 * NBUF;
    float* vv  = ws + 4 * NBUF;

    dim3 gg(128, 8);   // 8192/64 x 512/64

    prep_kernel<<<16384, 256, 0, stream>>>(x, epos, pos_tab, enc);

    for (int l = 0; l < 2; l++) {
        size_t o1 = (size_t)l * D_;
        size_t o2 = (size_t)l * D_ * D_;
        ln_kernel<<<2048, 256, 0, stream>>>(enc, ln1_s + o1, ln1_b + o1, t0);
        gemm_kernel<false, false><<<gg, 256, 0, stream>>>(t0, Wq + o2, bq + o1, nullptr, q);
        gemm_kernel<false, false><<<gg, 256, 0, stream>>>(t0, Wk + o2, bk + o1, nullptr, kk);
        gemm_kernel<false, false><<<gg, 256, 0, stream>>>(t0, Wv + o2, bv + o1, nullptr, vv);
        attn_kernel<<<256, 256, 0, stream>>>(q, kk, vv, t0);
        gemm_kernel<true, false><<<gg, 256, 0, stream>>>(t0, Wo + o2, bo + o1, enc, enc);
        ln_kernel<<<2048, 256, 0, stream>>>(enc, ln2_s + o1, ln2_b + o1, t0);
        gemm_kernel<false, true><<<gg, 256, 0, stream>>>(t0, W1 + o2, b1 + o1, nullptr, q);
        gemm_kernel<true, false><<<gg, 256, 0, stream>>>(q, W2 + o2, b2 + o1, enc, enc);
    }

    ln_kernel<<<2048, 256, 0, stream>>>(enc, lnf_s, lnf_b, t0);
    gemm_kernel<false, false><<<gg, 256, 0, stream>>>(t0, fc0_w, fc0_b, nullptr, q);
    pvam_kernel<<<B_ * ML_, 256, 0, stream>>>(q, gpos, emb, fc1_w, (float*)d_out);
}

// Round 2
// 408.368 us; speedup vs baseline: 3.8258x; 3.8258x over previous
//
#include <hip/hip_runtime.h>
#include <math.h>

#define B_ 32
#define D_ 512
#define T_ 256
#define NH_ 8
#define DK_ 64
#define ML_ 25

typedef unsigned short ushort_t;
using short8 = __attribute__((ext_vector_type(8))) short;
using f32x4  = __attribute__((ext_vector_type(4))) float;

__device__ __forceinline__ ushort_t f2bf(float f) {
    unsigned u = __float_as_uint(f);
    unsigned r = (u + 0x7fffu + ((u >> 16) & 1u)) >> 16;
    return (ushort_t)r;
}
__device__ __forceinline__ float bf2f(ushort_t h) {
    return __uint_as_float(((unsigned)h) << 16);
}
__device__ __forceinline__ void gl16(const void* g, void* l) {
    __builtin_amdgcn_global_load_lds((const __attribute__((address_space(1))) void*)g,
                                     (__attribute__((address_space(3))) void*)l, 16, 0, 0);
}
#define ZERO4(v) { (v)[0]=0.f; (v)[1]=0.f; (v)[2]=0.f; (v)[3]=0.f; }

// ---------------- prep: enc[b,t,c] = x[b,c,t]*sqrt(512) + pos[epos[t],c]  (LDS transpose) ----------------
__global__ __launch_bounds__(256) void prep_kernel(const float* __restrict__ x,
                                                   const int* __restrict__ epos,
                                                   const float* __restrict__ pos,
                                                   float* __restrict__ enc) {
    __shared__ float ld[64][65];
    int tt = blockIdx.x, ct = blockIdx.y, b = blockIdx.z;
    int t0 = tt * 64, c0 = ct * 64;
    int tid = threadIdx.x;
    int r = tid >> 4, c4 = (tid & 15) << 2;
#pragma unroll
    for (int p = 0; p < 4; p++) {
        int row = p * 16 + r;  // channel within tile
        float4 v = *(const float4*)(x + ((size_t)(b * D_ + c0 + row) * T_ + t0) + c4);
        ld[row][c4 + 0] = v.x; ld[row][c4 + 1] = v.y; ld[row][c4 + 2] = v.z; ld[row][c4 + 3] = v.w;
    }
    __syncthreads();
#pragma unroll
    for (int p = 0; p < 4; p++) {
        int tr = p * 16 + r;   // token within tile
        int ep = epos[t0 + tr];
        float4 pv = *(const float4*)(pos + (size_t)ep * D_ + c0 + c4);
        float4 o;
        o.x = ld[c4 + 0][tr] * 22.627417f + pv.x;
        o.y = ld[c4 + 1][tr] * 22.627417f + pv.y;
        o.z = ld[c4 + 2][tr] * 22.627417f + pv.z;
        o.w = ld[c4 + 3][tr] * 22.627417f + pv.w;
        *(float4*)(enc + (size_t)(b * T_ + t0 + tr) * D_ + c0 + c4) = o;
    }
}

// ---------------- weight convert: WT[n][k] = bf16(W[k][n]); fc0 also lo ----------------
__global__ __launch_bounds__(256) void convert_w_kernel(const float* __restrict__ Wq,
                                                        const float* __restrict__ Wk,
                                                        const float* __restrict__ Wv,
                                                        const float* __restrict__ Wo,
                                                        const float* __restrict__ W1,
                                                        const float* __restrict__ W2,
                                                        const float* __restrict__ fc0,
                                                        ushort_t* __restrict__ wt) {
    __shared__ float ld[64][65];
    int m = blockIdx.x >> 6;
    int tile = blockIdx.x & 63;
    int tn = tile >> 3, tk = tile & 7;
    int n0 = tn * 64, k0 = tk * 64;
    const float* src;
    if (m < 12) {
        int l = m / 6, w = m % 6;
        const float* bases[6] = {Wq, Wk, Wv, Wo, W1, W2};
        src = bases[w] + (size_t)l * D_ * D_;
    } else {
        src = fc0;
    }
    int tid = threadIdx.x;
    int r = tid >> 4, c4 = (tid & 15) << 2;
#pragma unroll
    for (int p = 0; p < 4; p++) {
        int row = p * 16 + r;  // k index
        float4 v = *(const float4*)(src + (size_t)(k0 + row) * D_ + n0 + c4);
        ld[row][c4 + 0] = v.x; ld[row][c4 + 1] = v.y; ld[row][c4 + 2] = v.z; ld[row][c4 + 3] = v.w;
    }
    __syncthreads();
    ushort_t* dsth = wt + (size_t)m * D_ * D_;
    ushort_t* dstl = wt + (size_t)13 * D_ * D_;
#pragma unroll
    for (int p = 0; p < 4; p++) {
        int n = p * 16 + r;
        int kc = c4;
        ushort_t h[4], lo[4];
#pragma unroll
        for (int i = 0; i < 4; i++) {
            float f = ld[kc + i][n];
            h[i] = f2bf(f);
            lo[i] = f2bf(f - bf2f(h[i]));
        }
        *(ushort4*)(dsth + (size_t)(n0 + n) * D_ + k0 + kc) = make_ushort4(h[0], h[1], h[2], h[3]);
        if (m == 12)
            *(ushort4*)(dstl + (size_t)(n0 + n) * D_ + k0 + kc) = make_ushort4(lo[0], lo[1], lo[2], lo[3]);
    }
}

// ---------------- LayerNorm -> bf16 hi (+lo) ----------------
template<bool LO>
__global__ __launch_bounds__(256) void ln_kernel(const float* __restrict__ x,
                                                 const float* __restrict__ s,
                                                 const float* __restrict__ b,
                                                 ushort_t* __restrict__ yh,
                                                 ushort_t* __restrict__ yl) {
    int wid = threadIdx.x >> 6, lane = threadIdx.x & 63;
    size_t row = (size_t)blockIdx.x * 4 + wid;
    const float4* xr = (const float4*)(x + row * D_);
    float4 v0 = xr[lane * 2], v1 = xr[lane * 2 + 1];
    float sum = v0.x + v0.y + v0.z + v0.w + v1.x + v1.y + v1.z + v1.w;
    for (int o = 32; o; o >>= 1) sum += __shfl_xor(sum, o);
    float mean = sum * (1.f / 512.f);
    float d[8] = {v0.x - mean, v0.y - mean, v0.z - mean, v0.w - mean,
                  v1.x - mean, v1.y - mean, v1.z - mean, v1.w - mean};
    float vs = 0.f;
#pragma unroll
    for (int i = 0; i < 8; i++) vs += d[i] * d[i];
    for (int o = 32; o; o >>= 1) vs += __shfl_xor(vs, o);
    float rs = 1.f / sqrtf(vs * (1.f / 512.f) + 1e-5f);
    const float4* s4 = (const float4*)s;
    const float4* b4 = (const float4*)b;
    float4 sa = s4[lane * 2], sb = s4[lane * 2 + 1];
    float4 ba = b4[lane * 2], bb = b4[lane * 2 + 1];
    float o8[8];
    o8[0] = d[0] * rs * sa.x + ba.x; o8[1] = d[1] * rs * sa.y + ba.y;
    o8[2] = d[2] * rs * sa.z + ba.z; o8[3] = d[3] * rs * sa.w + ba.w;
    o8[4] = d[4] * rs * sb.x + bb.x; o8[5] = d[5] * rs * sb.y + bb.y;
    o8[6] = d[6] * rs * sb.z + bb.z; o8[7] = d[7] * rs * sb.w + bb.w;
    ushort_t h[8];
#pragma unroll
    for (int i = 0; i < 8; i++) h[i] = f2bf(o8[i]);
    uint4 u;
    u.x = (unsigned)h[0] | ((unsigned)h[1] << 16);
    u.y = (unsigned)h[2] | ((unsigned)h[3] << 16);
    u.z = (unsigned)h[4] | ((unsigned)h[5] << 16);
    u.w = (unsigned)h[6] | ((unsigned)h[7] << 16);
    *(uint4*)(yh + row * D_ + lane * 8) = u;
    if (LO) {
        ushort_t l8[8];
#pragma unroll
        for (int i = 0; i < 8; i++) l8[i] = f2bf(o8[i] - bf2f(h[i]));
        uint4 ul;
        ul.x = (unsigned)l8[0] | ((unsigned)l8[1] << 16);
        ul.y = (unsigned)l8[2] | ((unsigned)l8[3] << 16);
        ul.z = (unsigned)l8[4] | ((unsigned)l8[5] << 16);
        ul.w = (unsigned)l8[6] | ((unsigned)l8[7] << 16);
        *(uint4*)(yl + row * D_ + lane * 8) = ul;
    }
}

// ---------------- MFMA GEMM: C[8192,512] = sum_seg A_seg[8192,512] * WT_seg[512,512]^T ----------------
// EPI: 0=bf16(+bias), 1=bf16 transposed->vt, 2=f32(+bias+res), 3=relu->bf16, 4=f32(+bias)
template<int EPI>
__global__ __launch_bounds__(256) void gemm_kernel(const ushort_t* __restrict__ A0,
                                                   const ushort_t* __restrict__ A1,
                                                   const ushort_t* __restrict__ A2,
                                                   const ushort_t* __restrict__ B0,
                                                   const ushort_t* __restrict__ B1,
                                                   const ushort_t* __restrict__ B2,
                                                   int nseg,
                                                   const float* __restrict__ bias,
                                                   const float* __restrict__ res,
                                                   float* __restrict__ outF,
                                                   ushort_t* __restrict__ outB) {
    __shared__ ushort_t As[2][128 * 64];
    __shared__ ushort_t Bs[2][128 * 64];
    int tid = threadIdx.x;
    // XCD-chunked swizzle: same-XCD blocks share the A slab
    int g = blockIdx.x;
    int lin = (g & 7) * 32 + (g >> 3);
    int bm = lin >> 2, bn = lin & 3;

    int lane = tid & 63;
    int wid = tid >> 6;
    int wm = wid >> 1, wn = wid & 1;

    f32x4 acc[4][4];
#pragma unroll
    for (int i = 0; i < 4; i++)
#pragma unroll
        for (int j = 0; j < 4; j++) ZERO4(acc[i][j]);

    int nt = nseg * 8;

#define STAGE(kt, buf)                                                                  \
    {                                                                                   \
        int seg_ = (kt) >> 3;                                                           \
        int k0_ = ((kt) & 7) * 64;                                                      \
        const ushort_t* Asg = seg_ == 0 ? A0 : (seg_ == 1 ? A1 : A2);                   \
        const ushort_t* Bsg = seg_ == 0 ? B0 : (seg_ == 1 ? B1 : B2);                   \
        _Pragma("unroll")                                                               \
        for (int it = 0; it < 4; it++) {                                                \
            int uu = tid + it * 256;                                                    \
            int row_ = uu >> 3;                                                         \
            int kb_ = (uu & 7) * 8;                                                     \
            gl16(Asg + (size_t)(bm * 128 + row_) * 512 + k0_ + kb_, &As[buf][uu * 8]);  \
            gl16(Bsg + (size_t)(bn * 128 + row_) * 512 + k0_ + kb_, &Bs[buf][uu * 8]);  \
        }                                                                               \
    }

    STAGE(0, 0);
    asm volatile("s_waitcnt vmcnt(0)" ::: "memory");
    __syncthreads();

    int buf = 0;
    for (int t = 0; t < nt; t++) {
        if (t + 1 < nt) STAGE(t + 1, buf ^ 1);
#pragma unroll
        for (int kc = 0; kc < 2; kc++) {
            short8 a[4], b[4];
#pragma unroll
            for (int i = 0; i < 4; i++)
                a[i] = *(const short8*)&As[buf][(wm * 64 + i * 16 + (lane & 15)) * 64 + kc * 32 + ((lane >> 4) << 3)];
#pragma unroll
            for (int j = 0; j < 4; j++)
                b[j] = *(const short8*)&Bs[buf][(wn * 64 + j * 16 + (lane & 15)) * 64 + kc * 32 + ((lane >> 4) << 3)];
#pragma unroll
            for (int i = 0; i < 4; i++)
#pragma unroll
                for (int j = 0; j < 4; j++)
                    acc[i][j] = __builtin_amdgcn_mfma_f32_16x16x32_bf16(a[i], b[j], acc[i][j], 0, 0, 0);
        }
        asm volatile("s_waitcnt vmcnt(0)" ::: "memory");
        __syncthreads();
        buf ^= 1;
    }
#undef STAGE

#pragma unroll
    for (int i = 0; i < 4; i++) {
#pragma unroll
        for (int j = 0; j < 4; j++) {
            int r0 = bm * 128 + wm * 64 + i * 16 + ((lane >> 4) << 2);
            int col = bn * 128 + wn * 64 + j * 16 + (lane & 15);
            float bc = bias[col];
#pragma unroll
            for (int jj = 0; jj < 4; jj++) {
                float v = acc[i][j][jj] + bc;
                int row = r0 + jj;
                size_t idx = (size_t)row * 512 + col;
                if (EPI == 0) {
                    outB[idx] = f2bf(v);
                } else if (EPI == 1) {
                    int bb = row >> 8, t = row & 255;
                    outB[((size_t)(bb * 8 + (col >> 6)) * 64 + (col & 63)) * 256 + t] = f2bf(v);
                } else if (EPI == 2) {
                    outF[idx] = v + res[idx];
                } else if (EPI == 3) {
                    outB[idx] = f2bf(fmaxf(v, 0.f));
                } else {
                    outF[idx] = v;
                }
            }
        }
    }
}

// ---------------- attn S = softmax(Q K^T / 8): block = 128 q-rows x all 256 keys ----------------
__global__ __launch_bounds__(256) void sgemm_sm_kernel(const ushort_t* __restrict__ q,
                                                       const ushort_t* __restrict__ k,
                                                       ushort_t* __restrict__ P,
                                                       int bh0) {
    __shared__ ushort_t Qs[128 * 64];
    __shared__ ushort_t Ks[256 * 64];
    int tid = threadIdx.x;
    int m0 = blockIdx.x * 128;
    int bhl = blockIdx.y;
    int bh = bh0 + bhl;
    int b = bh >> 3, h = bh & 7;
    // stage Q tile (128x64) and K tile (256x64)
#pragma unroll
    for (int it = 0; it < 4; it++) {
        int uu = tid + it * 256;
        int row = uu >> 3, kb = (uu & 7) * 8;
        gl16(q + (size_t)(b * T_ + m0 + row) * D_ + h * DK_ + kb, &Qs[uu * 8]);
    }
#pragma unroll
    for (int it = 0; it < 8; it++) {
        int uu = tid + it * 256;
        int row = uu >> 3, kb = (uu & 7) * 8;
        gl16(k + (size_t)(b * T_ + row) * D_ + h * DK_ + kb, &Ks[uu * 8]);
    }
    asm volatile("s_waitcnt vmcnt(0)" ::: "memory");
    __syncthreads();

    int lane = tid & 63;
    int wid = tid >> 6;
    int wm = wid >> 1, wn = wid & 1;

    f32x4 acc[4][8];
#pragma unroll
    for (int i = 0; i < 4; i++)
#pragma unroll
        for (int j = 0; j < 8; j++) ZERO4(acc[i][j]);

    short8 a[4][2];
#pragma unroll
    for (int i = 0; i < 4; i++)
#pragma unroll
        for (int kc = 0; kc < 2; kc++)
            a[i][kc] = *(const short8*)&Qs[(wm * 64 + i * 16 + (lane & 15)) * 64 + kc * 32 + ((lane >> 4) << 3)];
#pragma unroll
    for (int j = 0; j < 8; j++) {
        short8 b0 = *(const short8*)&Ks[(wn * 128 + j * 16 + (lane & 15)) * 64 + ((lane >> 4) << 3)];
        short8 b1 = *(const short8*)&Ks[(wn * 128 + j * 16 + (lane & 15)) * 64 + 32 + ((lane >> 4) << 3)];
#pragma unroll
        for (int i = 0; i < 4; i++) {
            acc[i][j] = __builtin_amdgcn_mfma_f32_16x16x32_bf16(a[i][0], b0, acc[i][j], 0, 0, 0);
            acc[i][j] = __builtin_amdgcn_mfma_f32_16x16x32_bf16(a[i][1], b1, acc[i][j], 0, 0, 0);
        }
    }
    // softmax per q-row; lane holds col (lane&15) of rows (lane>>4)*4+jj; full row = 8 j-frags x 16 lanes
    const float C = 0.125f * 1.44269504f;  // scale * log2(e)
#pragma unroll
    for (int i = 0; i < 4; i++) {
        float mx[4] = {-1e30f, -1e30f, -1e30f, -1e30f};
#pragma unroll
        for (int j = 0; j < 8; j++)
#pragma unroll
            for (int jj = 0; jj < 4; jj++) mx[jj] = fmaxf(mx[jj], acc[i][j][jj]);
#pragma unroll
        for (int m = 1; m < 16; m <<= 1)
#pragma unroll
            for (int jj = 0; jj < 4; jj++) mx[jj] = fmaxf(mx[jj], __shfl_xor(mx[jj], m));
        float sm[4] = {0.f, 0.f, 0.f, 0.f};
#pragma unroll
        for (int j = 0; j < 8; j++)
#pragma unroll
            for (int jj = 0; jj < 4; jj++) {
                float e = exp2f((acc[i][j][jj] - mx[jj]) * C);
                acc[i][j][jj] = e;
                sm[jj] += e;
            }
#pragma unroll
        for (int m = 1; m < 16; m <<= 1)
#pragma unroll
            for (int jj = 0; jj < 4; jj++) sm[jj] += __shfl_xor(sm[jj], m);
        float inv[4];
#pragma unroll
        for (int jj = 0; jj < 4; jj++) inv[jj] = 1.f / sm[jj];
#pragma unroll
        for (int j = 0; j < 8; j++) {
            int row0 = m0 + wm * 64 + i * 16 + ((lane >> 4) << 2);
            int col = wn * 128 + j * 16 + (lane & 15);
#pragma unroll
            for (int jj = 0; jj < 4; jj++)
                P[((size_t)bhl * T_ + row0 + jj) * T_ + col] = f2bf(acc[i][j][jj] * inv[jj]);
        }
    }
}

// ---------------- attn O = P V  (V pre-transposed [bh][dk][t]) ----------------
__global__ __launch_bounds__(256) void pv_kernel(const ushort_t* __restrict__ P,
                                                 const ushort_t* __restrict__ vt,
                                                 ushort_t* __restrict__ ao,
                                                 int bh0) {
    __shared__ ushort_t Ps[2][64 * 64];
    __shared__ ushort_t Vs[2][64 * 64];
    int tid = threadIdx.x;
    int m0 = blockIdx.x * 64;
    int bhl = blockIdx.y;
    int bh = bh0 + bhl;
    int b = bh >> 3, h = bh & 7;
    int lane = tid & 63;
    int wid = tid >> 6;
    int wm = wid >> 1, wn = wid & 1;

    f32x4 acc[2][2];
#pragma unroll
    for (int i = 0; i < 2; i++)
#pragma unroll
        for (int j = 0; j < 2; j++) ZERO4(acc[i][j]);

#define PVSTAGE(kt, buf)                                                                  \
    {                                                                                     \
        _Pragma("unroll")                                                                 \
        for (int it = 0; it < 2; it++) {                                                  \
            int uu = tid + it * 256;                                                      \
            int row_ = uu >> 3, kb_ = (uu & 7) * 8;                                       \
            gl16(P + ((size_t)bhl * T_ + m0 + row_) * T_ + (kt) * 64 + kb_, &Ps[buf][uu * 8]); \
            gl16(vt + ((size_t)bh * DK_ + row_) * T_ + (kt) * 64 + kb_, &Vs[buf][uu * 8]);     \
        }                                                                                 \
    }

    PVSTAGE(0, 0);
    asm volatile("s_waitcnt vmcnt(0)" ::: "memory");
    __syncthreads();
    int buf = 0;
    for (int t = 0; t < 4; t++) {
        if (t + 1 < 4) PVSTAGE(t + 1, buf ^ 1);
#pragma unroll
        for (int kc = 0; kc < 2; kc++) {
            short8 a[2], bb[2];
#pragma unroll
            for (int i = 0; i < 2; i++)
                a[i] = *(const short8*)&Ps[buf][(wm * 32 + i * 16 + (lane & 15)) * 64 + kc * 32 + ((lane >> 4) << 3)];
#pragma unroll
            for (int j = 0; j < 2; j++)
                bb[j] = *(const short8*)&Vs[buf][(wn * 32 + j * 16 + (lane & 15)) * 64 + kc * 32 + ((lane >> 4) << 3)];
#pragma unroll
            for (int i = 0; i < 2; i++)
#pragma unroll
                for (int j = 0; j < 2; j++)
                    acc[i][j] = __builtin_amdgcn_mfma_f32_16x16x32_bf16(a[i], bb[j], acc[i][j], 0, 0, 0);
        }
        asm volatile("s_waitcnt vmcnt(0)" ::: "memory");
        __syncthreads();
        buf ^= 1;
    }
#undef PVSTAGE

#pragma unroll
    for (int i = 0; i < 2; i++)
#pragma unroll
        for (int j = 0; j < 2; j++) {
            int r0 = m0 + wm * 32 + i * 16 + ((lane >> 4) << 2);
            int col = h * DK_ + wn * 32 + j * 16 + (lane & 15);
#pragma unroll
            for (int jj = 0; jj < 4; jj++)
                ao[(size_t)(b * T_ + r0 + jj) * D_ + col] = f2bf(acc[i][j][jj]);
        }
}

// ---------------- PVAM head ----------------
__device__ __forceinline__ float fast_tanh(float x) {
    x = fminf(10.f, fmaxf(-10.f, x));
    float a = exp2f(x * 2.885390082f);           // e^(2x)
    return (a - 1.f) * __builtin_amdgcn_rcpf(a + 1.f);
}

__global__ __launch_bounds__(256) void pvam_kernel(const float* __restrict__ wf,
                                                   const int* __restrict__ gpos,
                                                   const float* __restrict__ emb,
                                                   const float* __restrict__ w1,
                                                   float* __restrict__ out) {
    __shared__ float wp[512];
    __shared__ float w1s[512];
    __shared__ float sc[256];
    __shared__ float red[4];
    int bm = blockIdx.x;
    int b = bm / ML_, m = bm - b * ML_;
    int tid = threadIdx.x;
    if (tid < 128) {
        int mrow = gpos[m];
        ((float4*)wp)[tid] = ((const float4*)(emb + (size_t)mrow * D_))[tid];
    } else {
        ((float4*)w1s)[tid - 128] = ((const float4*)w1)[tid - 128];
    }
    __syncthreads();
    const float* wfb = wf + (size_t)b * T_ * D_;
    const float* wr = wfb + (size_t)tid * D_;
    float s = 0.f;
#pragma unroll 4
    for (int c = 0; c < 512; c += 4) {
        float4 v = *(const float4*)(wr + c);
        s += fast_tanh(v.x + wp[c + 0]) * w1s[c + 0];
        s += fast_tanh(v.y + wp[c + 1]) * w1s[c + 1];
        s += fast_tanh(v.z + wp[c + 2]) * w1s[c + 2];
        s += fast_tanh(v.w + wp[c + 3]) * w1s[c + 3];
    }
    float mx = s;
    for (int o = 32; o; o >>= 1) mx = fmaxf(mx, __shfl_xor(mx, o));
    if ((tid & 63) == 0) red[tid >> 6] = mx;
    __syncthreads();
    mx = fmaxf(fmaxf(red[0], red[1]), fmaxf(red[2], red[3]));
    float e = __expf(s - mx);
    float sum = e;
    for (int o = 32; o; o >>= 1) sum += __shfl_xor(sum, o);
    __syncthreads();
    if ((tid & 63) == 0) red[tid >> 6] = sum;
    __syncthreads();
    sum = red[0] + red[1] + red[2] + red[3];
    sc[tid] = e / sum;
    __syncthreads();
    float a0 = 0.f, a1 = 0.f;
    for (int t = 0; t < 256; t++) {
        float a = sc[t];
        a0 += a * wfb[(size_t)t * D_ + tid];
        a1 += a * wfb[(size_t)t * D_ + tid + 256];
    }
    float* op = out + (size_t)bm * D_;
    op[tid] = a0;
    op[tid + 256] = a1;
}

extern "C" void kernel_launch(void* const* d_in, const int* in_sizes, int n_in,
                              void* d_out, int out_size, void* d_ws, size_t ws_size,
                              hipStream_t stream) {
    (void)in_sizes; (void)n_in; (void)out_size; (void)ws_size;
    const float* x        = (const float*)d_in[0];
    const int*   epos     = (const int*)d_in[1];
    const int*   gpos     = (const int*)d_in[2];
    const float* pos_tab  = (const float*)d_in[3];
    const float* ln1_s    = (const float*)d_in[4];
    const float* ln1_b    = (const float*)d_in[5];
    const float* Wq       = (const float*)d_in[6];
    const float* bq       = (const float*)d_in[7];
    const float* Wk       = (const float*)d_in[8];
    const float* bk       = (const float*)d_in[9];
    const float* Wv       = (const float*)d_in[10];
    const float* bv       = (const float*)d_in[11];
    const float* Wo       = (const float*)d_in[12];
    const float* bo       = (const float*)d_in[13];
    const float* ln2_s    = (const float*)d_in[14];
    const float* ln2_b    = (const float*)d_in[15];
    const float* W1       = (const float*)d_in[16];
    const float* b1       = (const float*)d_in[17];
    const float* W2       = (const float*)d_in[18];
    const float* b2       = (const float*)d_in[19];
    const float* lnf_s    = (const float*)d_in[20];
    const float* lnf_b    = (const float*)d_in[21];
    const float* fc0_w    = (const float*)d_in[22];
    const float* fc0_b    = (const float*)d_in[23];
    const float* emb      = (const float*)d_in[24];
    const float* fc1_w    = (const float*)d_in[25];

    char* ws = (char*)d_ws;
    float*    enc = (float*)(ws);                       // 16.78 MB
    ushort_t* hi  = (ushort_t*)(ws + 16777216);         // 8.39 MB
    ushort_t* qb  = (ushort_t*)(ws + 25165824);         // 8.39 MB
    ushort_t* kb  = (ushort_t*)(ws + 33554432);         // 8.39 MB (lo overlays later)
    ushort_t* lo  = (ushort_t*)(ws + 33554432);
    ushort_t* vt  = (ushort_t*)(ws + 41943040);         // 8.39 MB (h1 overlays later)
    ushort_t* h1  = (ushort_t*)(ws + 41943040);
    ushort_t* ao  = (ushort_t*)(ws + 50331648);         // 8.39 MB
    ushort_t* P   = (ushort_t*)(ws + 58720256);         // 16.78 MB half-batch (wf overlays)
    float*    wf  = (float*)(ws + 58720256);
    ushort_t* wt  = (ushort_t*)(ws + 75497472);         // 7.34 MB (14 slices of 512KB)
    const size_t WSL = (size_t)D_ * D_;

    convert_w_kernel<<<13 * 64, 256, 0, stream>>>(Wq, Wk, Wv, Wo, W1, W2, fc0_w, wt);
    prep_kernel<<<dim3(4, 8, 32), 256, 0, stream>>>(x, epos, pos_tab, enc);

    for (int l = 0; l < 2; l++) {
        size_t o1 = (size_t)l * D_;
        const ushort_t* WqT = wt + (l * 6 + 0) * WSL;
        const ushort_t* WkT = wt + (l * 6 + 1) * WSL;
        const ushort_t* WvT = wt + (l * 6 + 2) * WSL;
        const ushort_t* WoT = wt + (l * 6 + 3) * WSL;
        const ushort_t* W1T = wt + (l * 6 + 4) * WSL;
        const ushort_t* W2T = wt + (l * 6 + 5) * WSL;

        ln_kernel<false><<<2048, 256, 0, stream>>>(enc, ln1_s + o1, ln1_b + o1, hi, nullptr);
        gemm_kernel<0><<<256, 256, 0, stream>>>(hi, nullptr, nullptr, WqT, nullptr, nullptr, 1, bq + o1, nullptr, nullptr, qb);
        gemm_kernel<0><<<256, 256, 0, stream>>>(hi, nullptr, nullptr, WkT, nullptr, nullptr, 1, bk + o1, nullptr, nullptr, kb);
        gemm_kernel<1><<<256, 256, 0, stream>>>(hi, nullptr, nullptr, WvT, nullptr, nullptr, 1, bv + o1, nullptr, nullptr, vt);
        for (int half = 0; half < 2; half++) {
            sgemm_sm_kernel<<<dim3(2, 128), 256, 0, stream>>>(qb, kb, P, half * 128);
            pv_kernel<<<dim3(4, 128), 256, 0, stream>>>(P, vt, ao, half * 128);
        }
        gemm_kernel<2><<<256, 256, 0, stream>>>(ao, nullptr, nullptr, WoT, nullptr, nullptr, 1, bo + o1, enc, enc, nullptr);
        ln_kernel<false><<<2048, 256, 0, stream>>>(enc, ln2_s + o1, ln2_b + o1, hi, nullptr);
        gemm_kernel<3><<<256, 256, 0, stream>>>(hi, nullptr, nullptr, W1T, nullptr, nullptr, 1, b1 + o1, nullptr, nullptr, h1);
        gemm_kernel<2><<<256, 256, 0, stream>>>(h1, nullptr, nullptr, W2T, nullptr, nullptr, 1, b2 + o1, enc, enc, nullptr);
    }

    ln_kernel<true><<<2048, 256, 0, stream>>>(enc, lnf_s, lnf_b, hi, lo);
    // fc0 split-bf16: Ah*Wh + Al*Wh + Ah*Wl
    gemm_kernel<4><<<256, 256, 0, stream>>>(hi, lo, hi, wt + 12 * WSL, wt + 12 * WSL, wt + 13 * WSL, 3,
                                            fc0_b, nullptr, wf, nullptr);
    pvam_kernel<<<B_ * ML_, 256, 0, stream>>>(wf, gpos, emb, fc1_w, (float*)d_out);
}

// Round 3
// 402.292 us; speedup vs baseline: 3.8835x; 1.0151x over previous
//
#include <hip/hip_runtime.h>
#include <math.h>

#define B_ 32
#define D_ 512
#define T_ 256
#define NH_ 8
#define DK_ 64
#define ML_ 25

typedef unsigned short ushort_t;
using short8 = __attribute__((ext_vector_type(8))) short;
using f32x4  = __attribute__((ext_vector_type(4))) float;

__device__ __forceinline__ ushort_t f2bf(float f) {
    unsigned u = __float_as_uint(f);
    unsigned r = (u + 0x7fffu + ((u >> 16) & 1u)) >> 16;
    return (ushort_t)r;
}
__device__ __forceinline__ float bf2f(ushort_t h) {
    return __uint_as_float(((unsigned)h) << 16);
}
__device__ __forceinline__ void gl16(const void* g, void* l) {
    __builtin_amdgcn_global_load_lds((const __attribute__((address_space(1))) void*)g,
                                     (__attribute__((address_space(3))) void*)l, 16, 0, 0);
}
#define ZERO4(v) { (v)[0]=0.f; (v)[1]=0.f; (v)[2]=0.f; (v)[3]=0.f; }

// ---------------- prep: enc[b,t,c] = x[b,c,t]*sqrt(512) + pos[epos[t],c]  (LDS transpose) ----------------
__global__ __launch_bounds__(256) void prep_kernel(const float* __restrict__ x,
                                                   const int* __restrict__ epos,
                                                   const float* __restrict__ pos,
                                                   float* __restrict__ enc) {
    __shared__ float ld[64][65];
    int tt = blockIdx.x, ct = blockIdx.y, b = blockIdx.z;
    int t0 = tt * 64, c0 = ct * 64;
    int tid = threadIdx.x;
    int r = tid >> 4, c4 = (tid & 15) << 2;
#pragma unroll
    for (int p = 0; p < 4; p++) {
        int row = p * 16 + r;  // channel within tile
        float4 v = *(const float4*)(x + ((size_t)(b * D_ + c0 + row) * T_ + t0) + c4);
        ld[row][c4 + 0] = v.x; ld[row][c4 + 1] = v.y; ld[row][c4 + 2] = v.z; ld[row][c4 + 3] = v.w;
    }
    __syncthreads();
#pragma unroll
    for (int p = 0; p < 4; p++) {
        int tr = p * 16 + r;   // token within tile
        int ep = epos[t0 + tr];
        float4 pv = *(const float4*)(pos + (size_t)ep * D_ + c0 + c4);
        float4 o;
        o.x = ld[c4 + 0][tr] * 22.627417f + pv.x;
        o.y = ld[c4 + 1][tr] * 22.627417f + pv.y;
        o.z = ld[c4 + 2][tr] * 22.627417f + pv.z;
        o.w = ld[c4 + 3][tr] * 22.627417f + pv.w;
        *(float4*)(enc + (size_t)(b * T_ + t0 + tr) * D_ + c0 + c4) = o;
    }
}

// ---------------- weight convert: WT[n][k] = bf16(W[k][n]); fc0 also lo ----------------
__global__ __launch_bounds__(256) void convert_w_kernel(const float* __restrict__ Wq,
                                                        const float* __restrict__ Wk,
                                                        const float* __restrict__ Wv,
                                                        const float* __restrict__ Wo,
                                                        const float* __restrict__ W1,
                                                        const float* __restrict__ W2,
                                                        const float* __restrict__ fc0,
                                                        ushort_t* __restrict__ wt) {
    __shared__ float ld[64][65];
    int m = blockIdx.x >> 6;
    int tile = blockIdx.x & 63;
    int tn = tile >> 3, tk = tile & 7;
    int n0 = tn * 64, k0 = tk * 64;
    const float* src;
    if (m < 12) {
        int l = m / 6, w = m % 6;
        const float* bases[6] = {Wq, Wk, Wv, Wo, W1, W2};
        src = bases[w] + (size_t)l * D_ * D_;
    } else {
        src = fc0;
    }
    int tid = threadIdx.x;
    int r = tid >> 4, c4 = (tid & 15) << 2;
#pragma unroll
    for (int p = 0; p < 4; p++) {
        int row = p * 16 + r;  // k index
        float4 v = *(const float4*)(src + (size_t)(k0 + row) * D_ + n0 + c4);
        ld[row][c4 + 0] = v.x; ld[row][c4 + 1] = v.y; ld[row][c4 + 2] = v.z; ld[row][c4 + 3] = v.w;
    }
    __syncthreads();
    ushort_t* dsth = wt + (size_t)m * D_ * D_;
    ushort_t* dstl = wt + (size_t)13 * D_ * D_;
#pragma unroll
    for (int p = 0; p < 4; p++) {
        int n = p * 16 + r;
        int kc = c4;
        ushort_t h[4], lo[4];
#pragma unroll
        for (int i = 0; i < 4; i++) {
            float f = ld[kc + i][n];
            h[i] = f2bf(f);
            lo[i] = f2bf(f - bf2f(h[i]));
        }
        *(ushort4*)(dsth + (size_t)(n0 + n) * D_ + k0 + kc) = make_ushort4(h[0], h[1], h[2], h[3]);
        if (m == 12)
            *(ushort4*)(dstl + (size_t)(n0 + n) * D_ + k0 + kc) = make_ushort4(lo[0], lo[1], lo[2], lo[3]);
    }
}

// ---------------- LayerNorm -> bf16 hi (+lo) ----------------
template<bool LO>
__global__ __launch_bounds__(256) void ln_kernel(const float* __restrict__ x,
                                                 const float* __restrict__ s,
                                                 const float* __restrict__ b,
                                                 ushort_t* __restrict__ yh,
                                                 ushort_t* __restrict__ yl) {
    int wid = threadIdx.x >> 6, lane = threadIdx.x & 63;
    size_t row = (size_t)blockIdx.x * 4 + wid;
    const float4* xr = (const float4*)(x + row * D_);
    float4 v0 = xr[lane * 2], v1 = xr[lane * 2 + 1];
    float sum = v0.x + v0.y + v0.z + v0.w + v1.x + v1.y + v1.z + v1.w;
    for (int o = 32; o; o >>= 1) sum += __shfl_xor(sum, o);
    float mean = sum * (1.f / 512.f);
    float d[8] = {v0.x - mean, v0.y - mean, v0.z - mean, v0.w - mean,
                  v1.x - mean, v1.y - mean, v1.z - mean, v1.w - mean};
    float vs = 0.f;
#pragma unroll
    for (int i = 0; i < 8; i++) vs += d[i] * d[i];
    for (int o = 32; o; o >>= 1) vs += __shfl_xor(vs, o);
    float rs = 1.f / sqrtf(vs * (1.f / 512.f) + 1e-5f);
    const float4* s4 = (const float4*)s;
    const float4* b4 = (const float4*)b;
    float4 sa = s4[lane * 2], sb = s4[lane * 2 + 1];
    float4 ba = b4[lane * 2], bb = b4[lane * 2 + 1];
    float o8[8];
    o8[0] = d[0] * rs * sa.x + ba.x; o8[1] = d[1] * rs * sa.y + ba.y;
    o8[2] = d[2] * rs * sa.z + ba.z; o8[3] = d[3] * rs * sa.w + ba.w;
    o8[4] = d[4] * rs * sb.x + bb.x; o8[5] = d[5] * rs * sb.y + bb.y;
    o8[6] = d[6] * rs * sb.z + bb.z; o8[7] = d[7] * rs * sb.w + bb.w;
    ushort_t h[8];
#pragma unroll
    for (int i = 0; i < 8; i++) h[i] = f2bf(o8[i]);
    uint4 u;
    u.x = (unsigned)h[0] | ((unsigned)h[1] << 16);
    u.y = (unsigned)h[2] | ((unsigned)h[3] << 16);
    u.z = (unsigned)h[4] | ((unsigned)h[5] << 16);
    u.w = (unsigned)h[6] | ((unsigned)h[7] << 16);
    *(uint4*)(yh + row * D_ + lane * 8) = u;
    if (LO) {
        ushort_t l8[8];
#pragma unroll
        for (int i = 0; i < 8; i++) l8[i] = f2bf(o8[i] - bf2f(h[i]));
        uint4 ul;
        ul.x = (unsigned)l8[0] | ((unsigned)l8[1] << 16);
        ul.y = (unsigned)l8[2] | ((unsigned)l8[3] << 16);
        ul.z = (unsigned)l8[4] | ((unsigned)l8[5] << 16);
        ul.w = (unsigned)l8[6] | ((unsigned)l8[7] << 16);
        *(uint4*)(yl + row * D_ + lane * 8) = ul;
    }
}

// ---------------- MFMA GEMM: C[8192,512] = sum_seg A_seg[8192,512] * WT_seg[512,512]^T ----------------
// EPI: 0=bf16(+bias), 1=bf16 transposed->vt, 2=f32(+bias+res), 3=relu->bf16, 4=f32(+bias)
template<int EPI>
__global__ __launch_bounds__(256) void gemm_kernel(const ushort_t* __restrict__ A0,
                                                   const ushort_t* __restrict__ A1,
                                                   const ushort_t* __restrict__ A2,
                                                   const ushort_t* __restrict__ B0,
                                                   const ushort_t* __restrict__ B1,
                                                   const ushort_t* __restrict__ B2,
                                                   int nseg,
                                                   const float* __restrict__ bias,
                                                   const float* __restrict__ res,
                                                   float* __restrict__ outF,
                                                   ushort_t* __restrict__ outB) {
    __shared__ ushort_t As[2][128 * 64];
    __shared__ ushort_t Bs[2][128 * 64];
    int tid = threadIdx.x;
    // XCD-chunked swizzle: same-XCD blocks share the A slab
    int g = blockIdx.x;
    int lin = (g & 7) * 32 + (g >> 3);
    int bm = lin >> 2, bn = lin & 3;

    int lane = tid & 63;
    int wid = tid >> 6;
    int wm = wid >> 1, wn = wid & 1;

    f32x4 acc[4][4];
#pragma unroll
    for (int i = 0; i < 4; i++)
#pragma unroll
        for (int j = 0; j < 4; j++) ZERO4(acc[i][j]);

    int nt = nseg * 8;

#define STAGE(kt, buf)                                                                  \
    {                                                                                   \
        int seg_ = (kt) >> 3;                                                           \
        int k0_ = ((kt) & 7) * 64;                                                      \
        const ushort_t* Asg = seg_ == 0 ? A0 : (seg_ == 1 ? A1 : A2);                   \
        const ushort_t* Bsg = seg_ == 0 ? B0 : (seg_ == 1 ? B1 : B2);                   \
        _Pragma("unroll")                                                               \
        for (int it = 0; it < 4; it++) {                                                \
            int uu = tid + it * 256;                                                    \
            int row_ = uu >> 3;                                                         \
            int kb_ = (uu & 7) * 8;                                                     \
            gl16(Asg + (size_t)(bm * 128 + row_) * 512 + k0_ + kb_, &As[buf][uu * 8]);  \
            gl16(Bsg + (size_t)(bn * 128 + row_) * 512 + k0_ + kb_, &Bs[buf][uu * 8]);  \
        }                                                                               \
    }

    STAGE(0, 0);
    asm volatile("s_waitcnt vmcnt(0)" ::: "memory");
    __syncthreads();

    int buf = 0;
    for (int t = 0; t < nt; t++) {
        if (t + 1 < nt) STAGE(t + 1, buf ^ 1);
#pragma unroll
        for (int kc = 0; kc < 2; kc++) {
            short8 a[4], b[4];
#pragma unroll
            for (int i = 0; i < 4; i++)
                a[i] = *(const short8*)&As[buf][(wm * 64 + i * 16 + (lane & 15)) * 64 + kc * 32 + ((lane >> 4) << 3)];
#pragma unroll
            for (int j = 0; j < 4; j++)
                b[j] = *(const short8*)&Bs[buf][(wn * 64 + j * 16 + (lane & 15)) * 64 + kc * 32 + ((lane >> 4) << 3)];
#pragma unroll
            for (int i = 0; i < 4; i++)
#pragma unroll
                for (int j = 0; j < 4; j++)
                    acc[i][j] = __builtin_amdgcn_mfma_f32_16x16x32_bf16(a[i], b[j], acc[i][j], 0, 0, 0);
        }
        asm volatile("s_waitcnt vmcnt(0)" ::: "memory");
        __syncthreads();
        buf ^= 1;
    }
#undef STAGE

#pragma unroll
    for (int i = 0; i < 4; i++) {
#pragma unroll
        for (int j = 0; j < 4; j++) {
            int r0 = bm * 128 + wm * 64 + i * 16 + ((lane >> 4) << 2);
            int col = bn * 128 + wn * 64 + j * 16 + (lane & 15);
            float bc = bias[col];
#pragma unroll
            for (int jj = 0; jj < 4; jj++) {
                float v = acc[i][j][jj] + bc;
                int row = r0 + jj;
                size_t idx = (size_t)row * 512 + col;
                if (EPI == 0) {
                    outB[idx] = f2bf(v);
                } else if (EPI == 1) {
                    int bb = row >> 8, t = row & 255;
                    outB[((size_t)(bb * 8 + (col >> 6)) * 64 + (col & 63)) * 256 + t] = f2bf(v);
                } else if (EPI == 2) {
                    outF[idx] = v + res[idx];
                } else if (EPI == 3) {
                    outB[idx] = f2bf(fmaxf(v, 0.f));
                } else {
                    outF[idx] = v;
                }
            }
        }
    }
}

// ---------------- attn S = softmax(Q K^T / 8): block = 128 q-rows x all 256 keys ----------------
__global__ __launch_bounds__(256) void sgemm_sm_kernel(const ushort_t* __restrict__ q,
                                                       const ushort_t* __restrict__ k,
                                                       ushort_t* __restrict__ P,
                                                       int bh0) {
    __shared__ ushort_t Qs[128 * 64];
    __shared__ ushort_t Ks[256 * 64];
    int tid = threadIdx.x;
    int m0 = blockIdx.x * 128;
    int bhl = blockIdx.y;
    int bh = bh0 + bhl;
    int b = bh >> 3, h = bh & 7;
    // stage Q tile (128x64) and K tile (256x64)
#pragma unroll
    for (int it = 0; it < 4; it++) {
        int uu = tid + it * 256;
        int row = uu >> 3, kb = (uu & 7) * 8;
        gl16(q + (size_t)(b * T_ + m0 + row) * D_ + h * DK_ + kb, &Qs[uu * 8]);
    }
#pragma unroll
    for (int it = 0; it < 8; it++) {
        int uu = tid + it * 256;
        int row = uu >> 3, kb = (uu & 7) * 8;
        gl16(k + (size_t)(b * T_ + row) * D_ + h * DK_ + kb, &Ks[uu * 8]);
    }
    asm volatile("s_waitcnt vmcnt(0)" ::: "memory");
    __syncthreads();

    int lane = tid & 63;
    int wid = tid >> 6;
    int wm = wid >> 1, wn = wid & 1;

    f32x4 acc[4][8];
#pragma unroll
    for (int i = 0; i < 4; i++)
#pragma unroll
        for (int j = 0; j < 8; j++) ZERO4(acc[i][j]);

    short8 a[4][2];
#pragma unroll
    for (int i = 0; i < 4; i++)
#pragma unroll
        for (int kc = 0; kc < 2; kc++)
            a[i][kc] = *(const short8*)&Qs[(wm * 64 + i * 16 + (lane & 15)) * 64 + kc * 32 + ((lane >> 4) << 3)];
#pragma unroll
    for (int j = 0; j < 8; j++) {
        short8 b0 = *(const short8*)&Ks[(wn * 128 + j * 16 + (lane & 15)) * 64 + ((lane >> 4) << 3)];
        short8 b1 = *(const short8*)&Ks[(wn * 128 + j * 16 + (lane & 15)) * 64 + 32 + ((lane >> 4) << 3)];
#pragma unroll
        for (int i = 0; i < 4; i++) {
            acc[i][j] = __builtin_amdgcn_mfma_f32_16x16x32_bf16(a[i][0], b0, acc[i][j], 0, 0, 0);
            acc[i][j] = __builtin_amdgcn_mfma_f32_16x16x32_bf16(a[i][1], b1, acc[i][j], 0, 0, 0);
        }
    }
    // softmax per q-row; lane holds col (lane&15) of rows (lane>>4)*4+jj; full row = 8 j-frags x 16 lanes
    const float C = 0.125f * 1.44269504f;  // scale * log2(e)
#pragma unroll
    for (int i = 0; i < 4; i++) {
        float mx[4] = {-1e30f, -1e30f, -1e30f, -1e30f};
#pragma unroll
        for (int j = 0; j < 8; j++)
#pragma unroll
            for (int jj = 0; jj < 4; jj++) mx[jj] = fmaxf(mx[jj], acc[i][j][jj]);
#pragma unroll
        for (int m = 1; m < 16; m <<= 1)
#pragma unroll
            for (int jj = 0; jj < 4; jj++) mx[jj] = fmaxf(mx[jj], __shfl_xor(mx[jj], m));
        float sm[4] = {0.f, 0.f, 0.f, 0.f};
#pragma unroll
        for (int j = 0; j < 8; j++)
#pragma unroll
            for (int jj = 0; jj < 4; jj++) {
                float e = exp2f((acc[i][j][jj] - mx[jj]) * C);
                acc[i][j][jj] = e;
                sm[jj] += e;
            }
#pragma unroll
        for (int m = 1; m < 16; m <<= 1)
#pragma unroll
            for (int jj = 0; jj < 4; jj++) sm[jj] += __shfl_xor(sm[jj], m);
        float inv[4];
#pragma unroll
        for (int jj = 0; jj < 4; jj++) inv[jj] = 1.f / sm[jj];
#pragma unroll
        for (int j = 0; j < 8; j++) {
            int row0 = m0 + wm * 64 + i * 16 + ((lane >> 4) << 2);
            int col = wn * 128 + j * 16 + (lane & 15);
#pragma unroll
            for (int jj = 0; jj < 4; jj++)
                P[((size_t)bhl * T_ + row0 + jj) * T_ + col] = f2bf(acc[i][j][jj] * inv[jj]);
        }
    }
}

// ---------------- attn O = P V  (V pre-transposed [bh][dk][t]) ----------------
__global__ __launch_bounds__(256) void pv_kernel(const ushort_t* __restrict__ P,
                                                 const ushort_t* __restrict__ vt,
                                                 ushort_t* __restrict__ ao,
                                                 int bh0) {
    __shared__ ushort_t Ps[2][64 * 64];
    __shared__ ushort_t Vs[2][64 * 64];
    int tid = threadIdx.x;
    int m0 = blockIdx.x * 64;
    int bhl = blockIdx.y;
    int bh = bh0 + bhl;
    int b = bh >> 3, h = bh & 7;
    int lane = tid & 63;
    int wid = tid >> 6;
    int wm = wid >> 1, wn = wid & 1;

    f32x4 acc[2][2];
#pragma unroll
    for (int i = 0; i < 2; i++)
#pragma unroll
        for (int j = 0; j < 2; j++) ZERO4(acc[i][j]);

#define PVSTAGE(kt, buf)                                                                  \
    {                                                                                     \
        _Pragma("unroll")                                                                 \
        for (int it = 0; it < 2; it++) {                                                  \
            int uu = tid + it * 256;                                                      \
            int row_ = uu >> 3, kb_ = (uu & 7) * 8;                                       \
            gl16(P + ((size_t)bhl * T_ + m0 + row_) * T_ + (kt) * 64 + kb_, &Ps[buf][uu * 8]); \
            gl16(vt + ((size_t)bh * DK_ + row_) * T_ + (kt) * 64 + kb_, &Vs[buf][uu * 8]);     \
        }                                                                                 \
    }

    PVSTAGE(0, 0);
    asm volatile("s_waitcnt vmcnt(0)" ::: "memory");
    __syncthreads();
    int buf = 0;
    for (int t = 0; t < 4; t++) {
        if (t + 1 < 4) PVSTAGE(t + 1, buf ^ 1);
#pragma unroll
        for (int kc = 0; kc < 2; kc++) {
            short8 a[2], bb[2];
#pragma unroll
            for (int i = 0; i < 2; i++)
                a[i] = *(const short8*)&Ps[buf][(wm * 32 + i * 16 + (lane & 15)) * 64 + kc * 32 + ((lane >> 4) << 3)];
#pragma unroll
            for (int j = 0; j < 2; j++)
                bb[j] = *(const short8*)&Vs[buf][(wn * 32 + j * 16 + (lane & 15)) * 64 + kc * 32 + ((lane >> 4) << 3)];
#pragma unroll
            for (int i = 0; i < 2; i++)
#pragma unroll
                for (int j = 0; j < 2; j++)
                    acc[i][j] = __builtin_amdgcn_mfma_f32_16x16x32_bf16(a[i], bb[j], acc[i][j], 0, 0, 0);
        }
        asm volatile("s_waitcnt vmcnt(0)" ::: "memory");
        __syncthreads();
        buf ^= 1;
    }
#undef PVSTAGE

#pragma unroll
    for (int i = 0; i < 2; i++)
#pragma unroll
        for (int j = 0; j < 2; j++) {
            int r0 = m0 + wm * 32 + i * 16 + ((lane >> 4) << 2);
            int col = h * DK_ + wn * 32 + j * 16 + (lane & 15);
#pragma unroll
            for (int jj = 0; jj < 4; jj++)
                ao[(size_t)(b * T_ + r0 + jj) * D_ + col] = f2bf(acc[i][j][jj]);
        }
}

// ---------------- PVAM scores: s[b,m,t] = sum_c tanh(wf[b,t,c]+wp[m,c])*w1[c] ----------------
__device__ __forceinline__ float fast_tanh(float x) {
    x = fminf(10.f, fmaxf(-10.f, x));
    float a = exp2f(x * 2.885390082f);           // e^(2x)
    return (a - 1.f) * __builtin_amdgcn_rcpf(a + 1.f);
}

// grid (8 ttiles, 32 b), 256 threads. 32 tokens/block, 8 threads/token, 64 ch/thread.
__global__ __launch_bounds__(256) void scores_kernel(const float* __restrict__ wf,
                                                     const int* __restrict__ gpos,
                                                     const float* __restrict__ emb,
                                                     const float* __restrict__ w1,
                                                     float* __restrict__ scores) {
    __shared__ float wpL[ML_][512];
    int tid = threadIdx.x;
    int b = blockIdx.y;
    int t = blockIdx.x * 32 + (tid >> 3);
    int cg = tid & 7;
    // stage wp = emb[gpos[m]] (25x512 f32)
    for (int idx = tid; idx < ML_ * 128; idx += 256) {
        int m = idx >> 7, w4 = idx & 127;
        *(float4*)&wpL[m][w4 << 2] = *(const float4*)(emb + (size_t)gpos[m] * D_ + (w4 << 2));
    }
    // thread's channels: c = cg*4 + j*32 + i  (j=0..15, i=0..3)
    float4 wfv[16], w1v[16];
    const float* wfr = wf + (size_t)(b * T_ + t) * D_ + (cg << 2);
#pragma unroll
    for (int j = 0; j < 16; j++) {
        wfv[j] = *(const float4*)(wfr + (j << 5));
        w1v[j] = *(const float4*)(w1 + (cg << 2) + (j << 5));
    }
    __syncthreads();
#pragma unroll 1
    for (int m = 0; m < ML_; m++) {
        float s = 0.f;
#pragma unroll
        for (int j = 0; j < 16; j++) {
            float4 wp4 = *(const float4*)&wpL[m][(cg << 2) + (j << 5)];
            s += fast_tanh(wfv[j].x + wp4.x) * w1v[j].x;
            s += fast_tanh(wfv[j].y + wp4.y) * w1v[j].y;
            s += fast_tanh(wfv[j].z + wp4.z) * w1v[j].z;
            s += fast_tanh(wfv[j].w + wp4.w) * w1v[j].w;
        }
        s += __shfl_xor(s, 1);
        s += __shfl_xor(s, 2);
        s += __shfl_xor(s, 4);
        if (cg == 0) scores[((size_t)b * ML_ + m) * T_ + t] = s;
    }
}

// softmax over t, in place: 800 rows of 256. grid 200 x 256 threads (wave per row).
__global__ __launch_bounds__(256) void softmax_kernel(float* __restrict__ sc) {
    int wid = threadIdx.x >> 6, lane = threadIdx.x & 63;
    size_t row = (size_t)blockIdx.x * 4 + wid;
    float4* p = (float4*)(sc + row * T_);
    float4 v = p[lane];
    float mx = fmaxf(fmaxf(v.x, v.y), fmaxf(v.z, v.w));
    for (int o = 32; o; o >>= 1) mx = fmaxf(mx, __shfl_xor(mx, o));
    float4 e;
    e.x = __expf(v.x - mx); e.y = __expf(v.y - mx);
    e.z = __expf(v.z - mx); e.w = __expf(v.w - mx);
    float sm = e.x + e.y + e.z + e.w;
    for (int o = 32; o; o >>= 1) sm += __shfl_xor(sm, o);
    float inv = 1.f / sm;
    e.x *= inv; e.y *= inv; e.z *= inv; e.w *= inv;
    p[lane] = e;
}

// weighted sum: out[b,m,c] = sum_t attn[b,m,t]*wf[b,t,c]. grid (5 mgroups, 32 b).
__global__ __launch_bounds__(256) void wsum_kernel(const float* __restrict__ attn,
                                                   const float* __restrict__ wf,
                                                   float* __restrict__ out) {
    __shared__ float at[T_][8];
    int tid = threadIdx.x;
    int b = blockIdx.y, m0 = blockIdx.x * 5;
#pragma unroll
    for (int q = 0; q < 5; q++) {
        float a = attn[((size_t)b * ML_ + m0 + q) * T_ + tid];
        at[tid][q] = a;
    }
    __syncthreads();
    int c0 = tid << 1;
    const float* wfb = wf + (size_t)b * T_ * D_ + c0;
    float acc[5][2] = {};
    for (int t = 0; t < T_; t++) {
        float2 v = *(const float2*)(wfb + (size_t)t * D_);
        float4 a4 = *(const float4*)&at[t][0];
        float a5 = at[t][4];
        acc[0][0] += a4.x * v.x; acc[0][1] += a4.x * v.y;
        acc[1][0] += a4.y * v.x; acc[1][1] += a4.y * v.y;
        acc[2][0] += a4.z * v.x; acc[2][1] += a4.z * v.y;
        acc[3][0] += a4.w * v.x; acc[3][1] += a4.w * v.y;
        acc[4][0] += a5 * v.x;   acc[4][1] += a5 * v.y;
    }
#pragma unroll
    for (int q = 0; q < 5; q++) {
        float2 o;
        o.x = acc[q][0]; o.y = acc[q][1];
        *(float2*)(out + ((size_t)b * ML_ + m0 + q) * D_ + c0) = o;
    }
}

extern "C" void kernel_launch(void* const* d_in, const int* in_sizes, int n_in,
                              void* d_out, int out_size, void* d_ws, size_t ws_size,
                              hipStream_t stream) {
    (void)in_sizes; (void)n_in; (void)out_size; (void)ws_size;
    const float* x        = (const float*)d_in[0];
    const int*   epos     = (const int*)d_in[1];
    const int*   gpos     = (const int*)d_in[2];
    const float* pos_tab  = (const float*)d_in[3];
    const float* ln1_s    = (const float*)d_in[4];
    const float* ln1_b    = (const float*)d_in[5];
    const float* Wq       = (const float*)d_in[6];
    const float* bq       = (const float*)d_in[7];
    const float* Wk       = (const float*)d_in[8];
    const float* bk       = (const float*)d_in[9];
    const float* Wv       = (const float*)d_in[10];
    const float* bv       = (const float*)d_in[11];
    const float* Wo       = (const float*)d_in[12];
    const float* bo       = (const float*)d_in[13];
    const float* ln2_s    = (const float*)d_in[14];
    const float* ln2_b    = (const float*)d_in[15];
    const float* W1       = (const float*)d_in[16];
    const float* b1       = (const float*)d_in[17];
    const float* W2       = (const float*)d_in[18];
    const float* b2       = (const float*)d_in[19];
    const float* lnf_s    = (const float*)d_in[20];
    const float* lnf_b    = (const float*)d_in[21];
    const float* fc0_w    = (const float*)d_in[22];
    const float* fc0_b    = (const float*)d_in[23];
    const float* emb      = (const float*)d_in[24];
    const float* fc1_w    = (const float*)d_in[25];

    char* ws = (char*)d_ws;
    float*    enc = (float*)(ws);                       // 16.78 MB
    ushort_t* hi  = (ushort_t*)(ws + 16777216);         // 8.39 MB
    ushort_t* qb  = (ushort_t*)(ws + 25165824);         // 8.39 MB
    ushort_t* kb  = (ushort_t*)(ws + 33554432);         // 8.39 MB (lo overlays later)
    ushort_t* lo  = (ushort_t*)(ws + 33554432);
    float*    scb = (float*)(ws + 33554432);            // scores 800KB (after fc0, lo dead)
    ushort_t* vt  = (ushort_t*)(ws + 41943040);         // 8.39 MB (h1 overlays later)
    ushort_t* h1  = (ushort_t*)(ws + 41943040);
    ushort_t* ao  = (ushort_t*)(ws + 50331648);         // 8.39 MB
    ushort_t* P   = (ushort_t*)(ws + 58720256);         // 16.78 MB half-batch (wf overlays)
    float*    wf  = (float*)(ws + 58720256);
    ushort_t* wt  = (ushort_t*)(ws + 75497472);         // 7.34 MB (14 slices of 512KB)
    const size_t WSL = (size_t)D_ * D_;

    convert_w_kernel<<<13 * 64, 256, 0, stream>>>(Wq, Wk, Wv, Wo, W1, W2, fc0_w, wt);
    prep_kernel<<<dim3(4, 8, 32), 256, 0, stream>>>(x, epos, pos_tab, enc);

    for (int l = 0; l < 2; l++) {
        size_t o1 = (size_t)l * D_;
        const ushort_t* WqT = wt + (l * 6 + 0) * WSL;
        const ushort_t* WkT = wt + (l * 6 + 1) * WSL;
        const ushort_t* WvT = wt + (l * 6 + 2) * WSL;
        const ushort_t* WoT = wt + (l * 6 + 3) * WSL;
        const ushort_t* W1T = wt + (l * 6 + 4) * WSL;
        const ushort_t* W2T = wt + (l * 6 + 5) * WSL;

        ln_kernel<false><<<2048, 256, 0, stream>>>(enc, ln1_s + o1, ln1_b + o1, hi, nullptr);
        gemm_kernel<0><<<256, 256, 0, stream>>>(hi, nullptr, nullptr, WqT, nullptr, nullptr, 1, bq + o1, nullptr, nullptr, qb);
        gemm_kernel<0><<<256, 256, 0, stream>>>(hi, nullptr, nullptr, WkT, nullptr, nullptr, 1, bk + o1, nullptr, nullptr, kb);
        gemm_kernel<1><<<256, 256, 0, stream>>>(hi, nullptr, nullptr, WvT, nullptr, nullptr, 1, bv + o1, nullptr, nullptr, vt);
        for (int half = 0; half < 2; half++) {
            sgemm_sm_kernel<<<dim3(2, 128), 256, 0, stream>>>(qb, kb, P, half * 128);
            pv_kernel<<<dim3(4, 128), 256, 0, stream>>>(P, vt, ao, half * 128);
        }
        gemm_kernel<2><<<256, 256, 0, stream>>>(ao, nullptr, nullptr, WoT, nullptr, nullptr, 1, bo + o1, enc, enc, nullptr);
        ln_kernel<false><<<2048, 256, 0, stream>>>(enc, ln2_s + o1, ln2_b + o1, hi, nullptr);
        gemm_kernel<3><<<256, 256, 0, stream>>>(hi, nullptr, nullptr, W1T, nullptr, nullptr, 1, b1 + o1, nullptr, nullptr, h1);
        gemm_kernel<2><<<256, 256, 0, stream>>>(h1, nullptr, nullptr, W2T, nullptr, nullptr, 1, b2 + o1, enc, enc, nullptr);
    }

    ln_kernel<true><<<2048, 256, 0, stream>>>(enc, lnf_s, lnf_b, hi, lo);
    // fc0 split-bf16: Ah*Wh + Al*Wh + Ah*Wl
    gemm_kernel<4><<<256, 256, 0, stream>>>(hi, lo, hi, wt + 12 * WSL, wt + 12 * WSL, wt + 13 * WSL, 3,
                                            fc0_b, nullptr, wf, nullptr);
    scores_kernel<<<dim3(8, 32), 256, 0, stream>>>(wf, gpos, emb, fc1_w, scb);
    softmax_kernel<<<200, 256, 0, stream>>>(scb);
    wsum_kernel<<<dim3(5, 32), 256, 0, stream>>>(scb, wf, (float*)d_out);
}

// Round 4
// 383.773 us; speedup vs baseline: 4.0709x; 1.0483x over previous
//
#include <hip/hip_runtime.h>
#include <math.h>

#define B_ 32
#define D_ 512
#define T_ 256
#define NH_ 8
#define DK_ 64
#define ML_ 25

typedef unsigned short ushort_t;
using short8 = __attribute__((ext_vector_type(8))) short;
using f32x4  = __attribute__((ext_vector_type(4))) float;

__device__ __forceinline__ ushort_t f2bf(float f) {
    unsigned u = __float_as_uint(f);
    unsigned r = (u + 0x7fffu + ((u >> 16) & 1u)) >> 16;
    return (ushort_t)r;
}
__device__ __forceinline__ float bf2f(ushort_t h) {
    return __uint_as_float(((unsigned)h) << 16);
}
__device__ __forceinline__ void gl16(const void* g, void* l) {
    __builtin_amdgcn_global_load_lds((const __attribute__((address_space(1))) void*)g,
                                     (__attribute__((address_space(3))) void*)l, 16, 0, 0);
}
#define ZERO4(v) { (v)[0]=0.f; (v)[1]=0.f; (v)[2]=0.f; (v)[3]=0.f; }

// ---------------- prep: enc[b,t,c] = x[b,c,t]*sqrt(512) + pos[epos[t],c]  (LDS transpose) ----------------
__global__ __launch_bounds__(256) void prep_kernel(const float* __restrict__ x,
                                                   const int* __restrict__ epos,
                                                   const float* __restrict__ pos,
                                                   float* __restrict__ enc) {
    __shared__ float ld[64][65];
    int tt = blockIdx.x, ct = blockIdx.y, b = blockIdx.z;
    int t0 = tt * 64, c0 = ct * 64;
    int tid = threadIdx.x;
    int r = tid >> 4, c4 = (tid & 15) << 2;
#pragma unroll
    for (int p = 0; p < 4; p++) {
        int row = p * 16 + r;  // channel within tile
        float4 v = *(const float4*)(x + ((size_t)(b * D_ + c0 + row) * T_ + t0) + c4);
        ld[row][c4 + 0] = v.x; ld[row][c4 + 1] = v.y; ld[row][c4 + 2] = v.z; ld[row][c4 + 3] = v.w;
    }
    __syncthreads();
#pragma unroll
    for (int p = 0; p < 4; p++) {
        int tr = p * 16 + r;   // token within tile
        int ep = epos[t0 + tr];
        float4 pv = *(const float4*)(pos + (size_t)ep * D_ + c0 + c4);
        float4 o;
        o.x = ld[c4 + 0][tr] * 22.627417f + pv.x;
        o.y = ld[c4 + 1][tr] * 22.627417f + pv.y;
        o.z = ld[c4 + 2][tr] * 22.627417f + pv.z;
        o.w = ld[c4 + 3][tr] * 22.627417f + pv.w;
        *(float4*)(enc + (size_t)(b * T_ + t0 + tr) * D_ + c0 + c4) = o;
    }
}

// ---------------- weight convert: WT[n][k] = bf16(W[k][n]); fc0 also lo ----------------
__global__ __launch_bounds__(256) void convert_w_kernel(const float* __restrict__ Wq,
                                                        const float* __restrict__ Wk,
                                                        const float* __restrict__ Wv,
                                                        const float* __restrict__ Wo,
                                                        const float* __restrict__ W1,
                                                        const float* __restrict__ W2,
                                                        const float* __restrict__ fc0,
                                                        ushort_t* __restrict__ wt) {
    __shared__ float ld[64][65];
    int m = blockIdx.x >> 6;
    int tile = blockIdx.x & 63;
    int tn = tile >> 3, tk = tile & 7;
    int n0 = tn * 64, k0 = tk * 64;
    const float* src;
    if (m < 12) {
        int l = m / 6, w = m % 6;
        const float* bases[6] = {Wq, Wk, Wv, Wo, W1, W2};
        src = bases[w] + (size_t)l * D_ * D_;
    } else {
        src = fc0;
    }
    int tid = threadIdx.x;
    int r = tid >> 4, c4 = (tid & 15) << 2;
#pragma unroll
    for (int p = 0; p < 4; p++) {
        int row = p * 16 + r;  // k index
        float4 v = *(const float4*)(src + (size_t)(k0 + row) * D_ + n0 + c4);
        ld[row][c4 + 0] = v.x; ld[row][c4 + 1] = v.y; ld[row][c4 + 2] = v.z; ld[row][c4 + 3] = v.w;
    }
    __syncthreads();
    ushort_t* dsth = wt + (size_t)m * D_ * D_;
    ushort_t* dstl = wt + (size_t)13 * D_ * D_;
#pragma unroll
    for (int p = 0; p < 4; p++) {
        int n = p * 16 + r;
        int kc = c4;
        ushort_t h[4], lo[4];
#pragma unroll
        for (int i = 0; i < 4; i++) {
            float f = ld[kc + i][n];
            h[i] = f2bf(f);
            lo[i] = f2bf(f - bf2f(h[i]));
        }
        *(ushort4*)(dsth + (size_t)(n0 + n) * D_ + k0 + kc) = make_ushort4(h[0], h[1], h[2], h[3]);
        if (m == 12)
            *(ushort4*)(dstl + (size_t)(n0 + n) * D_ + k0 + kc) = make_ushort4(lo[0], lo[1], lo[2], lo[3]);
    }
}

// ---------------- LayerNorm -> bf16 hi (+lo) ----------------
template<bool LO>
__global__ __launch_bounds__(256) void ln_kernel(const float* __restrict__ x,
                                                 const float* __restrict__ s,
                                                 const float* __restrict__ b,
                                                 ushort_t* __restrict__ yh,
                                                 ushort_t* __restrict__ yl) {
    int wid = threadIdx.x >> 6, lane = threadIdx.x & 63;
    size_t row = (size_t)blockIdx.x * 4 + wid;
    const float4* xr = (const float4*)(x + row * D_);
    float4 v0 = xr[lane * 2], v1 = xr[lane * 2 + 1];
    float sum = v0.x + v0.y + v0.z + v0.w + v1.x + v1.y + v1.z + v1.w;
    for (int o = 32; o; o >>= 1) sum += __shfl_xor(sum, o);
    float mean = sum * (1.f / 512.f);
    float d[8] = {v0.x - mean, v0.y - mean, v0.z - mean, v0.w - mean,
                  v1.x - mean, v1.y - mean, v1.z - mean, v1.w - mean};
    float vs = 0.f;
#pragma unroll
    for (int i = 0; i < 8; i++) vs += d[i] * d[i];
    for (int o = 32; o; o >>= 1) vs += __shfl_xor(vs, o);
    float rs = 1.f / sqrtf(vs * (1.f / 512.f) + 1e-5f);
    const float4* s4 = (const float4*)s;
    const float4* b4 = (const float4*)b;
    float4 sa = s4[lane * 2], sb = s4[lane * 2 + 1];
    float4 ba = b4[lane * 2], bb = b4[lane * 2 + 1];
    float o8[8];
    o8[0] = d[0] * rs * sa.x + ba.x; o8[1] = d[1] * rs * sa.y + ba.y;
    o8[2] = d[2] * rs * sa.z + ba.z; o8[3] = d[3] * rs * sa.w + ba.w;
    o8[4] = d[4] * rs * sb.x + bb.x; o8[5] = d[5] * rs * sb.y + bb.y;
    o8[6] = d[6] * rs * sb.z + bb.z; o8[7] = d[7] * rs * sb.w + bb.w;
    ushort_t h[8];
#pragma unroll
    for (int i = 0; i < 8; i++) h[i] = f2bf(o8[i]);
    uint4 u;
    u.x = (unsigned)h[0] | ((unsigned)h[1] << 16);
    u.y = (unsigned)h[2] | ((unsigned)h[3] << 16);
    u.z = (unsigned)h[4] | ((unsigned)h[5] << 16);
    u.w = (unsigned)h[6] | ((unsigned)h[7] << 16);
    *(uint4*)(yh + row * D_ + lane * 8) = u;
    if (LO) {
        ushort_t l8[8];
#pragma unroll
        for (int i = 0; i < 8; i++) l8[i] = f2bf(o8[i] - bf2f(h[i]));
        uint4 ul;
        ul.x = (unsigned)l8[0] | ((unsigned)l8[1] << 16);
        ul.y = (unsigned)l8[2] | ((unsigned)l8[3] << 16);
        ul.z = (unsigned)l8[4] | ((unsigned)l8[5] << 16);
        ul.w = (unsigned)l8[6] | ((unsigned)l8[7] << 16);
        *(uint4*)(yl + row * D_ + lane * 8) = ul;
    }
}

// ---------------- MFMA GEMM: C[8192,512] = sum_seg A_seg[8192,512] * WT_seg[512,512]^T ----------------
// EPI: 0=bf16(+bias), 1=bf16 transposed->vt, 2=f32(+bias+res), 3=relu->bf16, 4=f32(+bias)
template<int EPI>
__global__ __launch_bounds__(256) void gemm_kernel(const ushort_t* __restrict__ A0,
                                                   const ushort_t* __restrict__ A1,
                                                   const ushort_t* __restrict__ A2,
                                                   const ushort_t* __restrict__ B0,
                                                   const ushort_t* __restrict__ B1,
                                                   const ushort_t* __restrict__ B2,
                                                   int nseg,
                                                   const float* __restrict__ bias,
                                                   const float* __restrict__ res,
                                                   float* __restrict__ outF,
                                                   ushort_t* __restrict__ outB) {
    __shared__ ushort_t As[2][128 * 64];
    __shared__ ushort_t Bs[2][128 * 64];
    int tid = threadIdx.x;
    // XCD-chunked swizzle: same-XCD blocks share the A slab
    int g = blockIdx.x;
    int lin = (g & 7) * 32 + (g >> 3);
    int bm = lin >> 2, bn = lin & 3;

    int lane = tid & 63;
    int wid = tid >> 6;
    int wm = wid >> 1, wn = wid & 1;

    f32x4 acc[4][4];
#pragma unroll
    for (int i = 0; i < 4; i++)
#pragma unroll
        for (int j = 0; j < 4; j++) ZERO4(acc[i][j]);

    int nt = nseg * 8;

#define STAGE(kt, buf)                                                                  \
    {                                                                                   \
        int seg_ = (kt) >> 3;                                                           \
        int k0_ = ((kt) & 7) * 64;                                                      \
        const ushort_t* Asg = seg_ == 0 ? A0 : (seg_ == 1 ? A1 : A2);                   \
        const ushort_t* Bsg = seg_ == 0 ? B0 : (seg_ == 1 ? B1 : B2);                   \
        _Pragma("unroll")                                                               \
        for (int it = 0; it < 4; it++) {                                                \
            int uu = tid + it * 256;                                                    \
            int row_ = uu >> 3;                                                         \
            int kb_ = (uu & 7) * 8;                                                     \
            gl16(Asg + (size_t)(bm * 128 + row_) * 512 + k0_ + kb_, &As[buf][uu * 8]);  \
            gl16(Bsg + (size_t)(bn * 128 + row_) * 512 + k0_ + kb_, &Bs[buf][uu * 8]);  \
        }                                                                               \
    }

    STAGE(0, 0);
    asm volatile("s_waitcnt vmcnt(0)" ::: "memory");
    __syncthreads();

    int buf = 0;
    for (int t = 0; t < nt; t++) {
        if (t + 1 < nt) STAGE(t + 1, buf ^ 1);
#pragma unroll
        for (int kc = 0; kc < 2; kc++) {
            short8 a[4], b[4];
#pragma unroll
            for (int i = 0; i < 4; i++)
                a[i] = *(const short8*)&As[buf][(wm * 64 + i * 16 + (lane & 15)) * 64 + kc * 32 + ((lane >> 4) << 3)];
#pragma unroll
            for (int j = 0; j < 4; j++)
                b[j] = *(const short8*)&Bs[buf][(wn * 64 + j * 16 + (lane & 15)) * 64 + kc * 32 + ((lane >> 4) << 3)];
#pragma unroll
            for (int i = 0; i < 4; i++)
#pragma unroll
                for (int j = 0; j < 4; j++)
                    acc[i][j] = __builtin_amdgcn_mfma_f32_16x16x32_bf16(a[i], b[j], acc[i][j], 0, 0, 0);
        }
        asm volatile("s_waitcnt vmcnt(0)" ::: "memory");
        __syncthreads();
        buf ^= 1;
    }
#undef STAGE

#pragma unroll
    for (int i = 0; i < 4; i++) {
#pragma unroll
        for (int j = 0; j < 4; j++) {
            int r0 = bm * 128 + wm * 64 + i * 16 + ((lane >> 4) << 2);
            int col = bn * 128 + wn * 64 + j * 16 + (lane & 15);
            float bc = bias[col];
#pragma unroll
            for (int jj = 0; jj < 4; jj++) {
                float v = acc[i][j][jj] + bc;
                int row = r0 + jj;
                size_t idx = (size_t)row * 512 + col;
                if (EPI == 0) {
                    outB[idx] = f2bf(v);
                } else if (EPI == 1) {
                    int bb = row >> 8, t = row & 255;
                    outB[((size_t)(bb * 8 + (col >> 6)) * 64 + (col & 63)) * 256 + t] = f2bf(v);
                } else if (EPI == 2) {
                    outF[idx] = v + res[idx];
                } else if (EPI == 3) {
                    outB[idx] = f2bf(fmaxf(v, 0.f));
                } else {
                    outF[idx] = v;
                }
            }
        }
    }
}

// ---------------- attn S = softmax(Q K^T / 8): block = 128 q-rows x all 256 keys ----------------
__global__ __launch_bounds__(256) void sgemm_sm_kernel(const ushort_t* __restrict__ q,
                                                       const ushort_t* __restrict__ k,
                                                       ushort_t* __restrict__ P,
                                                       int bh0) {
    __shared__ ushort_t Qs[128 * 64];
    __shared__ ushort_t Ks[256 * 64];
    int tid = threadIdx.x;
    int m0 = blockIdx.x * 128;
    int bhl = blockIdx.y;
    int bh = bh0 + bhl;
    int b = bh >> 3, h = bh & 7;
    // stage Q tile (128x64) and K tile (256x64)
#pragma unroll
    for (int it = 0; it < 4; it++) {
        int uu = tid + it * 256;
        int row = uu >> 3, kb = (uu & 7) * 8;
        gl16(q + (size_t)(b * T_ + m0 + row) * D_ + h * DK_ + kb, &Qs[uu * 8]);
    }
#pragma unroll
    for (int it = 0; it < 8; it++) {
        int uu = tid + it * 256;
        int row = uu >> 3, kb = (uu & 7) * 8;
        gl16(k + (size_t)(b * T_ + row) * D_ + h * DK_ + kb, &Ks[uu * 8]);
    }
    asm volatile("s_waitcnt vmcnt(0)" ::: "memory");
    __syncthreads();

    int lane = tid & 63;
    int wid = tid >> 6;
    int wm = wid >> 1, wn = wid & 1;

    f32x4 acc[4][8];
#pragma unroll
    for (int i = 0; i < 4; i++)
#pragma unroll
        for (int j = 0; j < 8; j++) ZERO4(acc[i][j]);

    short8 a[4][2];
#pragma unroll
    for (int i = 0; i < 4; i++)
#pragma unroll
        for (int kc = 0; kc < 2; kc++)
            a[i][kc] = *(const short8*)&Qs[(wm * 64 + i * 16 + (lane & 15)) * 64 + kc * 32 + ((lane >> 4) << 3)];
#pragma unroll
    for (int j = 0; j < 8; j++) {
        short8 b0 = *(const short8*)&Ks[(wn * 128 + j * 16 + (lane & 15)) * 64 + ((lane >> 4) << 3)];
        short8 b1 = *(const short8*)&Ks[(wn * 128 + j * 16 + (lane & 15)) * 64 + 32 + ((lane >> 4) << 3)];
#pragma unroll
        for (int i = 0; i < 4; i++) {
            acc[i][j] = __builtin_amdgcn_mfma_f32_16x16x32_bf16(a[i][0], b0, acc[i][j], 0, 0, 0);
            acc[i][j] = __builtin_amdgcn_mfma_f32_16x16x32_bf16(a[i][1], b1, acc[i][j], 0, 0, 0);
        }
    }
    // softmax per q-row; lane holds col (lane&15) of rows (lane>>4)*4+jj; full row = 8 j-frags x 16 lanes
    const float C = 0.125f * 1.44269504f;  // scale * log2(e)
#pragma unroll
    for (int i = 0; i < 4; i++) {
        float mx[4] = {-1e30f, -1e30f, -1e30f, -1e30f};
#pragma unroll
        for (int j = 0; j < 8; j++)
#pragma unroll
            for (int jj = 0; jj < 4; jj++) mx[jj] = fmaxf(mx[jj], acc[i][j][jj]);
#pragma unroll
        for (int m = 1; m < 16; m <<= 1)
#pragma unroll
            for (int jj = 0; jj < 4; jj++) mx[jj] = fmaxf(mx[jj], __shfl_xor(mx[jj], m));
        float sm[4] = {0.f, 0.f, 0.f, 0.f};
#pragma unroll
        for (int j = 0; j < 8; j++)
#pragma unroll
            for (int jj = 0; jj < 4; jj++) {
                float e = exp2f((acc[i][j][jj] - mx[jj]) * C);
                acc[i][j][jj] = e;
                sm[jj] += e;
            }
#pragma unroll
        for (int m = 1; m < 16; m <<= 1)
#pragma unroll
            for (int jj = 0; jj < 4; jj++) sm[jj] += __shfl_xor(sm[jj], m);
        float inv[4];
#pragma unroll
        for (int jj = 0; jj < 4; jj++) inv[jj] = 1.f / sm[jj];
#pragma unroll
        for (int j = 0; j < 8; j++) {
            int row0 = m0 + wm * 64 + i * 16 + ((lane >> 4) << 2);
            int col = wn * 128 + j * 16 + (lane & 15);
#pragma unroll
            for (int jj = 0; jj < 4; jj++)
                P[((size_t)bhl * T_ + row0 + jj) * T_ + col] = f2bf(acc[i][j][jj] * inv[jj]);
        }
    }
}

// ---------------- attn O = P V  (V pre-transposed [bh][dk][t]) ----------------
__global__ __launch_bounds__(256) void pv_kernel(const ushort_t* __restrict__ P,
                                                 const ushort_t* __restrict__ vt,
                                                 ushort_t* __restrict__ ao,
                                                 int bh0) {
    __shared__ ushort_t Ps[2][64 * 64];
    __shared__ ushort_t Vs[2][64 * 64];
    int tid = threadIdx.x;
    int m0 = blockIdx.x * 64;
    int bhl = blockIdx.y;
    int bh = bh0 + bhl;
    int b = bh >> 3, h = bh & 7;
    int lane = tid & 63;
    int wid = tid >> 6;
    int wm = wid >> 1, wn = wid & 1;

    f32x4 acc[2][2];
#pragma unroll
    for (int i = 0; i < 2; i++)
#pragma unroll
        for (int j = 0; j < 2; j++) ZERO4(acc[i][j]);

#define PVSTAGE(kt, buf)                                                                  \
    {                                                                                     \
        _Pragma("unroll")                                                                 \
        for (int it = 0; it < 2; it++) {                                                  \
            int uu = tid + it * 256;                                                      \
            int row_ = uu >> 3, kb_ = (uu & 7) * 8;                                       \
            gl16(P + ((size_t)bhl * T_ + m0 + row_) * T_ + (kt) * 64 + kb_, &Ps[buf][uu * 8]); \
            gl16(vt + ((size_t)bh * DK_ + row_) * T_ + (kt) * 64 + kb_, &Vs[buf][uu * 8]);     \
        }                                                                                 \
    }

    PVSTAGE(0, 0);
    asm volatile("s_waitcnt vmcnt(0)" ::: "memory");
    __syncthreads();
    int buf = 0;
    for (int t = 0; t < 4; t++) {
        if (t + 1 < 4) PVSTAGE(t + 1, buf ^ 1);
#pragma unroll
        for (int kc = 0; kc < 2; kc++) {
            short8 a[2], bb[2];
#pragma unroll
            for (int i = 0; i < 2; i++)
                a[i] = *(const short8*)&Ps[buf][(wm * 32 + i * 16 + (lane & 15)) * 64 + kc * 32 + ((lane >> 4) << 3)];
#pragma unroll
            for (int j = 0; j < 2; j++)
                bb[j] = *(const short8*)&Vs[buf][(wn * 32 + j * 16 + (lane & 15)) * 64 + kc * 32 + ((lane >> 4) << 3)];
#pragma unroll
            for (int i = 0; i < 2; i++)
#pragma unroll
                for (int j = 0; j < 2; j++)
                    acc[i][j] = __builtin_amdgcn_mfma_f32_16x16x32_bf16(a[i], bb[j], acc[i][j], 0, 0, 0);
        }
        asm volatile("s_waitcnt vmcnt(0)" ::: "memory");
        __syncthreads();
        buf ^= 1;
    }
#undef PVSTAGE

#pragma unroll
    for (int i = 0; i < 2; i++)
#pragma unroll
        for (int j = 0; j < 2; j++) {
            int r0 = m0 + wm * 32 + i * 16 + ((lane >> 4) << 2);
            int col = h * DK_ + wn * 32 + j * 16 + (lane & 15);
#pragma unroll
            for (int jj = 0; jj < 4; jj++)
                ao[(size_t)(b * T_ + r0 + jj) * D_ + col] = f2bf(acc[i][j][jj]);
        }
}

// ---------------- PVAM scores: s[b,m,t] = sum_c tanh(wf[b,t,c]+wp[m,c])*w1[c] ----------------
__device__ __forceinline__ float fast_tanh(float x) {
    x = fminf(10.f, fmaxf(-10.f, x));
    float a = exp2f(x * 2.885390082f);           // e^(2x)
    return (a - 1.f) * __builtin_amdgcn_rcpf(a + 1.f);
}

// grid (8 ttiles, 32 b, 5 mgroups), 256 threads. 32 tokens/block, 8 threads/token, 64 ch/thread,
// 5 m-rows per block -> 5 independent tanh chains (ILP) + 12KB LDS (wp rows + w1 broadcast).
__global__ __launch_bounds__(256) void scores_kernel(const float* __restrict__ wf,
                                                     const int* __restrict__ gpos,
                                                     const float* __restrict__ emb,
                                                     const float* __restrict__ w1,
                                                     float* __restrict__ scores) {
    __shared__ float wpL[5][512];
    __shared__ float w1s[512];
    int tid = threadIdx.x;
    int b = blockIdx.y;
    int mg = blockIdx.z * 5;
    int t = blockIdx.x * 32 + (tid >> 3);
    int cg = tid & 7;
    // stage wp rows (5x512) + w1 (512)
    for (int idx = tid; idx < 5 * 128; idx += 256) {
        int m = idx >> 7, w4 = idx & 127;
        *(float4*)&wpL[m][w4 << 2] = *(const float4*)(emb + (size_t)gpos[mg + m] * D_ + (w4 << 2));
    }
    if (tid < 128) *(float4*)&w1s[tid << 2] = *(const float4*)(w1 + (tid << 2));
    // thread's channels: c = cg*4 + j*32 + i  (j=0..15, i=0..3)
    float4 wfv[16];
    const float* wfr = wf + (size_t)(b * T_ + t) * D_ + (cg << 2);
#pragma unroll
    for (int j = 0; j < 16; j++) wfv[j] = *(const float4*)(wfr + (j << 5));
    __syncthreads();
    float s[5] = {};
#pragma unroll
    for (int j = 0; j < 16; j++) {
        float4 w14 = *(const float4*)&w1s[(cg << 2) + (j << 5)];
#pragma unroll
        for (int m = 0; m < 5; m++) {
            float4 wp4 = *(const float4*)&wpL[m][(cg << 2) + (j << 5)];
            s[m] += fast_tanh(wfv[j].x + wp4.x) * w14.x;
            s[m] += fast_tanh(wfv[j].y + wp4.y) * w14.y;
            s[m] += fast_tanh(wfv[j].z + wp4.z) * w14.z;
            s[m] += fast_tanh(wfv[j].w + wp4.w) * w14.w;
        }
    }
#pragma unroll
    for (int m = 0; m < 5; m++) {
        s[m] += __shfl_xor(s[m], 1);
        s[m] += __shfl_xor(s[m], 2);
        s[m] += __shfl_xor(s[m], 4);
    }
    if (cg == 0) {
#pragma unroll
        for (int m = 0; m < 5; m++)
            scores[((size_t)b * ML_ + mg + m) * T_ + t] = s[m];
    }
}

// softmax over t, in place: 800 rows of 256. grid 200 x 256 threads (wave per row).
__global__ __launch_bounds__(256) void softmax_kernel(float* __restrict__ sc) {
    int wid = threadIdx.x >> 6, lane = threadIdx.x & 63;
    size_t row = (size_t)blockIdx.x * 4 + wid;
    float4* p = (float4*)(sc + row * T_);
    float4 v = p[lane];
    float mx = fmaxf(fmaxf(v.x, v.y), fmaxf(v.z, v.w));
    for (int o = 32; o; o >>= 1) mx = fmaxf(mx, __shfl_xor(mx, o));
    float4 e;
    e.x = __expf(v.x - mx); e.y = __expf(v.y - mx);
    e.z = __expf(v.z - mx); e.w = __expf(v.w - mx);
    float sm = e.x + e.y + e.z + e.w;
    for (int o = 32; o; o >>= 1) sm += __shfl_xor(sm, o);
    float inv = 1.f / sm;
    e.x *= inv; e.y *= inv; e.z *= inv; e.w *= inv;
    p[lane] = e;
}

// weighted sum: out[b,m,c] = sum_t attn[b,m,t]*wf[b,t,c]. grid (5 mgroups, 32 b).
__global__ __launch_bounds__(256) void wsum_kernel(const float* __restrict__ attn,
                                                   const float* __restrict__ wf,
                                                   float* __restrict__ out) {
    __shared__ float at[T_][8];
    int tid = threadIdx.x;
    int b = blockIdx.y, m0 = blockIdx.x * 5;
#pragma unroll
    for (int q = 0; q < 5; q++) {
        float a = attn[((size_t)b * ML_ + m0 + q) * T_ + tid];
        at[tid][q] = a;
    }
    __syncthreads();
    int c0 = tid << 1;
    const float* wfb = wf + (size_t)b * T_ * D_ + c0;
    float acc[5][2] = {};
    for (int t = 0; t < T_; t++) {
        float2 v = *(const float2*)(wfb + (size_t)t * D_);
        float4 a4 = *(const float4*)&at[t][0];
        float a5 = at[t][4];
        acc[0][0] += a4.x * v.x; acc[0][1] += a4.x * v.y;
        acc[1][0] += a4.y * v.x; acc[1][1] += a4.y * v.y;
        acc[2][0] += a4.z * v.x; acc[2][1] += a4.z * v.y;
        acc[3][0] += a4.w * v.x; acc[3][1] += a4.w * v.y;
        acc[4][0] += a5 * v.x;   acc[4][1] += a5 * v.y;
    }
#pragma unroll
    for (int q = 0; q < 5; q++) {
        float2 o;
        o.x = acc[q][0]; o.y = acc[q][1];
        *(float2*)(out + ((size_t)b * ML_ + m0 + q) * D_ + c0) = o;
    }
}

extern "C" void kernel_launch(void* const* d_in, const int* in_sizes, int n_in,
                              void* d_out, int out_size, void* d_ws, size_t ws_size,
                              hipStream_t stream) {
    (void)in_sizes; (void)n_in; (void)out_size; (void)ws_size;
    const float* x        = (const float*)d_in[0];
    const int*   epos     = (const int*)d_in[1];
    const int*   gpos     = (const int*)d_in[2];
    const float* pos_tab  = (const float*)d_in[3];
    const float* ln1_s    = (const float*)d_in[4];
    const float* ln1_b    = (const float*)d_in[5];
    const float* Wq       = (const float*)d_in[6];
    const float* bq       = (const float*)d_in[7];
    const float* Wk       = (const float*)d_in[8];
    const float* bk       = (const float*)d_in[9];
    const float* Wv       = (const float*)d_in[10];
    const float* bv       = (const float*)d_in[11];
    const float* Wo       = (const float*)d_in[12];
    const float* bo       = (const float*)d_in[13];
    const float* ln2_s    = (const float*)d_in[14];
    const float* ln2_b    = (const float*)d_in[15];
    const float* W1       = (const float*)d_in[16];
    const float* b1       = (const float*)d_in[17];
    const float* W2       = (const float*)d_in[18];
    const float* b2       = (const float*)d_in[19];
    const float* lnf_s    = (const float*)d_in[20];
    const float* lnf_b    = (const float*)d_in[21];
    const float* fc0_w    = (const float*)d_in[22];
    const float* fc0_b    = (const float*)d_in[23];
    const float* emb      = (const float*)d_in[24];
    const float* fc1_w    = (const float*)d_in[25];

    char* ws = (char*)d_ws;
    float*    enc = (float*)(ws);                       // 16.78 MB
    ushort_t* hi  = (ushort_t*)(ws + 16777216);         // 8.39 MB
    ushort_t* qb  = (ushort_t*)(ws + 25165824);         // 8.39 MB
    ushort_t* kb  = (ushort_t*)(ws + 33554432);         // 8.39 MB (lo overlays later)
    ushort_t* lo  = (ushort_t*)(ws + 33554432);
    float*    scb = (float*)(ws + 33554432);            // scores 800KB (after fc0, lo dead)
    ushort_t* vt  = (ushort_t*)(ws + 41943040);         // 8.39 MB (h1 overlays later)
    ushort_t* h1  = (ushort_t*)(ws + 41943040);
    ushort_t* ao  = (ushort_t*)(ws + 50331648);         // 8.39 MB
    ushort_t* P   = (ushort_t*)(ws + 58720256);         // 16.78 MB half-batch (wf overlays)
    float*    wf  = (float*)(ws + 58720256);
    ushort_t* wt  = (ushort_t*)(ws + 75497472);         // 7.34 MB (14 slices of 512KB)
    const size_t WSL = (size_t)D_ * D_;

    convert_w_kernel<<<13 * 64, 256, 0, stream>>>(Wq, Wk, Wv, Wo, W1, W2, fc0_w, wt);
    prep_kernel<<<dim3(4, 8, 32), 256, 0, stream>>>(x, epos, pos_tab, enc);

    for (int l = 0; l < 2; l++) {
        size_t o1 = (size_t)l * D_;
        const ushort_t* WqT = wt + (l * 6 + 0) * WSL;
        const ushort_t* WkT = wt + (l * 6 + 1) * WSL;
        const ushort_t* WvT = wt + (l * 6 + 2) * WSL;
        const ushort_t* WoT = wt + (l * 6 + 3) * WSL;
        const ushort_t* W1T = wt + (l * 6 + 4) * WSL;
        const ushort_t* W2T = wt + (l * 6 + 5) * WSL;

        ln_kernel<false><<<2048, 256, 0, stream>>>(enc, ln1_s + o1, ln1_b + o1, hi, nullptr);
        gemm_kernel<0><<<256, 256, 0, stream>>>(hi, nullptr, nullptr, WqT, nullptr, nullptr, 1, bq + o1, nullptr, nullptr, qb);
        gemm_kernel<0><<<256, 256, 0, stream>>>(hi, nullptr, nullptr, WkT, nullptr, nullptr, 1, bk + o1, nullptr, nullptr, kb);
        gemm_kernel<1><<<256, 256, 0, stream>>>(hi, nullptr, nullptr, WvT, nullptr, nullptr, 1, bv + o1, nullptr, nullptr, vt);
        for (int half = 0; half < 2; half++) {
            sgemm_sm_kernel<<<dim3(2, 128), 256, 0, stream>>>(qb, kb, P, half * 128);
            pv_kernel<<<dim3(4, 128), 256, 0, stream>>>(P, vt, ao, half * 128);
        }
        gemm_kernel<2><<<256, 256, 0, stream>>>(ao, nullptr, nullptr, WoT, nullptr, nullptr, 1, bo + o1, enc, enc, nullptr);
        ln_kernel<false><<<2048, 256, 0, stream>>>(enc, ln2_s + o1, ln2_b + o1, hi, nullptr);
        gemm_kernel<3><<<256, 256, 0, stream>>>(hi, nullptr, nullptr, W1T, nullptr, nullptr, 1, b1 + o1, nullptr, nullptr, h1);
        gemm_kernel<2><<<256, 256, 0, stream>>>(h1, nullptr, nullptr, W2T, nullptr, nullptr, 1, b2 + o1, enc, enc, nullptr);
    }

    ln_kernel<true><<<2048, 256, 0, stream>>>(enc, lnf_s, lnf_b, hi, lo);
    // fc0 split-bf16: Ah*Wh + Al*Wh + Ah*Wl
    gemm_kernel<4><<<256, 256, 0, stream>>>(hi, lo, hi, wt + 12 * WSL, wt + 12 * WSL, wt + 13 * WSL, 3,
                                            fc0_b, nullptr, wf, nullptr);
    scores_kernel<<<dim3(8, 32, 5), 256, 0, stream>>>(wf, gpos, emb, fc1_w, scb);
    softmax_kernel<<<200, 256, 0, stream>>>(scb);
    wsum_kernel<<<dim3(5, 32), 256, 0, stream>>>(scb, wf, (float*)d_out);
}

// Round 5
// 309.864 us; speedup vs baseline: 5.0420x; 1.2385x over previous
//
#include <hip/hip_runtime.h>
#include <math.h>

#define B_ 32
#define D_ 512
#define T_ 256
#define NH_ 8
#define DK_ 64
#define ML_ 25

typedef unsigned short ushort_t;
using short8 = __attribute__((ext_vector_type(8))) short;
using f32x4  = __attribute__((ext_vector_type(4))) float;

__device__ __forceinline__ ushort_t f2bf(float f) {
    unsigned u = __float_as_uint(f);
    unsigned r = (u + 0x7fffu + ((u >> 16) & 1u)) >> 16;
    return (ushort_t)r;
}
__device__ __forceinline__ float bf2f(ushort_t h) {
    return __uint_as_float(((unsigned)h) << 16);
}
__device__ __forceinline__ void gl16(const void* g, void* l) {
    __builtin_amdgcn_global_load_lds((const __attribute__((address_space(1))) void*)g,
                                     (__attribute__((address_space(3))) void*)l, 16, 0, 0);
}
#define ZERO4(v) { (v)[0]=0.f; (v)[1]=0.f; (v)[2]=0.f; (v)[3]=0.f; }

// ---------------- prep: enc[b,t,c] = x[b,c,t]*sqrt(512) + pos[epos[t],c]  (LDS transpose) ----------------
__global__ __launch_bounds__(256) void prep_kernel(const float* __restrict__ x,
                                                   const int* __restrict__ epos,
                                                   const float* __restrict__ pos,
                                                   float* __restrict__ enc) {
    __shared__ float ld[64][65];
    int tt = blockIdx.x, ct = blockIdx.y, b = blockIdx.z;
    int t0 = tt * 64, c0 = ct * 64;
    int tid = threadIdx.x;
    int r = tid >> 4, c4 = (tid & 15) << 2;
#pragma unroll
    for (int p = 0; p < 4; p++) {
        int row = p * 16 + r;  // channel within tile
        float4 v = *(const float4*)(x + ((size_t)(b * D_ + c0 + row) * T_ + t0) + c4);
        ld[row][c4 + 0] = v.x; ld[row][c4 + 1] = v.y; ld[row][c4 + 2] = v.z; ld[row][c4 + 3] = v.w;
    }
    __syncthreads();
#pragma unroll
    for (int p = 0; p < 4; p++) {
        int tr = p * 16 + r;   // token within tile
        int ep = epos[t0 + tr];
        float4 pv = *(const float4*)(pos + (size_t)ep * D_ + c0 + c4);
        float4 o;
        o.x = ld[c4 + 0][tr] * 22.627417f + pv.x;
        o.y = ld[c4 + 1][tr] * 22.627417f + pv.y;
        o.z = ld[c4 + 2][tr] * 22.627417f + pv.z;
        o.w = ld[c4 + 3][tr] * 22.627417f + pv.w;
        *(float4*)(enc + (size_t)(b * T_ + t0 + tr) * D_ + c0 + c4) = o;
    }
}

// ---------------- weight convert: WT[n][k] = bf16(W[k][n]); fc0 also lo ----------------
__global__ __launch_bounds__(256) void convert_w_kernel(const float* __restrict__ Wq,
                                                        const float* __restrict__ Wk,
                                                        const float* __restrict__ Wv,
                                                        const float* __restrict__ Wo,
                                                        const float* __restrict__ W1,
                                                        const float* __restrict__ W2,
                                                        const float* __restrict__ fc0,
                                                        ushort_t* __restrict__ wt) {
    __shared__ float ld[64][65];
    int m = blockIdx.x >> 6;
    int tile = blockIdx.x & 63;
    int tn = tile >> 3, tk = tile & 7;
    int n0 = tn * 64, k0 = tk * 64;
    const float* src;
    if (m < 12) {
        int l = m / 6, w = m % 6;
        const float* bases[6] = {Wq, Wk, Wv, Wo, W1, W2};
        src = bases[w] + (size_t)l * D_ * D_;
    } else {
        src = fc0;
    }
    int tid = threadIdx.x;
    int r = tid >> 4, c4 = (tid & 15) << 2;
#pragma unroll
    for (int p = 0; p < 4; p++) {
        int row = p * 16 + r;  // k index
        float4 v = *(const float4*)(src + (size_t)(k0 + row) * D_ + n0 + c4);
        ld[row][c4 + 0] = v.x; ld[row][c4 + 1] = v.y; ld[row][c4 + 2] = v.z; ld[row][c4 + 3] = v.w;
    }
    __syncthreads();
    ushort_t* dsth = wt + (size_t)m * D_ * D_;
    ushort_t* dstl = wt + (size_t)13 * D_ * D_;
#pragma unroll
    for (int p = 0; p < 4; p++) {
        int n = p * 16 + r;
        int kc = c4;
        ushort_t h[4], lo[4];
#pragma unroll
        for (int i = 0; i < 4; i++) {
            float f = ld[kc + i][n];
            h[i] = f2bf(f);
            lo[i] = f2bf(f - bf2f(h[i]));
        }
        *(ushort4*)(dsth + (size_t)(n0 + n) * D_ + k0 + kc) = make_ushort4(h[0], h[1], h[2], h[3]);
        if (m == 12)
            *(ushort4*)(dstl + (size_t)(n0 + n) * D_ + k0 + kc) = make_ushort4(lo[0], lo[1], lo[2], lo[3]);
    }
}

// ---------------- LayerNorm -> bf16 hi (+lo) ----------------
template<bool LO>
__global__ __launch_bounds__(256) void ln_kernel(const float* __restrict__ x,
                                                 const float* __restrict__ s,
                                                 const float* __restrict__ b,
                                                 ushort_t* __restrict__ yh,
                                                 ushort_t* __restrict__ yl) {
    int wid = threadIdx.x >> 6, lane = threadIdx.x & 63;
    size_t row = (size_t)blockIdx.x * 4 + wid;
    const float4* xr = (const float4*)(x + row * D_);
    float4 v0 = xr[lane * 2], v1 = xr[lane * 2 + 1];
    float sum = v0.x + v0.y + v0.z + v0.w + v1.x + v1.y + v1.z + v1.w;
    for (int o = 32; o; o >>= 1) sum += __shfl_xor(sum, o);
    float mean = sum * (1.f / 512.f);
    float d[8] = {v0.x - mean, v0.y - mean, v0.z - mean, v0.w - mean,
                  v1.x - mean, v1.y - mean, v1.z - mean, v1.w - mean};
    float vs = 0.f;
#pragma unroll
    for (int i = 0; i < 8; i++) vs += d[i] * d[i];
    for (int o = 32; o; o >>= 1) vs += __shfl_xor(vs, o);
    float rs = 1.f / sqrtf(vs * (1.f / 512.f) + 1e-5f);
    const float4* s4 = (const float4*)s;
    const float4* b4 = (const float4*)b;
    float4 sa = s4[lane * 2], sb = s4[lane * 2 + 1];
    float4 ba = b4[lane * 2], bb = b4[lane * 2 + 1];
    float o8[8];
    o8[0] = d[0] * rs * sa.x + ba.x; o8[1] = d[1] * rs * sa.y + ba.y;
    o8[2] = d[2] * rs * sa.z + ba.z; o8[3] = d[3] * rs * sa.w + ba.w;
    o8[4] = d[4] * rs * sb.x + bb.x; o8[5] = d[5] * rs * sb.y + bb.y;
    o8[6] = d[6] * rs * sb.z + bb.z; o8[7] = d[7] * rs * sb.w + bb.w;
    ushort_t h[8];
#pragma unroll
    for (int i = 0; i < 8; i++) h[i] = f2bf(o8[i]);
    uint4 u;
    u.x = (unsigned)h[0] | ((unsigned)h[1] << 16);
    u.y = (unsigned)h[2] | ((unsigned)h[3] << 16);
    u.z = (unsigned)h[4] | ((unsigned)h[5] << 16);
    u.w = (unsigned)h[6] | ((unsigned)h[7] << 16);
    *(uint4*)(yh + row * D_ + lane * 8) = u;
    if (LO) {
        ushort_t l8[8];
#pragma unroll
        for (int i = 0; i < 8; i++) l8[i] = f2bf(o8[i] - bf2f(h[i]));
        uint4 ul;
        ul.x = (unsigned)l8[0] | ((unsigned)l8[1] << 16);
        ul.y = (unsigned)l8[2] | ((unsigned)l8[3] << 16);
        ul.z = (unsigned)l8[4] | ((unsigned)l8[5] << 16);
        ul.w = (unsigned)l8[6] | ((unsigned)l8[7] << 16);
        *(uint4*)(yl + row * D_ + lane * 8) = ul;
    }
}

// ---------------- MFMA GEMM: C[8192,N] = sum_seg A_seg[8192,512] * WT_seg[N,512]^T ----------------
// EPI: 2=f32(+bias+res), 3=relu->bf16, 4=f32(+bias), 5=QKV fused (q,k plain bf16; v transposed)
// LDS tiles use granule-XOR swizzle (T2): source-preswizzled on stage, XOR'd on read.
template<int EPI>
__global__ __launch_bounds__(256) void gemm_kernel(const ushort_t* __restrict__ A0,
                                                   const ushort_t* __restrict__ A1,
                                                   const ushort_t* __restrict__ A2,
                                                   const ushort_t* __restrict__ B0,
                                                   const ushort_t* __restrict__ B1,
                                                   const ushort_t* __restrict__ B2,
                                                   int nseg, int nbn,
                                                   const float* __restrict__ bias,
                                                   const float* __restrict__ bias2,
                                                   const float* __restrict__ bias3,
                                                   const float* __restrict__ res,
                                                   float* __restrict__ outF,
                                                   ushort_t* __restrict__ outB) {
    __shared__ ushort_t As[2][128 * 64];
    __shared__ ushort_t Bs[2][128 * 64];
    int tid = threadIdx.x;
    // XCD-chunked bijective swizzle (grid % 8 == 0)
    int g = blockIdx.x;
    int per = gridDim.x >> 3;
    int lin = (g & 7) * per + (g >> 3);
    int bm = lin / nbn, bn = lin % nbn;

    int lane = tid & 63;
    int wid = tid >> 6;
    int wm = wid >> 1, wn = wid & 1;
    int xr = (lane & 7) << 3;

    f32x4 acc[4][4];
#pragma unroll
    for (int i = 0; i < 4; i++)
#pragma unroll
        for (int j = 0; j < 4; j++) ZERO4(acc[i][j]);

    int nt = nseg * 8;

#define STAGE(kt, buf)                                                                  \
    {                                                                                   \
        int seg_ = (kt) >> 3;                                                           \
        int k0_ = ((kt) & 7) * 64;                                                      \
        const ushort_t* Asg = seg_ == 0 ? A0 : (seg_ == 1 ? A1 : A2);                   \
        const ushort_t* Bsg = seg_ == 0 ? B0 : (seg_ == 1 ? B1 : B2);                   \
        _Pragma("unroll")                                                               \
        for (int it = 0; it < 4; it++) {                                                \
            int uu = tid + it * 256;                                                    \
            int row_ = uu >> 3;                                                         \
            int kb_ = (((uu & 7) ^ (row_ & 7)) << 3);                                   \
            gl16(Asg + (size_t)(bm * 128 + row_) * 512 + k0_ + kb_, &As[buf][uu * 8]);  \
            gl16(Bsg + (size_t)(bn * 128 + row_) * 512 + k0_ + kb_, &Bs[buf][uu * 8]);  \
        }                                                                               \
    }

    STAGE(0, 0);
    asm volatile("s_waitcnt vmcnt(0)" ::: "memory");
    __syncthreads();

    int buf = 0;
    for (int t = 0; t < nt; t++) {
        if (t + 1 < nt) STAGE(t + 1, buf ^ 1);
#pragma unroll
        for (int kc = 0; kc < 2; kc++) {
            short8 a[4], b[4];
            int koff = (kc * 32 + ((lane >> 4) << 3)) ^ xr;
#pragma unroll
            for (int i = 0; i < 4; i++)
                a[i] = *(const short8*)&As[buf][(wm * 64 + i * 16 + (lane & 15)) * 64 + koff];
#pragma unroll
            for (int j = 0; j < 4; j++)
                b[j] = *(const short8*)&Bs[buf][(wn * 64 + j * 16 + (lane & 15)) * 64 + koff];
#pragma unroll
            for (int i = 0; i < 4; i++)
#pragma unroll
                for (int j = 0; j < 4; j++)
                    acc[i][j] = __builtin_amdgcn_mfma_f32_16x16x32_bf16(a[i], b[j], acc[i][j], 0, 0, 0);
        }
        asm volatile("s_waitcnt vmcnt(0)" ::: "memory");
        __syncthreads();
        buf ^= 1;
    }
#undef STAGE

#pragma unroll
    for (int i = 0; i < 4; i++) {
#pragma unroll
        for (int j = 0; j < 4; j++) {
            int r0 = bm * 128 + wm * 64 + i * 16 + ((lane >> 4) << 2);
            int col = bn * 128 + wn * 64 + j * 16 + (lane & 15);
            int seg = col >> 9;
            int ccol = col & 511;
            const float* bp = bias;
            if (EPI == 5) bp = (seg == 0) ? bias : (seg == 1 ? bias2 : bias3);
            float bc = bp[EPI == 5 ? ccol : col];
#pragma unroll
            for (int jj = 0; jj < 4; jj++) {
                float v = acc[i][j][jj] + bc;
                int row = r0 + jj;
                size_t idx = (size_t)row * 512 + col;
                if (EPI == 2) {
                    outF[idx] = v + res[idx];
                } else if (EPI == 3) {
                    outB[idx] = f2bf(fmaxf(v, 0.f));
                } else if (EPI == 4) {
                    outF[idx] = v;
                } else if (EPI == 5) {
                    if (seg < 2) {
                        outB[(size_t)seg * 4194304 + (size_t)row * 512 + ccol] = f2bf(v);
                    } else {
                        int bb2 = row >> 8, t2 = row & 255;
                        outB[(size_t)2 * 4194304 +
                             ((size_t)(bb2 * 8 + (ccol >> 6)) * 64 + (ccol & 63)) * 256 + t2] = f2bf(v);
                    }
                }
            }
        }
    }
}

// ---------------- fused attention: block = (64 q-rows, bh). QK^T -> softmax -> PV ----------------
__global__ __launch_bounds__(256) void attn_fused_kernel(const ushort_t* __restrict__ q,
                                                         const ushort_t* __restrict__ k,
                                                         const ushort_t* __restrict__ vt,
                                                         ushort_t* __restrict__ ao) {
    __shared__ ushort_t KVs[256 * 64];   // K tile, then reused for V^T (64 dk x 256 t)
    __shared__ ushort_t Ps[64 * 256];    // P (bf16), XOR-swizzled
    int tid = threadIdx.x;
    int lane = tid & 63;
    int wid = tid >> 6;
    int m0 = blockIdx.x * 64;
    int bh = blockIdx.y;
    int b = bh >> 3, h = bh & 7;
    int xr = (lane & 7) << 3;

    // stage K (256x64), source-preswizzled
#pragma unroll
    for (int it = 0; it < 8; it++) {
        int uu = tid + it * 256;
        int row = uu >> 3;
        int gx = ((uu & 7) ^ (row & 7)) << 3;
        gl16(k + (size_t)(b * T_ + row) * D_ + h * DK_ + gx, &KVs[uu * 8]);
    }
    // Q direct to regs (wave wid owns rows m0+wid*16 .. +15)
    short8 qa0, qa1;
    {
        int qrow = m0 + wid * 16 + (lane & 15);
        const ushort_t* qp = q + (size_t)(b * T_ + qrow) * D_ + h * DK_ + ((lane >> 4) << 3);
        qa0 = *(const short8*)(qp);
        qa1 = *(const short8*)(qp + 32);
    }
    f32x4 acc[16];
#pragma unroll
    for (int j = 0; j < 16; j++) ZERO4(acc[j]);
    asm volatile("s_waitcnt vmcnt(0)" ::: "memory");
    __syncthreads();

#pragma unroll
    for (int j = 0; j < 16; j++) {
        int krow = j * 16 + (lane & 15);
        short8 b0 = *(const short8*)&KVs[krow * 64 + ((((lane >> 4) << 3)) ^ xr)];
        short8 b1 = *(const short8*)&KVs[krow * 64 + ((32 + ((lane >> 4) << 3)) ^ xr)];
        acc[j] = __builtin_amdgcn_mfma_f32_16x16x32_bf16(qa0, b0, acc[j], 0, 0, 0);
        acc[j] = __builtin_amdgcn_mfma_f32_16x16x32_bf16(qa1, b1, acc[j], 0, 0, 0);
    }
    __syncthreads();   // all K reads done; KVs can be overwritten

    // stage V^T (64 dk x 256 t) into KVs while softmax runs
#pragma unroll
    for (int it = 0; it < 8; it++) {
        int uu = tid + it * 256;
        int row = uu >> 5;
        int gx = ((uu & 31) ^ (row & 7)) << 3;
        gl16(vt + ((size_t)bh * DK_ + row) * T_ + gx, &KVs[uu * 8]);
    }

    // softmax over 256 cols; lane group (lane>>4) holds rows +jj
    const float C = 0.125f * 1.44269504f;
#pragma unroll
    for (int jj = 0; jj < 4; jj++) {
        float mx = -1e30f;
#pragma unroll
        for (int j = 0; j < 16; j++) mx = fmaxf(mx, acc[j][jj]);
#pragma unroll
        for (int msk = 1; msk < 16; msk <<= 1) mx = fmaxf(mx, __shfl_xor(mx, msk));
        float sm = 0.f;
#pragma unroll
        for (int j = 0; j < 16; j++) {
            float e = __builtin_amdgcn_exp2f((acc[j][jj] - mx) * C);
            acc[j][jj] = e;
            sm += e;
        }
#pragma unroll
        for (int msk = 1; msk < 16; msk <<= 1) sm += __shfl_xor(sm, msk);
        float inv = 1.f / sm;
#pragma unroll
        for (int j = 0; j < 16; j++) acc[j][jj] *= inv;
    }
    // write P to LDS (swizzled)
#pragma unroll
    for (int j = 0; j < 16; j++) {
#pragma unroll
        for (int jj = 0; jj < 4; jj++) {
            int row = wid * 16 + ((lane >> 4) << 2) + jj;
            int col = j * 16 + (lane & 15);
            Ps[row * 256 + (col ^ ((row & 7) << 3))] = f2bf(acc[j][jj]);
        }
    }
    asm volatile("s_waitcnt vmcnt(0)" ::: "memory");
    __syncthreads();

    // PV: out 64x64; wave (wm,wn) does rows wm*32+i*16, cols wn*32+j*16
    int wm = wid >> 1, wn = wid & 1;
    f32x4 acc2[2][2];
#pragma unroll
    for (int i = 0; i < 2; i++)
#pragma unroll
        for (int j = 0; j < 2; j++) ZERO4(acc2[i][j]);
#pragma unroll
    for (int kc = 0; kc < 8; kc++) {
        int off = (kc * 32 + ((lane >> 4) << 3)) ^ xr;
        short8 a0 = *(const short8*)&Ps[(wm * 32 + (lane & 15)) * 256 + off];
        short8 a1 = *(const short8*)&Ps[(wm * 32 + 16 + (lane & 15)) * 256 + off];
        short8 b0 = *(const short8*)&KVs[(wn * 32 + (lane & 15)) * 256 + off];
        short8 b1 = *(const short8*)&KVs[(wn * 32 + 16 + (lane & 15)) * 256 + off];
        acc2[0][0] = __builtin_amdgcn_mfma_f32_16x16x32_bf16(a0, b0, acc2[0][0], 0, 0, 0);
        acc2[0][1] = __builtin_amdgcn_mfma_f32_16x16x32_bf16(a0, b1, acc2[0][1], 0, 0, 0);
        acc2[1][0] = __builtin_amdgcn_mfma_f32_16x16x32_bf16(a1, b0, acc2[1][0], 0, 0, 0);
        acc2[1][1] = __builtin_amdgcn_mfma_f32_16x16x32_bf16(a1, b1, acc2[1][1], 0, 0, 0);
    }
#pragma unroll
    for (int i = 0; i < 2; i++)
#pragma unroll
        for (int j = 0; j < 2; j++)
#pragma unroll
            for (int jj = 0; jj < 4; jj++)
                ao[(size_t)(b * T_ + m0 + wm * 32 + i * 16 + ((lane >> 4) << 2) + jj) * D_ +
                   h * DK_ + wn * 32 + j * 16 + (lane & 15)] = f2bf(acc2[i][j][jj]);
}

// ---------------- PVAM scores: s[b,m,t] = Sum_c w1[c] - 2*Sum_c w1[c]/(exp2(K*(wf+wp))+1) ----------------
// grid (8 ttiles, 32 b, 5 mgroups), 256 threads. 32 tokens/block, 8 threads/token, 64 ch/thread.
__global__ __launch_bounds__(256) void scores_kernel(const float* __restrict__ wf,
                                                     const int* __restrict__ gpos,
                                                     const float* __restrict__ emb,
                                                     const float* __restrict__ w1,
                                                     float* __restrict__ scores) {
    __shared__ float wpL[5][512];   // K2 * wp
    __shared__ float w1m2[512];     // -2 * w1
    const float K2 = 2.885390082f;  // 2*log2(e)
    int tid = threadIdx.x;
    int b = blockIdx.y;
    int mg = blockIdx.z * 5;
    int t = blockIdx.x * 32 + (tid >> 3);
    int cg = tid & 7;
    for (int idx = tid; idx < 5 * 128; idx += 256) {
        int m = idx >> 7, w4 = idx & 127;
        float4 v = *(const float4*)(emb + (size_t)gpos[mg + m] * D_ + (w4 << 2));
        v.x *= K2; v.y *= K2; v.z *= K2; v.w *= K2;
        *(float4*)&wpL[m][w4 << 2] = v;
    }
    if (tid < 128) {
        float4 v = *(const float4*)(w1 + (tid << 2));
        v.x *= -2.f; v.y *= -2.f; v.z *= -2.f; v.w *= -2.f;
        *(float4*)&w1m2[tid << 2] = v;
    }
    // thread's channels: c = cg*4 + j*32 + i  (j=0..15, i=0..3)
    float4 wfs[16];
    float W1S = 0.f;
    const float* wfr = wf + (size_t)(b * T_ + t) * D_ + (cg << 2);
#pragma unroll
    for (int j = 0; j < 16; j++) {
        float4 v = *(const float4*)(wfr + (j << 5));
        wfs[j].x = v.x * K2; wfs[j].y = v.y * K2; wfs[j].z = v.z * K2; wfs[j].w = v.w * K2;
        float4 wv = *(const float4*)(w1 + (cg << 2) + (j << 5));
        W1S += wv.x + wv.y + wv.z + wv.w;
    }
    __syncthreads();
    float s[5] = {W1S, W1S, W1S, W1S, W1S};
#pragma unroll
    for (int j = 0; j < 16; j++) {
        float4 w14 = *(const float4*)&w1m2[(cg << 2) + (j << 5)];
#pragma unroll
        for (int m = 0; m < 5; m++) {
            float4 wp4 = *(const float4*)&wpL[m][(cg << 2) + (j << 5)];
            s[m] += w14.x * __builtin_amdgcn_rcpf(__builtin_amdgcn_exp2f(wfs[j].x + wp4.x) + 1.f);
            s[m] += w14.y * __builtin_amdgcn_rcpf(__builtin_amdgcn_exp2f(wfs[j].y + wp4.y) + 1.f);
            s[m] += w14.z * __builtin_amdgcn_rcpf(__builtin_amdgcn_exp2f(wfs[j].z + wp4.z) + 1.f);
            s[m] += w14.w * __builtin_amdgcn_rcpf(__builtin_amdgcn_exp2f(wfs[j].w + wp4.w) + 1.f);
        }
    }
#pragma unroll
    for (int m = 0; m < 5; m++) {
        s[m] += __shfl_xor(s[m], 1);
        s[m] += __shfl_xor(s[m], 2);
        s[m] += __shfl_xor(s[m], 4);
    }
    if (cg == 0) {
#pragma unroll
        for (int m = 0; m < 5; m++)
            scores[((size_t)b * ML_ + mg + m) * T_ + t] = s[m];
    }
}

// softmax over t, in place: 800 rows of 256. grid 200 x 256 threads (wave per row).
__global__ __launch_bounds__(256) void softmax_kernel(float* __restrict__ sc) {
    int wid = threadIdx.x >> 6, lane = threadIdx.x & 63;
    size_t row = (size_t)blockIdx.x * 4 + wid;
    float4* p = (float4*)(sc + row * T_);
    float4 v = p[lane];
    float mx = fmaxf(fmaxf(v.x, v.y), fmaxf(v.z, v.w));
    for (int o = 32; o; o >>= 1) mx = fmaxf(mx, __shfl_xor(mx, o));
    float4 e;
    e.x = __expf(v.x - mx); e.y = __expf(v.y - mx);
    e.z = __expf(v.z - mx); e.w = __expf(v.w - mx);
    float sm = e.x + e.y + e.z + e.w;
    for (int o = 32; o; o >>= 1) sm += __shfl_xor(sm, o);
    float inv = 1.f / sm;
    e.x *= inv; e.y *= inv; e.z *= inv; e.w *= inv;
    p[lane] = e;
}

// weighted sum: out[b,m,c] = sum_t attn[b,m,t]*wf[b,t,c]. grid (5 mgroups, 32 b).
__global__ __launch_bounds__(256) void wsum_kernel(const float* __restrict__ attn,
                                                   const float* __restrict__ wf,
                                                   float* __restrict__ out) {
    __shared__ float at[T_][8];
    int tid = threadIdx.x;
    int b = blockIdx.y, m0 = blockIdx.x * 5;
#pragma unroll
    for (int q = 0; q < 5; q++) {
        float a = attn[((size_t)b * ML_ + m0 + q) * T_ + tid];
        at[tid][q] = a;
    }
    __syncthreads();
    int c0 = tid << 1;
    const float* wfb = wf + (size_t)b * T_ * D_ + c0;
    float acc[5][2] = {};
    for (int t = 0; t < T_; t++) {
        float2 v = *(const float2*)(wfb + (size_t)t * D_);
        float4 a4 = *(const float4*)&at[t][0];
        float a5 = at[t][4];
        acc[0][0] += a4.x * v.x; acc[0][1] += a4.x * v.y;
        acc[1][0] += a4.y * v.x; acc[1][1] += a4.y * v.y;
        acc[2][0] += a4.z * v.x; acc[2][1] += a4.z * v.y;
        acc[3][0] += a4.w * v.x; acc[3][1] += a4.w * v.y;
        acc[4][0] += a5 * v.x;   acc[4][1] += a5 * v.y;
    }
#pragma unroll
    for (int q = 0; q < 5; q++) {
        float2 o;
        o.x = acc[q][0]; o.y = acc[q][1];
        *(float2*)(out + ((size_t)b * ML_ + m0 + q) * D_ + c0) = o;
    }
}

extern "C" void kernel_launch(void* const* d_in, const int* in_sizes, int n_in,
                              void* d_out, int out_size, void* d_ws, size_t ws_size,
                              hipStream_t stream) {
    (void)in_sizes; (void)n_in; (void)out_size; (void)ws_size;
    const float* x        = (const float*)d_in[0];
    const int*   epos     = (const int*)d_in[1];
    const int*   gpos     = (const int*)d_in[2];
    const float* pos_tab  = (const float*)d_in[3];
    const float* ln1_s    = (const float*)d_in[4];
    const float* ln1_b    = (const float*)d_in[5];
    const float* Wq       = (const float*)d_in[6];
    const float* bq       = (const float*)d_in[7];
    const float* Wk       = (const float*)d_in[8];
    const float* bk       = (const float*)d_in[9];
    const float* Wv       = (const float*)d_in[10];
    const float* bv       = (const float*)d_in[11];
    const float* Wo       = (const float*)d_in[12];
    const float* bo       = (const float*)d_in[13];
    const float* ln2_s    = (const float*)d_in[14];
    const float* ln2_b    = (const float*)d_in[15];
    const float* W1       = (const float*)d_in[16];
    const float* b1       = (const float*)d_in[17];
    const float* W2       = (const float*)d_in[18];
    const float* b2       = (const float*)d_in[19];
    const float* lnf_s    = (const float*)d_in[20];
    const float* lnf_b    = (const float*)d_in[21];
    const float* fc0_w    = (const float*)d_in[22];
    const float* fc0_b    = (const float*)d_in[23];
    const float* emb      = (const float*)d_in[24];
    const float* fc1_w    = (const float*)d_in[25];

    char* ws = (char*)d_ws;
    float*    enc = (float*)(ws);                       // 16.78 MB
    ushort_t* hi  = (ushort_t*)(ws + 16777216);         // 8.39 MB
    ushort_t* qb  = (ushort_t*)(ws + 25165824);         // 8.39 MB (qkv base; kb/vt follow)
    ushort_t* kb  = (ushort_t*)(ws + 33554432);         // 8.39 MB (lo/scb overlay later)
    ushort_t* lo  = (ushort_t*)(ws + 33554432);
    float*    scb = (float*)(ws + 33554432);            // scores 800KB (after fc0, kb/lo dead)
    ushort_t* vt  = (ushort_t*)(ws + 41943040);         // 8.39 MB (h1 overlays later)
    ushort_t* h1  = (ushort_t*)(ws + 41943040);
    ushort_t* ao  = (ushort_t*)(ws + 50331648);         // 8.39 MB
    float*    wf  = (float*)(ws + 58720256);            // 16.78 MB
    ushort_t* wt  = (ushort_t*)(ws + 75497472);         // 7.34 MB (14 slices of 512KB)
    const size_t WSL = (size_t)D_ * D_;

    convert_w_kernel<<<13 * 64, 256, 0, stream>>>(Wq, Wk, Wv, Wo, W1, W2, fc0_w, wt);
    prep_kernel<<<dim3(4, 8, 32), 256, 0, stream>>>(x, epos, pos_tab, enc);

    for (int l = 0; l < 2; l++) {
        size_t o1 = (size_t)l * D_;
        const ushort_t* WqkvT = wt + (l * 6 + 0) * WSL;   // [1536][512] concat
        const ushort_t* WoT = wt + (l * 6 + 3) * WSL;
        const ushort_t* W1T = wt + (l * 6 + 4) * WSL;
        const ushort_t* W2T = wt + (l * 6 + 5) * WSL;

        ln_kernel<false><<<2048, 256, 0, stream>>>(enc, ln1_s + o1, ln1_b + o1, hi, nullptr);
        gemm_kernel<5><<<768, 256, 0, stream>>>(hi, nullptr, nullptr, WqkvT, nullptr, nullptr,
                                                1, 12, bq + o1, bk + o1, bv + o1, nullptr, nullptr, qb);
        attn_fused_kernel<<<dim3(4, 256), 256, 0, stream>>>(qb, kb, vt, ao);
        gemm_kernel<2><<<256, 256, 0, stream>>>(ao, nullptr, nullptr, WoT, nullptr, nullptr,
                                                1, 4, bo + o1, nullptr, nullptr, enc, enc, nullptr);
        ln_kernel<false><<<2048, 256, 0, stream>>>(enc, ln2_s + o1, ln2_b + o1, hi, nullptr);
        gemm_kernel<3><<<256, 256, 0, stream>>>(hi, nullptr, nullptr, W1T, nullptr, nullptr,
                                                1, 4, b1 + o1, nullptr, nullptr, nullptr, nullptr, h1);
        gemm_kernel<2><<<256, 256, 0, stream>>>(h1, nullptr, nullptr, W2T, nullptr, nullptr,
                                                1, 4, b2 + o1, nullptr, nullptr, enc, enc, nullptr);
    }

    ln_kernel<true><<<2048, 256, 0, stream>>>(enc, lnf_s, lnf_b, hi, lo);
    // fc0 split-bf16: Ah*Wh + Al*Wh + Ah*Wl
    gemm_kernel<4><<<256, 256, 0, stream>>>(hi, lo, hi, wt + 12 * WSL, wt + 12 * WSL, wt + 13 * WSL,
                                            3, 4, fc0_b, nullptr, nullptr, nullptr, wf, nullptr);
    scores_kernel<<<dim3(8, 32, 5), 256, 0, stream>>>(wf, gpos, emb, fc1_w, scb);
    softmax_kernel<<<200, 256, 0, stream>>>(scb);
    wsum_kernel<<<dim3(5, 32), 256, 0, stream>>>(scb, wf, (float*)d_out);
}

// Round 7
// 295.830 us; speedup vs baseline: 5.2811x; 1.0474x over previous
//
#include <hip/hip_runtime.h>
#include <math.h>

#define B_ 32
#define D_ 512
#define T_ 256
#define NH_ 8
#define DK_ 64
#define ML_ 25

typedef unsigned short ushort_t;
using short8 = __attribute__((ext_vector_type(8))) short;
using f32x4  = __attribute__((ext_vector_type(4))) float;

__device__ __forceinline__ ushort_t f2bf(float f) {
    unsigned u = __float_as_uint(f);
    unsigned r = (u + 0x7fffu + ((u >> 16) & 1u)) >> 16;
    return (ushort_t)r;
}
__device__ __forceinline__ float bf2f(ushort_t h) {
    return __uint_as_float(((unsigned)h) << 16);
}
__device__ __forceinline__ void gl16(const void* g, void* l) {
    __builtin_amdgcn_global_load_lds((const __attribute__((address_space(1))) void*)g,
                                     (__attribute__((address_space(3))) void*)l, 16, 0, 0);
}
#define ZERO4(v) { (v)[0]=0.f; (v)[1]=0.f; (v)[2]=0.f; (v)[3]=0.f; }

// ---------------- prep: enc[b,t,c] = x[b,c,t]*sqrt(512) + pos[epos[t],c]  (LDS transpose) ----------------
__global__ __launch_bounds__(256) void prep_kernel(const float* __restrict__ x,
                                                   const int* __restrict__ epos,
                                                   const float* __restrict__ pos,
                                                   float* __restrict__ enc) {
    __shared__ float ld[64][65];
    int tt = blockIdx.x, ct = blockIdx.y, b = blockIdx.z;
    int t0 = tt * 64, c0 = ct * 64;
    int tid = threadIdx.x;
    int r = tid >> 4, c4 = (tid & 15) << 2;
#pragma unroll
    for (int p = 0; p < 4; p++) {
        int row = p * 16 + r;  // channel within tile
        float4 v = *(const float4*)(x + ((size_t)(b * D_ + c0 + row) * T_ + t0) + c4);
        ld[row][c4 + 0] = v.x; ld[row][c4 + 1] = v.y; ld[row][c4 + 2] = v.z; ld[row][c4 + 3] = v.w;
    }
    __syncthreads();
#pragma unroll
    for (int p = 0; p < 4; p++) {
        int tr = p * 16 + r;   // token within tile
        int ep = epos[t0 + tr];
        float4 pv = *(const float4*)(pos + (size_t)ep * D_ + c0 + c4);
        float4 o;
        o.x = ld[c4 + 0][tr] * 22.627417f + pv.x;
        o.y = ld[c4 + 1][tr] * 22.627417f + pv.y;
        o.z = ld[c4 + 2][tr] * 22.627417f + pv.z;
        o.w = ld[c4 + 3][tr] * 22.627417f + pv.w;
        *(float4*)(enc + (size_t)(b * T_ + t0 + tr) * D_ + c0 + c4) = o;
    }
}

// ---------------- weight convert: WT[n][k] = bf16(W[k][n]); fc0 also lo ----------------
__global__ __launch_bounds__(256) void convert_w_kernel(const float* __restrict__ Wq,
                                                        const float* __restrict__ Wk,
                                                        const float* __restrict__ Wv,
                                                        const float* __restrict__ Wo,
                                                        const float* __restrict__ W1,
                                                        const float* __restrict__ W2,
                                                        const float* __restrict__ fc0,
                                                        ushort_t* __restrict__ wt) {
    __shared__ float ld[64][65];
    int m = blockIdx.x >> 6;
    int tile = blockIdx.x & 63;
    int tn = tile >> 3, tk = tile & 7;
    int n0 = tn * 64, k0 = tk * 64;
    const float* src;
    if (m < 12) {
        int l = m / 6, w = m % 6;
        const float* bases[6] = {Wq, Wk, Wv, Wo, W1, W2};
        src = bases[w] + (size_t)l * D_ * D_;
    } else {
        src = fc0;
    }
    int tid = threadIdx.x;
    int r = tid >> 4, c4 = (tid & 15) << 2;
#pragma unroll
    for (int p = 0; p < 4; p++) {
        int row = p * 16 + r;  // k index
        float4 v = *(const float4*)(src + (size_t)(k0 + row) * D_ + n0 + c4);
        ld[row][c4 + 0] = v.x; ld[row][c4 + 1] = v.y; ld[row][c4 + 2] = v.z; ld[row][c4 + 3] = v.w;
    }
    __syncthreads();
    ushort_t* dsth = wt + (size_t)m * D_ * D_;
    ushort_t* dstl = wt + (size_t)13 * D_ * D_;
#pragma unroll
    for (int p = 0; p < 4; p++) {
        int n = p * 16 + r;
        int kc = c4;
        ushort_t h[4], lo[4];
#pragma unroll
        for (int i = 0; i < 4; i++) {
            float f = ld[kc + i][n];
            h[i] = f2bf(f);
            lo[i] = f2bf(f - bf2f(h[i]));
        }
        *(ushort4*)(dsth + (size_t)(n0 + n) * D_ + k0 + kc) = make_ushort4(h[0], h[1], h[2], h[3]);
        if (m == 12)
            *(ushort4*)(dstl + (size_t)(n0 + n) * D_ + k0 + kc) = make_ushort4(lo[0], lo[1], lo[2], lo[3]);
    }
}

// ---------------- LayerNorm -> bf16 hi (+lo) ----------------
template<bool LO>
__global__ __launch_bounds__(256) void ln_kernel(const float* __restrict__ x,
                                                 const float* __restrict__ s,
                                                 const float* __restrict__ b,
                                                 ushort_t* __restrict__ yh,
                                                 ushort_t* __restrict__ yl) {
    int wid = threadIdx.x >> 6, lane = threadIdx.x & 63;
    size_t row = (size_t)blockIdx.x * 4 + wid;
    const float4* xr = (const float4*)(x + row * D_);
    float4 v0 = xr[lane * 2], v1 = xr[lane * 2 + 1];
    float sum = v0.x + v0.y + v0.z + v0.w + v1.x + v1.y + v1.z + v1.w;
    for (int o = 32; o; o >>= 1) sum += __shfl_xor(sum, o);
    float mean = sum * (1.f / 512.f);
    float d[8] = {v0.x - mean, v0.y - mean, v0.z - mean, v0.w - mean,
                  v1.x - mean, v1.y - mean, v1.z - mean, v1.w - mean};
    float vs = 0.f;
#pragma unroll
    for (int i = 0; i < 8; i++) vs += d[i] * d[i];
    for (int o = 32; o; o >>= 1) vs += __shfl_xor(vs, o);
    float rs = 1.f / sqrtf(vs * (1.f / 512.f) + 1e-5f);
    const float4* s4 = (const float4*)s;
    const float4* b4 = (const float4*)b;
    float4 sa = s4[lane * 2], sb = s4[lane * 2 + 1];
    float4 ba = b4[lane * 2], bb = b4[lane * 2 + 1];
    float o8[8];
    o8[0] = d[0] * rs * sa.x + ba.x; o8[1] = d[1] * rs * sa.y + ba.y;
    o8[2] = d[2] * rs * sa.z + ba.z; o8[3] = d[3] * rs * sa.w + ba.w;
    o8[4] = d[4] * rs * sb.x + bb.x; o8[5] = d[5] * rs * sb.y + bb.y;
    o8[6] = d[6] * rs * sb.z + bb.z; o8[7] = d[7] * rs * sb.w + bb.w;
    ushort_t h[8];
#pragma unroll
    for (int i = 0; i < 8; i++) h[i] = f2bf(o8[i]);
    uint4 u;
    u.x = (unsigned)h[0] | ((unsigned)h[1] << 16);
    u.y = (unsigned)h[2] | ((unsigned)h[3] << 16);
    u.z = (unsigned)h[4] | ((unsigned)h[5] << 16);
    u.w = (unsigned)h[6] | ((unsigned)h[7] << 16);
    *(uint4*)(yh + row * D_ + lane * 8) = u;
    if (LO) {
        ushort_t l8[8];
#pragma unroll
        for (int i = 0; i < 8; i++) l8[i] = f2bf(o8[i] - bf2f(h[i]));
        uint4 ul;
        ul.x = (unsigned)l8[0] | ((unsigned)l8[1] << 16);
        ul.y = (unsigned)l8[2] | ((unsigned)l8[3] << 16);
        ul.z = (unsigned)l8[4] | ((unsigned)l8[5] << 16);
        ul.w = (unsigned)l8[6] | ((unsigned)l8[7] << 16);
        *(uint4*)(yl + row * D_ + lane * 8) = ul;
    }
}

// ---------------- MFMA GEMM: C[8192,N] = sum_seg A_seg[8192,512] * WT_seg[N,512]^T ----------------
// Tile 128x64, 3-deep LDS pipeline with counted vmcnt (never drains to 0 mid-loop).
// EPI: 2=f32(+bias+res), 3=relu->bf16, 4=f32(+bias), 5=QKV fused (q,k plain bf16; v transposed)
template<int EPI>
__global__ __launch_bounds__(256) void gemm_kernel(const ushort_t* __restrict__ A0,
                                                   const ushort_t* __restrict__ A1,
                                                   const ushort_t* __restrict__ A2,
                                                   const ushort_t* __restrict__ B0,
                                                   const ushort_t* __restrict__ B1,
                                                   const ushort_t* __restrict__ B2,
                                                   int nseg, int nbn,
                                                   const float* __restrict__ bias,
                                                   const float* __restrict__ bias2,
                                                   const float* __restrict__ bias3,
                                                   const float* __restrict__ res,
                                                   float* __restrict__ outF,
                                                   ushort_t* __restrict__ outB) {
    __shared__ ushort_t As[3][128 * 64];
    __shared__ ushort_t Bs[3][64 * 64];
    int tid = threadIdx.x;
    // XCD-chunked bijective swizzle (grid % 8 == 0)
    int g = blockIdx.x;
    int per = gridDim.x >> 3;
    int lin = (g & 7) * per + (g >> 3);
    int bm = lin / nbn, bn = lin % nbn;

    int lane = tid & 63;
    int wid = tid >> 6;
    int wm = wid >> 1, wn = wid & 1;       // wave owns 64x32 of the 128x64 tile
    int xr = (lane & 7) << 3;

    f32x4 acc[4][2];
#pragma unroll
    for (int i = 0; i < 4; i++)
#pragma unroll
        for (int j = 0; j < 2; j++) ZERO4(acc[i][j]);

    int nt = nseg * 8;

    // 6 gl16 per thread per tile: A 4 (128x64), B 2 (64x64)
#define STAGE(kt, buf)                                                                  \
    {                                                                                   \
        int seg_ = (kt) >> 3;                                                           \
        int k0_ = ((kt) & 7) * 64;                                                      \
        const ushort_t* Asg = seg_ == 0 ? A0 : (seg_ == 1 ? A1 : A2);                   \
        const ushort_t* Bsg = seg_ == 0 ? B0 : (seg_ == 1 ? B1 : B2);                   \
        _Pragma("unroll")                                                               \
        for (int it = 0; it < 4; it++) {                                                \
            int uu = tid + it * 256;                                                    \
            int row_ = uu >> 3;                                                         \
            int kb_ = (((uu & 7) ^ (row_ & 7)) << 3);                                   \
            gl16(Asg + (size_t)(bm * 128 + row_) * 512 + k0_ + kb_, &As[buf][uu * 8]);  \
        }                                                                               \
        _Pragma("unroll")                                                               \
        for (int it = 0; it < 2; it++) {                                                \
            int uu = tid + it * 256;                                                    \
            int row_ = uu >> 3;                                                         \
            int kb_ = (((uu & 7) ^ (row_ & 7)) << 3);                                   \
            gl16(Bsg + (size_t)(bn * 64 + row_) * 512 + k0_ + kb_, &Bs[buf][uu * 8]);   \
        }                                                                               \
    }

#define COMPUTE(bufc)                                                                        \
    {                                                                                        \
        _Pragma("unroll")                                                                    \
        for (int kc = 0; kc < 2; kc++) {                                                     \
            short8 a[4], b[2];                                                               \
            int koff = (kc * 32 + ((lane >> 4) << 3)) ^ xr;                                  \
            _Pragma("unroll")                                                                \
            for (int i = 0; i < 4; i++)                                                      \
                a[i] = *(const short8*)&As[bufc][(wm * 64 + i * 16 + (lane & 15)) * 64 + koff]; \
            _Pragma("unroll")                                                                \
            for (int j = 0; j < 2; j++)                                                      \
                b[j] = *(const short8*)&Bs[bufc][(wn * 32 + j * 16 + (lane & 15)) * 64 + koff]; \
            _Pragma("unroll")                                                                \
            for (int i = 0; i < 4; i++)                                                      \
                _Pragma("unroll")                                                            \
                for (int j = 0; j < 2; j++)                                                  \
                    acc[i][j] = __builtin_amdgcn_mfma_f32_16x16x32_bf16(a[i], b[j], acc[i][j], 0, 0, 0); \
        }                                                                                    \
    }

    STAGE(0, 0);
    if (nt > 1) STAGE(1, 1);
    asm volatile("s_waitcnt vmcnt(6)" ::: "memory");   // tile 0 landed (tile 1's 6 may remain)
    __syncthreads();

    int cur = 0;
    for (int t = 0; t < nt; t++) {
        if (t + 2 < nt) STAGE(t + 2, (cur + 2 >= 3 ? cur - 1 : cur + 2));   // (cur+2)%3
        COMPUTE(cur);
        if (t + 2 < nt) {
            asm volatile("s_waitcnt vmcnt(6)" ::: "memory");   // t+1 landed; t+2 in flight
        } else if (t + 1 < nt) {
            asm volatile("s_waitcnt vmcnt(0)" ::: "memory");
        }
        __syncthreads();
        cur = (cur == 2) ? 0 : cur + 1;
    }
#undef STAGE
#undef COMPUTE

#pragma unroll
    for (int i = 0; i < 4; i++) {
#pragma unroll
        for (int j = 0; j < 2; j++) {
            int r0 = bm * 128 + wm * 64 + i * 16 + ((lane >> 4) << 2);
            int col = bn * 64 + wn * 32 + j * 16 + (lane & 15);
            int seg = col >> 9;
            int ccol = col & 511;
            const float* bp = bias;
            if (EPI == 5) bp = (seg == 0) ? bias : (seg == 1 ? bias2 : bias3);
            float bc = bp[EPI == 5 ? ccol : col];
#pragma unroll
            for (int jj = 0; jj < 4; jj++) {
                float v = acc[i][j][jj] + bc;
                int row = r0 + jj;
                size_t idx = (size_t)row * 512 + col;
                if (EPI == 2) {
                    outF[idx] = v + res[idx];
                } else if (EPI == 3) {
                    outB[idx] = f2bf(fmaxf(v, 0.f));
                } else if (EPI == 4) {
                    outF[idx] = v;
                } else if (EPI == 5) {
                    if (seg < 2) {
                        outB[(size_t)seg * 4194304 + (size_t)row * 512 + ccol] = f2bf(v);
                    } else {
                        int bb2 = row >> 8, t2 = row & 255;
                        outB[(size_t)2 * 4194304 +
                             ((size_t)(bb2 * 8 + (ccol >> 6)) * 64 + (ccol & 63)) * 256 + t2] = f2bf(v);
                    }
                }
            }
        }
    }
}

// ---------------- fused attention: block = (64 q-rows, bh). QK^T -> softmax -> PV ----------------
__global__ __launch_bounds__(256) void attn_fused_kernel(const ushort_t* __restrict__ q,
                                                         const ushort_t* __restrict__ k,
                                                         const ushort_t* __restrict__ vt,
                                                         ushort_t* __restrict__ ao) {
    __shared__ ushort_t KVs[256 * 64];   // K tile, then reused for V^T (64 dk x 256 t)
    __shared__ ushort_t Ps[64 * 256];    // P (bf16), XOR-swizzled
    int tid = threadIdx.x;
    int lane = tid & 63;
    int wid = tid >> 6;
    int m0 = blockIdx.x * 64;
    int bh = blockIdx.y;
    int b = bh >> 3, h = bh & 7;
    int xr = (lane & 7) << 3;

    // stage K (256x64), source-preswizzled
#pragma unroll
    for (int it = 0; it < 8; it++) {
        int uu = tid + it * 256;
        int row = uu >> 3;
        int gx = ((uu & 7) ^ (row & 7)) << 3;
        gl16(k + (size_t)(b * T_ + row) * D_ + h * DK_ + gx, &KVs[uu * 8]);
    }
    // Q direct to regs (wave wid owns rows m0+wid*16 .. +15)
    short8 qa0, qa1;
    {
        int qrow = m0 + wid * 16 + (lane & 15);
        const ushort_t* qp = q + (size_t)(b * T_ + qrow) * D_ + h * DK_ + ((lane >> 4) << 3);
        qa0 = *(const short8*)(qp);
        qa1 = *(const short8*)(qp + 32);
    }
    f32x4 acc[16];
#pragma unroll
    for (int j = 0; j < 16; j++) ZERO4(acc[j]);
    asm volatile("s_waitcnt vmcnt(0)" ::: "memory");
    __syncthreads();

#pragma unroll
    for (int j = 0; j < 16; j++) {
        int krow = j * 16 + (lane & 15);
        short8 b0 = *(const short8*)&KVs[krow * 64 + ((((lane >> 4) << 3)) ^ xr)];
        short8 b1 = *(const short8*)&KVs[krow * 64 + ((32 + ((lane >> 4) << 3)) ^ xr)];
        acc[j] = __builtin_amdgcn_mfma_f32_16x16x32_bf16(qa0, b0, acc[j], 0, 0, 0);
        acc[j] = __builtin_amdgcn_mfma_f32_16x16x32_bf16(qa1, b1, acc[j], 0, 0, 0);
    }
    __syncthreads();   // all K reads done; KVs can be overwritten

    // stage V^T (64 dk x 256 t) into KVs while softmax runs
#pragma unroll
    for (int it = 0; it < 8; it++) {
        int uu = tid + it * 256;
        int row = uu >> 5;
        int gx = ((uu & 31) ^ (row & 7)) << 3;
        gl16(vt + ((size_t)bh * DK_ + row) * T_ + gx, &KVs[uu * 8]);
    }

    // softmax over 256 cols; lane group (lane>>4) holds rows +jj
    const float C = 0.125f * 1.44269504f;
#pragma unroll
    for (int jj = 0; jj < 4; jj++) {
        float mx = -1e30f;
#pragma unroll
        for (int j = 0; j < 16; j++) mx = fmaxf(mx, acc[j][jj]);
#pragma unroll
        for (int msk = 1; msk < 16; msk <<= 1) mx = fmaxf(mx, __shfl_xor(mx, msk));
        float sm = 0.f;
#pragma unroll
        for (int j = 0; j < 16; j++) {
            float e = __builtin_amdgcn_exp2f((acc[j][jj] - mx) * C);
            acc[j][jj] = e;
            sm += e;
        }
#pragma unroll
        for (int msk = 1; msk < 16; msk <<= 1) sm += __shfl_xor(sm, msk);
        float inv = 1.f / sm;
#pragma unroll
        for (int j = 0; j < 16; j++) acc[j][jj] *= inv;
    }
    // write P to LDS (swizzled)
#pragma unroll
    for (int j = 0; j < 16; j++) {
#pragma unroll
        for (int jj = 0; jj < 4; jj++) {
            int row = wid * 16 + ((lane >> 4) << 2) + jj;
            int col = j * 16 + (lane & 15);
            Ps[row * 256 + (col ^ ((row & 7) << 3))] = f2bf(acc[j][jj]);
        }
    }
    asm volatile("s_waitcnt vmcnt(0)" ::: "memory");
    __syncthreads();

    // PV: out 64x64; wave (wm,wn) does rows wm*32+i*16, cols wn*32+j*16
    int wm = wid >> 1, wn = wid & 1;
    f32x4 acc2[2][2];
#pragma unroll
    for (int i = 0; i < 2; i++)
#pragma unroll
        for (int j = 0; j < 2; j++) ZERO4(acc2[i][j]);
#pragma unroll
    for (int kc = 0; kc < 8; kc++) {
        int off = (kc * 32 + ((lane >> 4) << 3)) ^ xr;
        short8 a0 = *(const short8*)&Ps[(wm * 32 + (lane & 15)) * 256 + off];
        short8 a1 = *(const short8*)&Ps[(wm * 32 + 16 + (lane & 15)) * 256 + off];
        short8 b0 = *(const short8*)&KVs[(wn * 32 + (lane & 15)) * 256 + off];
        short8 b1 = *(const short8*)&KVs[(wn * 32 + 16 + (lane & 15)) * 256 + off];
        acc2[0][0] = __builtin_amdgcn_mfma_f32_16x16x32_bf16(a0, b0, acc2[0][0], 0, 0, 0);
        acc2[0][1] = __builtin_amdgcn_mfma_f32_16x16x32_bf16(a0, b1, acc2[0][1], 0, 0, 0);
        acc2[1][0] = __builtin_amdgcn_mfma_f32_16x16x32_bf16(a1, b0, acc2[1][0], 0, 0, 0);
        acc2[1][1] = __builtin_amdgcn_mfma_f32_16x16x32_bf16(a1, b1, acc2[1][1], 0, 0, 0);
    }
#pragma unroll
    for (int i = 0; i < 2; i++)
#pragma unroll
        for (int j = 0; j < 2; j++)
#pragma unroll
            for (int jj = 0; jj < 4; jj++)
                ao[(size_t)(b * T_ + m0 + wm * 32 + i * 16 + ((lane >> 4) << 2) + jj) * D_ +
                   h * DK_ + wn * 32 + j * 16 + (lane & 15)] = f2bf(acc2[i][j][jj]);
}

// ---------------- PVAM scores: s[b,m,t] = Sum_c w1[c] - 2*Sum_c w1[c]/(exp2(K*(wf+wp))+1) ----------------
// grid (8 ttiles, 32 b, 5 mgroups), 256 threads. 32 tokens/block, 8 threads/token, 64 ch/thread.
__global__ __launch_bounds__(256) void scores_kernel(const float* __restrict__ wf,
                                                     const int* __restrict__ gpos,
                                                     const float* __restrict__ emb,
                                                     const float* __restrict__ w1,
                                                     float* __restrict__ scores) {
    __shared__ float wpL[5][512];   // K2 * wp
    __shared__ float w1m2[512];     // -2 * w1
    const float K2 = 2.885390082f;  // 2*log2(e)
    int tid = threadIdx.x;
    int b = blockIdx.y;
    int mg = blockIdx.z * 5;
    int t = blockIdx.x * 32 + (tid >> 3);
    int cg = tid & 7;
    for (int idx = tid; idx < 5 * 128; idx += 256) {
        int m = idx >> 7, w4 = idx & 127;
        float4 v = *(const float4*)(emb + (size_t)gpos[mg + m] * D_ + (w4 << 2));
        v.x *= K2; v.y *= K2; v.z *= K2; v.w *= K2;
        *(float4*)&wpL[m][w4 << 2] = v;
    }
    if (tid < 128) {
        float4 v = *(const float4*)(w1 + (tid << 2));
        v.x *= -2.f; v.y *= -2.f; v.z *= -2.f; v.w *= -2.f;
        *(float4*)&w1m2[tid << 2] = v;
    }
    // thread's channels: c = cg*4 + j*32 + i  (j=0..15, i=0..3)
    float4 wfs[16];
    float W1S = 0.f;
    const float* wfr = wf + (size_t)(b * T_ + t) * D_ + (cg << 2);
#pragma unroll
    for (int j = 0; j < 16; j++) {
        float4 v = *(const float4*)(wfr + (j << 5));
        wfs[j].x = v.x * K2; wfs[j].y = v.y * K2; wfs[j].z = v.z * K2; wfs[j].w = v.w * K2;
        float4 wv = *(const float4*)(w1 + (cg << 2) + (j << 5));
        W1S += wv.x + wv.y + wv.z + wv.w;
    }
    __syncthreads();
    float s[5] = {W1S, W1S, W1S, W1S, W1S};
#pragma unroll
    for (int j = 0; j < 16; j++) {
        float4 w14 = *(const float4*)&w1m2[(cg << 2) + (j << 5)];
#pragma unroll
        for (int m = 0; m < 5; m++) {
            float4 wp4 = *(const float4*)&wpL[m][(cg << 2) + (j << 5)];
            s[m] += w14.x * __builtin_amdgcn_rcpf(__builtin_amdgcn_exp2f(wfs[j].x + wp4.x) + 1.f);
            s[m] += w14.y * __builtin_amdgcn_rcpf(__builtin_amdgcn_exp2f(wfs[j].y + wp4.y) + 1.f);
            s[m] += w14.z * __builtin_amdgcn_rcpf(__builtin_amdgcn_exp2f(wfs[j].z + wp4.z) + 1.f);
            s[m] += w14.w * __builtin_amdgcn_rcpf(__builtin_amdgcn_exp2f(wfs[j].w + wp4.w) + 1.f);
        }
    }
#pragma unroll
    for (int m = 0; m < 5; m++) {
        s[m] += __shfl_xor(s[m], 1);
        s[m] += __shfl_xor(s[m], 2);
        s[m] += __shfl_xor(s[m], 4);
    }
    if (cg == 0) {
#pragma unroll
        for (int m = 0; m < 5; m++)
            scores[((size_t)b * ML_ + mg + m) * T_ + t] = s[m];
    }
}

// softmax over t, in place: 800 rows of 256. grid 200 x 256 threads (wave per row).
__global__ __launch_bounds__(256) void softmax_kernel(float* __restrict__ sc) {
    int wid = threadIdx.x >> 6, lane = threadIdx.x & 63;
    size_t row = (size_t)blockIdx.x * 4 + wid;
    float4* p = (float4*)(sc + row * T_);
    float4 v = p[lane];
    float mx = fmaxf(fmaxf(v.x, v.y), fmaxf(v.z, v.w));
    for (int o = 32; o; o >>= 1) mx = fmaxf(mx, __shfl_xor(mx, o));
    float4 e;
    e.x = __expf(v.x - mx); e.y = __expf(v.y - mx);
    e.z = __expf(v.z - mx); e.w = __expf(v.w - mx);
    float sm = e.x + e.y + e.z + e.w;
    for (int o = 32; o; o >>= 1) sm += __shfl_xor(sm, o);
    float inv = 1.f / sm;
    e.x *= inv; e.y *= inv; e.z *= inv; e.w *= inv;
    p[lane] = e;
}

// weighted sum: out[b,m,c] = sum_t attn[b,m,t]*wf[b,t,c]. grid (5 mgroups, 32 b).
__global__ __launch_bounds__(256) void wsum_kernel(const float* __restrict__ attn,
                                                   const float* __restrict__ wf,
                                                   float* __restrict__ out) {
    __shared__ float at[T_][8];
    int tid = threadIdx.x;
    int b = blockIdx.y, m0 = blockIdx.x * 5;
#pragma unroll
    for (int q = 0; q < 5; q++) {
        float a = attn[((size_t)b * ML_ + m0 + q) * T_ + tid];
        at[tid][q] = a;
    }
    __syncthreads();
    int c0 = tid << 1;
    const float* wfb = wf + (size_t)b * T_ * D_ + c0;
    float acc[5][2] = {};
    for (int t = 0; t < T_; t++) {
        float2 v = *(const float2*)(wfb + (size_t)t * D_);
        float4 a4 = *(const float4*)&at[t][0];
        float a5 = at[t][4];
        acc[0][0] += a4.x * v.x; acc[0][1] += a4.x * v.y;
        acc[1][0] += a4.y * v.x; acc[1][1] += a4.y * v.y;
        acc[2][0] += a4.z * v.x; acc[2][1] += a4.z * v.y;
        acc[3][0] += a4.w * v.x; acc[3][1] += a4.w * v.y;
        acc[4][0] += a5 * v.x;   acc[4][1] += a5 * v.y;
    }
#pragma unroll
    for (int q = 0; q < 5; q++) {
        float2 o;
        o.x = acc[q][0]; o.y = acc[q][1];
        *(float2*)(out + ((size_t)b * ML_ + m0 + q) * D_ + c0) = o;
    }
}

extern "C" void kernel_launch(void* const* d_in, const int* in_sizes, int n_in,
                              void* d_out, int out_size, void* d_ws, size_t ws_size,
                              hipStream_t stream) {
    (void)in_sizes; (void)n_in; (void)out_size; (void)ws_size;
    const float* x        = (const float*)d_in[0];
    const int*   epos     = (const int*)d_in[1];
    const int*   gpos     = (const int*)d_in[2];
    const float* pos_tab  = (const float*)d_in[3];
    const float* ln1_s    = (const float*)d_in[4];
    const float* ln1_b    = (const float*)d_in[5];
    const float* Wq       = (const float*)d_in[6];
    const float* bq       = (const float*)d_in[7];
    const float* Wk       = (const float*)d_in[8];
    const float* bk       = (const float*)d_in[9];
    const float* Wv       = (const float*)d_in[10];
    const float* bv       = (const float*)d_in[11];
    const float* Wo       = (const float*)d_in[12];
    const float* bo       = (const float*)d_in[13];
    const float* ln2_s    = (const float*)d_in[14];
    const float* ln2_b    = (const float*)d_in[15];
    const float* W1       = (const float*)d_in[16];
    const float* b1       = (const float*)d_in[17];
    const float* W2       = (const float*)d_in[18];
    const float* b2       = (const float*)d_in[19];
    const float* lnf_s    = (const float*)d_in[20];
    const float* lnf_b    = (const float*)d_in[21];
    const float* fc0_w    = (const float*)d_in[22];
    const float* fc0_b    = (const float*)d_in[23];
    const float* emb      = (const float*)d_in[24];
    const float* fc1_w    = (const float*)d_in[25];

    char* ws = (char*)d_ws;
    float*    enc = (float*)(ws);                       // 16.78 MB
    ushort_t* hi  = (ushort_t*)(ws + 16777216);         // 8.39 MB
    ushort_t* qb  = (ushort_t*)(ws + 25165824);         // 8.39 MB (qkv base; kb/vt follow)
    ushort_t* kb  = (ushort_t*)(ws + 33554432);         // 8.39 MB (lo/scb overlay later)
    ushort_t* lo  = (ushort_t*)(ws + 33554432);
    float*    scb = (float*)(ws + 33554432);            // scores 800KB (after fc0, kb/lo dead)
    ushort_t* vt  = (ushort_t*)(ws + 41943040);         // 8.39 MB (h1 overlays later)
    ushort_t* h1  = (ushort_t*)(ws + 41943040);
    ushort_t* ao  = (ushort_t*)(ws + 50331648);         // 8.39 MB
    float*    wf  = (float*)(ws + 58720256);            // 16.78 MB
    ushort_t* wt  = (ushort_t*)(ws + 75497472);         // 7.34 MB (14 slices of 512KB)
    const size_t WSL = (size_t)D_ * D_;

    convert_w_kernel<<<13 * 64, 256, 0, stream>>>(Wq, Wk, Wv, Wo, W1, W2, fc0_w, wt);
    prep_kernel<<<dim3(4, 8, 32), 256, 0, stream>>>(x, epos, pos_tab, enc);

    for (int l = 0; l < 2; l++) {
        size_t o1 = (size_t)l * D_;
        const ushort_t* WqkvT = wt + (l * 6 + 0) * WSL;   // [1536][512] concat
        const ushort_t* WoT = wt + (l * 6 + 3) * WSL;
        const ushort_t* W1T = wt + (l * 6 + 4) * WSL;
        const ushort_t* W2T = wt + (l * 6 + 5) * WSL;

        ln_kernel<false><<<2048, 256, 0, stream>>>(enc, ln1_s + o1, ln1_b + o1, hi, nullptr);
        gemm_kernel<5><<<1536, 256, 0, stream>>>(hi, nullptr, nullptr, WqkvT, nullptr, nullptr,
                                                 1, 24, bq + o1, bk + o1, bv + o1, nullptr, nullptr, qb);
        attn_fused_kernel<<<dim3(4, 256), 256, 0, stream>>>(qb, kb, vt, ao);
        gemm_kernel<2><<<512, 256, 0, stream>>>(ao, nullptr, nullptr, WoT, nullptr, nullptr,
                                                1, 8, bo + o1, nullptr, nullptr, enc, enc, nullptr);
        ln_kernel<false><<<2048, 256, 0, stream>>>(enc, ln2_s + o1, ln2_b + o1, hi, nullptr);
        gemm_kernel<3><<<512, 256, 0, stream>>>(hi, nullptr, nullptr, W1T, nullptr, nullptr,
                                                1, 8, b1 + o1, nullptr, nullptr, nullptr, nullptr, h1);
        gemm_kernel<2><<<512, 256, 0, stream>>>(h1, nullptr, nullptr, W2T, nullptr, nullptr,
                                                1, 8, b2 + o1, nullptr, nullptr, enc, enc, nullptr);
    }

    ln_kernel<true><<<2048, 256, 0, stream>>>(enc, lnf_s, lnf_b, hi, lo);
    // fc0 split-bf16: Ah*Wh + Al*Wh + Ah*Wl
    gemm_kernel<4><<<512, 256, 0, stream>>>(hi, lo, hi, wt + 12 * WSL, wt + 12 * WSL, wt + 13 * WSL,
                                            3, 8, fc0_b, nullptr, nullptr, nullptr, wf, nullptr);
    scores_kernel<<<dim3(8, 32, 5), 256, 0, stream>>>(wf, gpos, emb, fc1_w, scb);
    softmax_kernel<<<200, 256, 0, stream>>>(scb);
    wsum_kernel<<<dim3(5, 32), 256, 0, stream>>>(scb, wf, (float*)d_out);
}

// Round 8
// 294.568 us; speedup vs baseline: 5.3038x; 1.0043x over previous
//
#include <hip/hip_runtime.h>
#include <math.h>

#define B_ 32
#define D_ 512
#define T_ 256
#define NH_ 8
#define DK_ 64
#define ML_ 25

typedef unsigned short ushort_t;
using short8 = __attribute__((ext_vector_type(8))) short;
using f32x4  = __attribute__((ext_vector_type(4))) float;

__device__ __forceinline__ ushort_t f2bf(float f) {
    unsigned u = __float_as_uint(f);
    unsigned r = (u + 0x7fffu + ((u >> 16) & 1u)) >> 16;
    return (ushort_t)r;
}
__device__ __forceinline__ float bf2f(ushort_t h) {
    return __uint_as_float(((unsigned)h) << 16);
}
__device__ __forceinline__ void gl16(const void* g, void* l) {
    __builtin_amdgcn_global_load_lds((const __attribute__((address_space(1))) void*)g,
                                     (__attribute__((address_space(3))) void*)l, 16, 0, 0);
}
#define ZERO4(v) { (v)[0]=0.f; (v)[1]=0.f; (v)[2]=0.f; (v)[3]=0.f; }

// ---------------- prep: enc[b,t,c] = x[b,c,t]*sqrt(512) + pos[epos[t],c]  (LDS transpose) ----------------
__global__ __launch_bounds__(256) void prep_kernel(const float* __restrict__ x,
                                                   const int* __restrict__ epos,
                                                   const float* __restrict__ pos,
                                                   float* __restrict__ enc) {
    __shared__ float ld[64][65];
    int tt = blockIdx.x, ct = blockIdx.y, b = blockIdx.z;
    int t0 = tt * 64, c0 = ct * 64;
    int tid = threadIdx.x;
    int r = tid >> 4, c4 = (tid & 15) << 2;
#pragma unroll
    for (int p = 0; p < 4; p++) {
        int row = p * 16 + r;  // channel within tile
        float4 v = *(const float4*)(x + ((size_t)(b * D_ + c0 + row) * T_ + t0) + c4);
        ld[row][c4 + 0] = v.x; ld[row][c4 + 1] = v.y; ld[row][c4 + 2] = v.z; ld[row][c4 + 3] = v.w;
    }
    __syncthreads();
#pragma unroll
    for (int p = 0; p < 4; p++) {
        int tr = p * 16 + r;   // token within tile
        int ep = epos[t0 + tr];
        float4 pv = *(const float4*)(pos + (size_t)ep * D_ + c0 + c4);
        float4 o;
        o.x = ld[c4 + 0][tr] * 22.627417f + pv.x;
        o.y = ld[c4 + 1][tr] * 22.627417f + pv.y;
        o.z = ld[c4 + 2][tr] * 22.627417f + pv.z;
        o.w = ld[c4 + 3][tr] * 22.627417f + pv.w;
        *(float4*)(enc + (size_t)(b * T_ + t0 + tr) * D_ + c0 + c4) = o;
    }
}

// ---------------- weight convert: WT[n][k] = bf16(W[k][n]); fc0 also lo ----------------
__global__ __launch_bounds__(256) void convert_w_kernel(const float* __restrict__ Wq,
                                                        const float* __restrict__ Wk,
                                                        const float* __restrict__ Wv,
                                                        const float* __restrict__ Wo,
                                                        const float* __restrict__ W1,
                                                        const float* __restrict__ W2,
                                                        const float* __restrict__ fc0,
                                                        ushort_t* __restrict__ wt) {
    __shared__ float ld[64][65];
    int m = blockIdx.x >> 6;
    int tile = blockIdx.x & 63;
    int tn = tile >> 3, tk = tile & 7;
    int n0 = tn * 64, k0 = tk * 64;
    const float* src;
    if (m < 12) {
        int l = m / 6, w = m % 6;
        const float* bases[6] = {Wq, Wk, Wv, Wo, W1, W2};
        src = bases[w] + (size_t)l * D_ * D_;
    } else {
        src = fc0;
    }
    int tid = threadIdx.x;
    int r = tid >> 4, c4 = (tid & 15) << 2;
#pragma unroll
    for (int p = 0; p < 4; p++) {
        int row = p * 16 + r;  // k index
        float4 v = *(const float4*)(src + (size_t)(k0 + row) * D_ + n0 + c4);
        ld[row][c4 + 0] = v.x; ld[row][c4 + 1] = v.y; ld[row][c4 + 2] = v.z; ld[row][c4 + 3] = v.w;
    }
    __syncthreads();
    ushort_t* dsth = wt + (size_t)m * D_ * D_;
    ushort_t* dstl = wt + (size_t)13 * D_ * D_;
#pragma unroll
    for (int p = 0; p < 4; p++) {
        int n = p * 16 + r;
        int kc = c4;
        ushort_t h[4], lo[4];
#pragma unroll
        for (int i = 0; i < 4; i++) {
            float f = ld[kc + i][n];
            h[i] = f2bf(f);
            lo[i] = f2bf(f - bf2f(h[i]));
        }
        *(ushort4*)(dsth + (size_t)(n0 + n) * D_ + k0 + kc) = make_ushort4(h[0], h[1], h[2], h[3]);
        if (m == 12)
            *(ushort4*)(dstl + (size_t)(n0 + n) * D_ + k0 + kc) = make_ushort4(lo[0], lo[1], lo[2], lo[3]);
    }
}

// ---------------- LayerNorm -> bf16 hi (+lo) ----------------
template<bool LO>
__global__ __launch_bounds__(256) void ln_kernel(const float* __restrict__ x,
                                                 const float* __restrict__ s,
                                                 const float* __restrict__ b,
                                                 ushort_t* __restrict__ yh,
                                                 ushort_t* __restrict__ yl) {
    int wid = threadIdx.x >> 6, lane = threadIdx.x & 63;
    size_t row = (size_t)blockIdx.x * 4 + wid;
    const float4* xr = (const float4*)(x + row * D_);
    float4 v0 = xr[lane * 2], v1 = xr[lane * 2 + 1];
    float sum = v0.x + v0.y + v0.z + v0.w + v1.x + v1.y + v1.z + v1.w;
    for (int o = 32; o; o >>= 1) sum += __shfl_xor(sum, o);
    float mean = sum * (1.f / 512.f);
    float d[8] = {v0.x - mean, v0.y - mean, v0.z - mean, v0.w - mean,
                  v1.x - mean, v1.y - mean, v1.z - mean, v1.w - mean};
    float vs = 0.f;
#pragma unroll
    for (int i = 0; i < 8; i++) vs += d[i] * d[i];
    for (int o = 32; o; o >>= 1) vs += __shfl_xor(vs, o);
    float rs = 1.f / sqrtf(vs * (1.f / 512.f) + 1e-5f);
    const float4* s4 = (const float4*)s;
    const float4* b4 = (const float4*)b;
    float4 sa = s4[lane * 2], sb = s4[lane * 2 + 1];
    float4 ba = b4[lane * 2], bb = b4[lane * 2 + 1];
    float o8[8];
    o8[0] = d[0] * rs * sa.x + ba.x; o8[1] = d[1] * rs * sa.y + ba.y;
    o8[2] = d[2] * rs * sa.z + ba.z; o8[3] = d[3] * rs * sa.w + ba.w;
    o8[4] = d[4] * rs * sb.x + bb.x; o8[5] = d[5] * rs * sb.y + bb.y;
    o8[6] = d[6] * rs * sb.z + bb.z; o8[7] = d[7] * rs * sb.w + bb.w;
    ushort_t h[8];
#pragma unroll
    for (int i = 0; i < 8; i++) h[i] = f2bf(o8[i]);
    uint4 u;
    u.x = (unsigned)h[0] | ((unsigned)h[1] << 16);
    u.y = (unsigned)h[2] | ((unsigned)h[3] << 16);
    u.z = (unsigned)h[4] | ((unsigned)h[5] << 16);
    u.w = (unsigned)h[6] | ((unsigned)h[7] << 16);
    *(uint4*)(yh + row * D_ + lane * 8) = u;
    if (LO) {
        ushort_t l8[8];
#pragma unroll
        for (int i = 0; i < 8; i++) l8[i] = f2bf(o8[i] - bf2f(h[i]));
        uint4 ul;
        ul.x = (unsigned)l8[0] | ((unsigned)l8[1] << 16);
        ul.y = (unsigned)l8[2] | ((unsigned)l8[3] << 16);
        ul.z = (unsigned)l8[4] | ((unsigned)l8[5] << 16);
        ul.w = (unsigned)l8[6] | ((unsigned)l8[7] << 16);
        *(uint4*)(yl + row * D_ + lane * 8) = ul;
    }
}

// ---------------- MFMA GEMM: C[8192,N] = sum_seg A_seg[8192,512] * WT_seg[N,512]^T ----------------
// Tile 128x64, 3-deep LDS pipeline, counted vmcnt + RAW s_barrier (no compiler vmcnt(0) drain).
// Safety: every wave waits vmcnt<=6 (its tile-t+1 loads landed) BEFORE the barrier; ds_read data
// is consumed into regs by MFMAs before the barrier; no ds_writes in this kernel.
// EPI: 2=f32(+bias+res), 3=relu->bf16, 4=f32(+bias), 5=QKV fused (q,k plain bf16; v transposed)
template<int EPI>
__global__ __launch_bounds__(256) void gemm_kernel(const ushort_t* __restrict__ A0,
                                                   const ushort_t* __restrict__ A1,
                                                   const ushort_t* __restrict__ A2,
                                                   const ushort_t* __restrict__ B0,
                                                   const ushort_t* __restrict__ B1,
                                                   const ushort_t* __restrict__ B2,
                                                   int nseg, int nbn,
                                                   const float* __restrict__ bias,
                                                   const float* __restrict__ bias2,
                                                   const float* __restrict__ bias3,
                                                   const float* __restrict__ res,
                                                   float* __restrict__ outF,
                                                   ushort_t* __restrict__ outB) {
    __shared__ ushort_t As[3][128 * 64];
    __shared__ ushort_t Bs[3][64 * 64];
    int tid = threadIdx.x;
    // XCD-chunked bijective swizzle (grid % 8 == 0)
    int g = blockIdx.x;
    int per = gridDim.x >> 3;
    int lin = (g & 7) * per + (g >> 3);
    int bm = lin / nbn, bn = lin % nbn;

    int lane = tid & 63;
    int wid = tid >> 6;
    int wm = wid >> 1, wn = wid & 1;       // wave owns 64x32 of the 128x64 tile
    int xr = (lane & 7) << 3;

    f32x4 acc[4][2];
#pragma unroll
    for (int i = 0; i < 4; i++)
#pragma unroll
        for (int j = 0; j < 2; j++) ZERO4(acc[i][j]);

    int nt = nseg * 8;

    // 6 gl16 per thread per tile: A 4 (128x64), B 2 (64x64)
#define STAGE(kt, buf)                                                                  \
    {                                                                                   \
        int seg_ = (kt) >> 3;                                                           \
        int k0_ = ((kt) & 7) * 64;                                                      \
        const ushort_t* Asg = seg_ == 0 ? A0 : (seg_ == 1 ? A1 : A2);                   \
        const ushort_t* Bsg = seg_ == 0 ? B0 : (seg_ == 1 ? B1 : B2);                   \
        _Pragma("unroll")                                                               \
        for (int it = 0; it < 4; it++) {                                                \
            int uu = tid + it * 256;                                                    \
            int row_ = uu >> 3;                                                         \
            int kb_ = (((uu & 7) ^ (row_ & 7)) << 3);                                   \
            gl16(Asg + (size_t)(bm * 128 + row_) * 512 + k0_ + kb_, &As[buf][uu * 8]);  \
        }                                                                               \
        _Pragma("unroll")                                                               \
        for (int it = 0; it < 2; it++) {                                                \
            int uu = tid + it * 256;                                                    \
            int row_ = uu >> 3;                                                         \
            int kb_ = (((uu & 7) ^ (row_ & 7)) << 3);                                   \
            gl16(Bsg + (size_t)(bn * 64 + row_) * 512 + k0_ + kb_, &Bs[buf][uu * 8]);   \
        }                                                                               \
    }

#define COMPUTE(bufc)                                                                        \
    {                                                                                        \
        _Pragma("unroll")                                                                    \
        for (int kc = 0; kc < 2; kc++) {                                                     \
            short8 a[4], b[2];                                                               \
            int koff = (kc * 32 + ((lane >> 4) << 3)) ^ xr;                                  \
            _Pragma("unroll")                                                                \
            for (int i = 0; i < 4; i++)                                                      \
                a[i] = *(const short8*)&As[bufc][(wm * 64 + i * 16 + (lane & 15)) * 64 + koff]; \
            _Pragma("unroll")                                                                \
            for (int j = 0; j < 2; j++)                                                      \
                b[j] = *(const short8*)&Bs[bufc][(wn * 32 + j * 16 + (lane & 15)) * 64 + koff]; \
            _Pragma("unroll")                                                                \
            for (int i = 0; i < 4; i++)                                                      \
                _Pragma("unroll")                                                            \
                for (int j = 0; j < 2; j++)                                                  \
                    acc[i][j] = __builtin_amdgcn_mfma_f32_16x16x32_bf16(a[i], b[j], acc[i][j], 0, 0, 0); \
        }                                                                                    \
    }

    STAGE(0, 0);
    if (nt > 1) STAGE(1, 1);
    asm volatile("s_waitcnt vmcnt(6)" ::: "memory");   // tile 0 landed (tile 1's 6 may remain)
    __builtin_amdgcn_s_barrier();

    int cur = 0;
    for (int t = 0; t < nt; t++) {
        if (t + 2 < nt) STAGE(t + 2, (cur + 2 >= 3 ? cur - 1 : cur + 2));   // (cur+2)%3
        COMPUTE(cur);
        if (t + 2 < nt) {
            asm volatile("s_waitcnt vmcnt(6)" ::: "memory");   // t+1 landed; t+2 in flight
        } else if (t + 1 < nt) {
            asm volatile("s_waitcnt vmcnt(0)" ::: "memory");
        }
        __builtin_amdgcn_s_barrier();
        cur = (cur == 2) ? 0 : cur + 1;
    }
#undef STAGE
#undef COMPUTE

#pragma unroll
    for (int i = 0; i < 4; i++) {
#pragma unroll
        for (int j = 0; j < 2; j++) {
            int r0 = bm * 128 + wm * 64 + i * 16 + ((lane >> 4) << 2);
            int col = bn * 64 + wn * 32 + j * 16 + (lane & 15);
            int seg = col >> 9;
            int ccol = col & 511;
            const float* bp = bias;
            if (EPI == 5) bp = (seg == 0) ? bias : (seg == 1 ? bias2 : bias3);
            float bc = bp[EPI == 5 ? ccol : col];
#pragma unroll
            for (int jj = 0; jj < 4; jj++) {
                float v = acc[i][j][jj] + bc;
                int row = r0 + jj;
                size_t idx = (size_t)row * 512 + col;
                if (EPI == 2) {
                    outF[idx] = v + res[idx];
                } else if (EPI == 3) {
                    outB[idx] = f2bf(fmaxf(v, 0.f));
                } else if (EPI == 4) {
                    outF[idx] = v;
                } else if (EPI == 5) {
                    if (seg < 2) {
                        outB[(size_t)seg * 4194304 + (size_t)row * 512 + ccol] = f2bf(v);
                    } else {
                        int bb2 = row >> 8, t2 = row & 255;
                        outB[(size_t)2 * 4194304 +
                             ((size_t)(bb2 * 8 + (ccol >> 6)) * 64 + (ccol & 63)) * 256 + t2] = f2bf(v);
                    }
                }
            }
        }
    }
}

// ---------------- fused attention: block = (64 q-rows, bh). QK^T -> softmax -> PV ----------------
__global__ __launch_bounds__(256) void attn_fused_kernel(const ushort_t* __restrict__ q,
                                                         const ushort_t* __restrict__ k,
                                                         const ushort_t* __restrict__ vt,
                                                         ushort_t* __restrict__ ao) {
    __shared__ ushort_t KVs[256 * 64];   // K tile, then reused for V^T (64 dk x 256 t)
    __shared__ ushort_t Ps[64 * 256];    // P (bf16), XOR-swizzled
    int tid = threadIdx.x;
    int lane = tid & 63;
    int wid = tid >> 6;
    int m0 = blockIdx.x * 64;
    int bh = blockIdx.y;
    int b = bh >> 3, h = bh & 7;
    int xr = (lane & 7) << 3;

    // stage K (256x64), source-preswizzled
#pragma unroll
    for (int it = 0; it < 8; it++) {
        int uu = tid + it * 256;
        int row = uu >> 3;
        int gx = ((uu & 7) ^ (row & 7)) << 3;
        gl16(k + (size_t)(b * T_ + row) * D_ + h * DK_ + gx, &KVs[uu * 8]);
    }
    // Q direct to regs (wave wid owns rows m0+wid*16 .. +15)
    short8 qa0, qa1;
    {
        int qrow = m0 + wid * 16 + (lane & 15);
        const ushort_t* qp = q + (size_t)(b * T_ + qrow) * D_ + h * DK_ + ((lane >> 4) << 3);
        qa0 = *(const short8*)(qp);
        qa1 = *(const short8*)(qp + 32);
    }
    f32x4 acc[16];
#pragma unroll
    for (int j = 0; j < 16; j++) ZERO4(acc[j]);
    asm volatile("s_waitcnt vmcnt(0)" ::: "memory");
    __syncthreads();

#pragma unroll
    for (int j = 0; j < 16; j++) {
        int krow = j * 16 + (lane & 15);
        short8 b0 = *(const short8*)&KVs[krow * 64 + ((((lane >> 4) << 3)) ^ xr)];
        short8 b1 = *(const short8*)&KVs[krow * 64 + ((32 + ((lane >> 4) << 3)) ^ xr)];
        acc[j] = __builtin_amdgcn_mfma_f32_16x16x32_bf16(qa0, b0, acc[j], 0, 0, 0);
        acc[j] = __builtin_amdgcn_mfma_f32_16x16x32_bf16(qa1, b1, acc[j], 0, 0, 0);
    }
    __syncthreads();   // all K reads done; KVs can be overwritten

    // stage V^T (64 dk x 256 t) into KVs while softmax runs
#pragma unroll
    for (int it = 0; it < 8; it++) {
        int uu = tid + it * 256;
        int row = uu >> 5;
        int gx = ((uu & 31) ^ (row & 7)) << 3;
        gl16(vt + ((size_t)bh * DK_ + row) * T_ + gx, &KVs[uu * 8]);
    }

    // softmax over 256 cols; lane group (lane>>4) holds rows +jj
    const float C = 0.125f * 1.44269504f;
#pragma unroll
    for (int jj = 0; jj < 4; jj++) {
        float mx = -1e30f;
#pragma unroll
        for (int j = 0; j < 16; j++) mx = fmaxf(mx, acc[j][jj]);
#pragma unroll
        for (int msk = 1; msk < 16; msk <<= 1) mx = fmaxf(mx, __shfl_xor(mx, msk));
        float sm = 0.f;
#pragma unroll
        for (int j = 0; j < 16; j++) {
            float e = __builtin_amdgcn_exp2f((acc[j][jj] - mx) * C);
            acc[j][jj] = e;
            sm += e;
        }
#pragma unroll
        for (int msk = 1; msk < 16; msk <<= 1) sm += __shfl_xor(sm, msk);
        float inv = 1.f / sm;
#pragma unroll
        for (int j = 0; j < 16; j++) acc[j][jj] *= inv;
    }
    // write P to LDS (swizzled)
#pragma unroll
    for (int j = 0; j < 16; j++) {
#pragma unroll
        for (int jj = 0; jj < 4; jj++) {
            int row = wid * 16 + ((lane >> 4) << 2) + jj;
            int col = j * 16 + (lane & 15);
            Ps[row * 256 + (col ^ ((row & 7) << 3))] = f2bf(acc[j][jj]);
        }
    }
    asm volatile("s_waitcnt vmcnt(0)" ::: "memory");
    __syncthreads();

    // PV: out 64x64; wave (wm,wn) does rows wm*32+i*16, cols wn*32+j*16
    int wm = wid >> 1, wn = wid & 1;
    f32x4 acc2[2][2];
#pragma unroll
    for (int i = 0; i < 2; i++)
#pragma unroll
        for (int j = 0; j < 2; j++) ZERO4(acc2[i][j]);
#pragma unroll
    for (int kc = 0; kc < 8; kc++) {
        int off = (kc * 32 + ((lane >> 4) << 3)) ^ xr;
        short8 a0 = *(const short8*)&Ps[(wm * 32 + (lane & 15)) * 256 + off];
        short8 a1 = *(const short8*)&Ps[(wm * 32 + 16 + (lane & 15)) * 256 + off];
        short8 b0 = *(const short8*)&KVs[(wn * 32 + (lane & 15)) * 256 + off];
        short8 b1 = *(const short8*)&KVs[(wn * 32 + 16 + (lane & 15)) * 256 + off];
        acc2[0][0] = __builtin_amdgcn_mfma_f32_16x16x32_bf16(a0, b0, acc2[0][0], 0, 0, 0);
        acc2[0][1] = __builtin_amdgcn_mfma_f32_16x16x32_bf16(a0, b1, acc2[0][1], 0, 0, 0);
        acc2[1][0] = __builtin_amdgcn_mfma_f32_16x16x32_bf16(a1, b0, acc2[1][0], 0, 0, 0);
        acc2[1][1] = __builtin_amdgcn_mfma_f32_16x16x32_bf16(a1, b1, acc2[1][1], 0, 0, 0);
    }
#pragma unroll
    for (int i = 0; i < 2; i++)
#pragma unroll
        for (int j = 0; j < 2; j++)
#pragma unroll
            for (int jj = 0; jj < 4; jj++)
                ao[(size_t)(b * T_ + m0 + wm * 32 + i * 16 + ((lane >> 4) << 2) + jj) * D_ +
                   h * DK_ + wn * 32 + j * 16 + (lane & 15)] = f2bf(acc2[i][j][jj]);
}

// ---------------- PVAM scores: s[b,m,t] = Sum_c w1[c] - 2*Sum_c w1[c]/(exp2(K*(wf+wp))+1) ----------------
// grid (8 ttiles, 32 b, 5 mgroups), 256 threads. 32 tokens/block, 8 threads/token, 64 ch/thread.
__global__ __launch_bounds__(256) void scores_kernel(const float* __restrict__ wf,
                                                     const int* __restrict__ gpos,
                                                     const float* __restrict__ emb,
                                                     const float* __restrict__ w1,
                                                     float* __restrict__ scores) {
    __shared__ float wpL[5][512];   // K2 * wp
    __shared__ float w1m2[512];     // -2 * w1
    const float K2 = 2.885390082f;  // 2*log2(e)
    int tid = threadIdx.x;
    int b = blockIdx.y;
    int mg = blockIdx.z * 5;
    int t = blockIdx.x * 32 + (tid >> 3);
    int cg = tid & 7;
    for (int idx = tid; idx < 5 * 128; idx += 256) {
        int m = idx >> 7, w4 = idx & 127;
        float4 v = *(const float4*)(emb + (size_t)gpos[mg + m] * D_ + (w4 << 2));
        v.x *= K2; v.y *= K2; v.z *= K2; v.w *= K2;
        *(float4*)&wpL[m][w4 << 2] = v;
    }
    if (tid < 128) {
        float4 v = *(const float4*)(w1 + (tid << 2));
        v.x *= -2.f; v.y *= -2.f; v.z *= -2.f; v.w *= -2.f;
        *(float4*)&w1m2[tid << 2] = v;
    }
    // thread's channels: c = cg*4 + j*32 + i  (j=0..15, i=0..3)
    float4 wfs[16];
    float W1S = 0.f;
    const float* wfr = wf + (size_t)(b * T_ + t) * D_ + (cg << 2);
#pragma unroll
    for (int j = 0; j < 16; j++) {
        float4 v = *(const float4*)(wfr + (j << 5));
        wfs[j].x = v.x * K2; wfs[j].y = v.y * K2; wfs[j].z = v.z * K2; wfs[j].w = v.w * K2;
        float4 wv = *(const float4*)(w1 + (cg << 2) + (j << 5));
        W1S += wv.x + wv.y + wv.z + wv.w;
    }
    __syncthreads();
    float s[5] = {W1S, W1S, W1S, W1S, W1S};
#pragma unroll
    for (int j = 0; j < 16; j++) {
        float4 w14 = *(const float4*)&w1m2[(cg << 2) + (j << 5)];
#pragma unroll
        for (int m = 0; m < 5; m++) {
            float4 wp4 = *(const float4*)&wpL[m][(cg << 2) + (j << 5)];
            s[m] += w14.x * __builtin_amdgcn_rcpf(__builtin_amdgcn_exp2f(wfs[j].x + wp4.x) + 1.f);
            s[m] += w14.y * __builtin_amdgcn_rcpf(__builtin_amdgcn_exp2f(wfs[j].y + wp4.y) + 1.f);
            s[m] += w14.z * __builtin_amdgcn_rcpf(__builtin_amdgcn_exp2f(wfs[j].z + wp4.z) + 1.f);
            s[m] += w14.w * __builtin_amdgcn_rcpf(__builtin_amdgcn_exp2f(wfs[j].w + wp4.w) + 1.f);
        }
    }
#pragma unroll
    for (int m = 0; m < 5; m++) {
        s[m] += __shfl_xor(s[m], 1);
        s[m] += __shfl_xor(s[m], 2);
        s[m] += __shfl_xor(s[m], 4);
    }
    if (cg == 0) {
#pragma unroll
        for (int m = 0; m < 5; m++)
            scores[((size_t)b * ML_ + mg + m) * T_ + t] = s[m];
    }
}

// softmax over t, in place: 800 rows of 256. grid 200 x 256 threads (wave per row).
__global__ __launch_bounds__(256) void softmax_kernel(float* __restrict__ sc) {
    int wid = threadIdx.x >> 6, lane = threadIdx.x & 63;
    size_t row = (size_t)blockIdx.x * 4 + wid;
    float4* p = (float4*)(sc + row * T_);
    float4 v = p[lane];
    float mx = fmaxf(fmaxf(v.x, v.y), fmaxf(v.z, v.w));
    for (int o = 32; o; o >>= 1) mx = fmaxf(mx, __shfl_xor(mx, o));
    float4 e;
    e.x = __expf(v.x - mx); e.y = __expf(v.y - mx);
    e.z = __expf(v.z - mx); e.w = __expf(v.w - mx);
    float sm = e.x + e.y + e.z + e.w;
    for (int o = 32; o; o >>= 1) sm += __shfl_xor(sm, o);
    float inv = 1.f / sm;
    e.x *= inv; e.y *= inv; e.z *= inv; e.w *= inv;
    p[lane] = e;
}

// weighted sum: out[b,m,c] = sum_t attn[b,m,t]*wf[b,t,c]. grid (5 mgroups, 32 b).
__global__ __launch_bounds__(256) void wsum_kernel(const float* __restrict__ attn,
                                                   const float* __restrict__ wf,
                                                   float* __restrict__ out) {
    __shared__ float at[T_][8];
    int tid = threadIdx.x;
    int b = blockIdx.y, m0 = blockIdx.x * 5;
#pragma unroll
    for (int q = 0; q < 5; q++) {
        float a = attn[((size_t)b * ML_ + m0 + q) * T_ + tid];
        at[tid][q] = a;
    }
    __syncthreads();
    int c0 = tid << 1;
    const float* wfb = wf + (size_t)b * T_ * D_ + c0;
    float acc[5][2] = {};
    for (int t = 0; t < T_; t++) {
        float2 v = *(const float2*)(wfb + (size_t)t * D_);
        float4 a4 = *(const float4*)&at[t][0];
        float a5 = at[t][4];
        acc[0][0] += a4.x * v.x; acc[0][1] += a4.x * v.y;
        acc[1][0] += a4.y * v.x; acc[1][1] += a4.y * v.y;
        acc[2][0] += a4.z * v.x; acc[2][1] += a4.z * v.y;
        acc[3][0] += a4.w * v.x; acc[3][1] += a4.w * v.y;
        acc[4][0] += a5 * v.x;   acc[4][1] += a5 * v.y;
    }
#pragma unroll
    for (int q = 0; q < 5; q++) {
        float2 o;
        o.x = acc[q][0]; o.y = acc[q][1];
        *(float2*)(out + ((size_t)b * ML_ + m0 + q) * D_ + c0) = o;
    }
}

extern "C" void kernel_launch(void* const* d_in, const int* in_sizes, int n_in,
                              void* d_out, int out_size, void* d_ws, size_t ws_size,
                              hipStream_t stream) {
    (void)in_sizes; (void)n_in; (void)out_size; (void)ws_size;
    const float* x        = (const float*)d_in[0];
    const int*   epos     = (const int*)d_in[1];
    const int*   gpos     = (const int*)d_in[2];
    const float* pos_tab  = (const float*)d_in[3];
    const float* ln1_s    = (const float*)d_in[4];
    const float* ln1_b    = (const float*)d_in[5];
    const float* Wq       = (const float*)d_in[6];
    const float* bq       = (const float*)d_in[7];
    const float* Wk       = (const float*)d_in[8];
    const float* bk       = (const float*)d_in[9];
    const float* Wv       = (const float*)d_in[10];
    const float* bv       = (const float*)d_in[11];
    const float* Wo       = (const float*)d_in[12];
    const float* bo       = (const float*)d_in[13];
    const float* ln2_s    = (const float*)d_in[14];
    const float* ln2_b    = (const float*)d_in[15];
    const float* W1       = (const float*)d_in[16];
    const float* b1       = (const float*)d_in[17];
    const float* W2       = (const float*)d_in[18];
    const float* b2       = (const float*)d_in[19];
    const float* lnf_s    = (const float*)d_in[20];
    const float* lnf_b    = (const float*)d_in[21];
    const float* fc0_w    = (const float*)d_in[22];
    const float* fc0_b    = (const float*)d_in[23];
    const float* emb      = (const float*)d_in[24];
    const float* fc1_w    = (const float*)d_in[25];

    char* ws = (char*)d_ws;
    float*    enc = (float*)(ws);                       // 16.78 MB
    ushort_t* hi  = (ushort_t*)(ws + 16777216);         // 8.39 MB
    ushort_t* qb  = (ushort_t*)(ws + 25165824);         // 8.39 MB (qkv base; kb/vt follow)
    ushort_t* kb  = (ushort_t*)(ws + 33554432);         // 8.39 MB (lo/scb overlay later)
    ushort_t* lo  = (ushort_t*)(ws + 33554432);
    float*    scb = (float*)(ws + 33554432);            // scores 800KB (after fc0, kb/lo dead)
    ushort_t* vt  = (ushort_t*)(ws + 41943040);         // 8.39 MB (h1 overlays later)
    ushort_t* h1  = (ushort_t*)(ws + 41943040);
    ushort_t* ao  = (ushort_t*)(ws + 50331648);         // 8.39 MB
    float*    wf  = (float*)(ws + 58720256);            // 16.78 MB
    ushort_t* wt  = (ushort_t*)(ws + 75497472);         // 7.34 MB (14 slices of 512KB)
    const size_t WSL = (size_t)D_ * D_;

    convert_w_kernel<<<13 * 64, 256, 0, stream>>>(Wq, Wk, Wv, Wo, W1, W2, fc0_w, wt);
    prep_kernel<<<dim3(4, 8, 32), 256, 0, stream>>>(x, epos, pos_tab, enc);

    for (int l = 0; l < 2; l++) {
        size_t o1 = (size_t)l * D_;
        const ushort_t* WqkvT = wt + (l * 6 + 0) * WSL;   // [1536][512] concat
        const ushort_t* WoT = wt + (l * 6 + 3) * WSL;
        const ushort_t* W1T = wt + (l * 6 + 4) * WSL;
        const ushort_t* W2T = wt + (l * 6 + 5) * WSL;

        ln_kernel<false><<<2048, 256, 0, stream>>>(enc, ln1_s + o1, ln1_b + o1, hi, nullptr);
        gemm_kernel<5><<<1536, 256, 0, stream>>>(hi, nullptr, nullptr, WqkvT, nullptr, nullptr,
                                                 1, 24, bq + o1, bk + o1, bv + o1, nullptr, nullptr, qb);
        attn_fused_kernel<<<dim3(4, 256), 256, 0, stream>>>(qb, kb, vt, ao);
        gemm_kernel<2><<<512, 256, 0, stream>>>(ao, nullptr, nullptr, WoT, nullptr, nullptr,
                                                1, 8, bo + o1, nullptr, nullptr, enc, enc, nullptr);
        ln_kernel<false><<<2048, 256, 0, stream>>>(enc, ln2_s + o1, ln2_b + o1, hi, nullptr);
        gemm_kernel<3><<<512, 256, 0, stream>>>(hi, nullptr, nullptr, W1T, nullptr, nullptr,
                                                1, 8, b1 + o1, nullptr, nullptr, nullptr, nullptr, h1);
        gemm_kernel<2><<<512, 256, 0, stream>>>(h1, nullptr, nullptr, W2T, nullptr, nullptr,
                                                1, 8, b2 + o1, nullptr, nullptr, enc, enc, nullptr);
    }

    ln_kernel<true><<<2048, 256, 0, stream>>>(enc, lnf_s, lnf_b, hi, lo);
    // fc0 split-bf16: Ah*Wh + Al*Wh + Ah*Wl
    gemm_kernel<4><<<512, 256, 0, stream>>>(hi, lo, hi, wt + 12 * WSL, wt + 12 * WSL, wt + 13 * WSL,
                                            3, 8, fc0_b, nullptr, nullptr, nullptr, wf, nullptr);
    scores_kernel<<<dim3(8, 32, 5), 256, 0, stream>>>(wf, gpos, emb, fc1_w, scb);
    softmax_kernel<<<200, 256, 0, stream>>>(scb);
    wsum_kernel<<<dim3(5, 32), 256, 0, stream>>>(scb, wf, (float*)d_out);
}